// Round 4
// baseline (544.363 us; speedup 1.0000x reference)
//
#include <hip/hip_runtime.h>
#include <hip/hip_bf16.h>
#include <math.h>
#include <type_traits>

typedef __hip_bfloat16 bf16;
typedef __attribute__((ext_vector_type(8))) short short8;
typedef __attribute__((ext_vector_type(4))) float f32x4;

// Problem constants
#define NB 4
#define NS 1024
#define ND 1024
#define NH 16
#define NDH 64
#define NR 64
#define NDFF 4096
#define NM (NB*NS)     // 4096 rows
#define NTOPK 204      // int(1024*0.2)

static __device__ __forceinline__ float b2f(bf16 x) { return __bfloat162float(x); }
static __device__ __forceinline__ bf16  f2b(float x) { return __float2bfloat16(x); }
static __device__ __forceinline__ unsigned short bfbits(float x) {
  bf16 h = __float2bfloat16(x);
  return *reinterpret_cast<unsigned short*>(&h);
}

// async global->LDS, 16B per lane; LDS dest = wave-uniform base + lane*16
static __device__ __forceinline__ void gload_lds16(const void* g, void* l) {
  __builtin_amdgcn_global_load_lds(
      (const __attribute__((address_space(1))) void*)g,
      (__attribute__((address_space(3))) void*)l, 16, 0, 0);
}

// counted vmcnt wait (T4): wait own outstanding VMEM ops <= N, leaving the
// newest N (the in-flight prefetch) pending across the following barrier.
template<int N> static __device__ __forceinline__ void vm_wait() {
  if constexpr (N == 0)       asm volatile("s_waitcnt vmcnt(0)" ::: "memory");
  else if constexpr (N == 4)  asm volatile("s_waitcnt vmcnt(4)" ::: "memory");
  else if constexpr (N == 6)  asm volatile("s_waitcnt vmcnt(6)" ::: "memory");
  else if constexpr (N == 8)  asm volatile("s_waitcnt vmcnt(8)" ::: "memory");
  else static_assert(N == 0, "unsupported vmcnt");
}
// raw barrier (no implicit vmcnt drain); memory clobber = compiler fence so
// LDS accesses cannot be moved across it.
static __device__ __forceinline__ void bar() {
  asm volatile("s_barrier" ::: "memory");
}

// 8 consecutive bf16 -> fp32 (one 16B load)
static __device__ __forceinline__ void ld8(const bf16* p, float* d) {
  const uint4 u = *(const uint4*)p;
  d[0] = __uint_as_float((u.x & 0xffffu) << 16);
  d[1] = __uint_as_float(u.x & 0xffff0000u);
  d[2] = __uint_as_float((u.y & 0xffffu) << 16);
  d[3] = __uint_as_float(u.y & 0xffff0000u);
  d[4] = __uint_as_float((u.z & 0xffffu) << 16);
  d[5] = __uint_as_float(u.z & 0xffff0000u);
  d[6] = __uint_as_float((u.w & 0xffffu) << 16);
  d[7] = __uint_as_float(u.w & 0xffff0000u);
}

static __device__ __forceinline__ float block_sum_256(float v, float* rbuf, int tid) {
  rbuf[tid] = v;
  __syncthreads();
  #pragma unroll
  for (int st = 128; st > 0; st >>= 1) {
    if (tid < st) rbuf[tid] += rbuf[tid + st];
    __syncthreads();
  }
  const float r = rbuf[0];
  __syncthreads();
  return r;
}

// ---------------------------------------------------------------------------
// Fused fp32 -> bf16 cast over 6 regions (each a multiple of 1024 elems).
// ---------------------------------------------------------------------------
struct CastArgs {
  const float* in[6];
  bf16* out[6];
  unsigned end[6];   // cumulative block counts
};
__global__ __launch_bounds__(256) void cast6_kernel(CastArgs a) {
  const unsigned b = blockIdx.x;
  int r = 0; unsigned base = 0;
  #pragma unroll
  for (int k = 0; k < 5; ++k)
    if (b >= a.end[k]) { r = k + 1; base = a.end[k]; }
  const float* in = a.in[r];
  bf16* out = a.out[r];
  const unsigned i = ((b - base) * 256 + threadIdx.x) * 4;
  const float4 v = *(const float4*)(in + i);
  uint2 o;
  o.x = (unsigned)bfbits(v.x) | ((unsigned)bfbits(v.y) << 16);
  o.y = (unsigned)bfbits(v.z) | ((unsigned)bfbits(v.w) << 16);
  *(uint2*)(out + i) = o;
}

// Concat Qp_w/Kp_w -> bf16 [128][1024], Qp_b/Kp_b -> fp32 [128]
__global__ __launch_bounds__(256) void pack_qk_kernel(
    const float* __restrict__ Qw, const float* __restrict__ Kw,
    const float* __restrict__ Qb, const float* __restrict__ Kb,
    bf16* __restrict__ w, float* __restrict__ bias) {
  const int r = blockIdx.x;  // 0..127
  const float* srcw = (r < 64) ? (Qw + (size_t)r * ND) : (Kw + (size_t)(r - 64) * ND);
  for (int i = threadIdx.x; i < ND; i += 256) w[(size_t)r * ND + i] = f2b(srcw[i]);
  if (r == 0)
    for (int i = threadIdx.x; i < 128; i += 256)
      bias[i] = (i < 64) ? Qb[i] : Kb[i - 64];
}

// ---------------------------------------------------------------------------
// Generic batched MFMA GEMM: C = scale*(A @ W^T) (+bias), bf16 in.
// LDS-pressure split (this round's change): A is staged via global_load_lds
// (XOR-slot swizzle as before); B FRAGMENTS ARE LOADED DIRECTLY GLOBAL->VGPR
// (the MFMA B-frag layout row=lane&15, k=(lane>>4)*8+e is 16B/lane of a
// row-major K-contiguous matrix — same pattern as the attn Q-frags). This
// halves LDS traffic (the measured bottleneck: 72KB/K-tile/block vs an ~85B/cy
// LDS pipe) and moves B onto the parallel VMEM/L2 pipe (panels are L2-hot).
// B regs are double-buffered with STATIC indexing (integral_constant).
// Counted-vmcnt pipeline (T4): per K-iter
//   stageA(next) ; loadB(next) ; s_waitcnt vmcnt(LPW) ; s_barrier ;
//   compute(cur) ; s_barrier
// LPW = A-stage insts + B loads per wave per iter -> waits only on the
// PREVIOUS iteration's ops; fresh prefetch stays in flight across barriers.
// 256 threads = 4 waves in a 2x2 grid; wave tile = (BM/2)x(BN/2).
// Batch z: off = (z>>4)*Hi + (z&15)*Lo.  K multiple of BK; K/BK even or ==1.
// XCD-compact swizzle when gridDim.x%8==0 (perf heuristic only).
// ---------------------------------------------------------------------------
template<int BM, int BN, int BK, int BIAS, int RELU, int OUTF32>
__global__ __launch_bounds__(256) void mfma_gemm(
    const bf16* __restrict__ A, const bf16* __restrict__ W,
    const float* __restrict__ bias, void* __restrict__ C,
    int K, int lda, int ldb, int ldc,
    long long aHi, long long aLo, long long bHi, long long bLo,
    long long cHi, long long cLo, float scale)
{
  constexpr int WTM = BM / 2;
  constexpr int WTN = BN / 2;
  constexpr int AM = WTM / 16;
  constexpr int AN = WTN / 16;
  constexpr int KK = BK / 32;        // MFMA sub-steps per K-tile
  constexpr int SLOTS = BK / 8;      // 16B slots per LDS row
  constexpr int RPC = 512 / BK;      // rows per wave per gload_lds16 call
  constexpr int ASTG = (BM * BK) / 2048;   // A-stage insts per wave per iter
  constexpr int LPW  = ASTG + AN * KK;     // total VMEM insts per wave per iter
  __shared__ short As[2][BM * BK];
  const int tid  = threadIdx.x;
  const int lane = tid & 63;
  const int w    = tid >> 6;
  const int z    = blockIdx.z;
  const long long aOff = (long long)(z >> 4) * aHi + (long long)(z & 15) * aLo;
  const long long bOff = (long long)(z >> 4) * bHi + (long long)(z & 15) * bLo;
  const long long cOff = (long long)(z >> 4) * cHi + (long long)(z & 15) * cLo;

  int bx = blockIdx.x, by = blockIdx.y;
  if ((gridDim.x & 7) == 0) {
    const unsigned lin = blockIdx.y * gridDim.x + blockIdx.x;
    const unsigned Wd = gridDim.x >> 3;
    const unsigned xcd = lin & 7, i = lin >> 3;
    bx = (int)(xcd * Wd + (i % Wd));
    by = (int)(i / Wd);
  }
  const int m0 = by * BM;
  const int n0 = bx * BN;
  const int wr = w >> 1, wc = w & 1;
  const int lm = lane & 15, quad = lane >> 4;

  f32x4 acc[AM][AN];
  #pragma unroll
  for (int i = 0; i < AM; ++i)
    #pragma unroll
    for (int j = 0; j < AN; ++j) acc[i][j] = (f32x4){0.f, 0.f, 0.f, 0.f};

  // A staging lane map + slot swizzle (write side, on GLOBAL source col)
  const int slot = lane & (SLOTS - 1);
  const int sr   = lane / SLOTS;
  const int swz  = (BK == 32) ? ((sr >> 1) & 3) : (sr & 7);
  const int scol = (slot ^ swz) << 3;  // shorts
  const int xv   = (BK == 32) ? ((lm >> 1) & 3) : (lm & 7);
  const bf16* Ab = A + aOff;
  const bf16* Bb = W + bOff + (long long)(n0 + wc * WTN + lm) * ldb + quad * 8;

  auto stageA = [&](int buf, int t) {
    const int k0 = t * BK;
    #pragma unroll
    for (int u = 0; u < ASTG; ++u) {
      const int row = w * (BM / 4) + u * RPC;
      gload_lds16(Ab + (long long)(m0 + row + sr) * lda + k0 + scol, &As[buf][row * BK]);
    }
  };

  short8 brg[2][AN * KK];          // B fragments, double-buffered in regs
  auto loadB = [&](auto BUF, int t) {
    constexpr int bu = decltype(BUF)::value;
    const int k0 = t * BK;
    #pragma unroll
    for (int j = 0; j < AN; ++j)
      #pragma unroll
      for (int kk = 0; kk < KK; ++kk)
        brg[bu][j * KK + kk] =
            *(const short8*)(Bb + (long long)(j * 16) * ldb + k0 + kk * 32);
  };

  auto compute = [&](auto BUF) {
    constexpr int bu = decltype(BUF)::value;
    #pragma unroll
    for (int kk = 0; kk < KK; ++kk) {
      const int cb = ((kk * 4 + quad) ^ xv) << 3;   // swizzled 16B slot, shorts
      short8 af[AM];
      #pragma unroll
      for (int i = 0; i < AM; ++i)
        af[i] = *(const short8*)&As[bu][(wr * WTM + i * 16 + lm) * BK + cb];
      #pragma unroll
      for (int i = 0; i < AM; ++i)
        #pragma unroll
        for (int j = 0; j < AN; ++j)
          acc[i][j] = __builtin_amdgcn_mfma_f32_16x16x32_bf16(
              af[i], brg[bu][j * KK + kk], acc[i][j], 0, 0, 0);
    }
  };
  const std::integral_constant<int, 0> B0{};
  const std::integral_constant<int, 1> B1{};

  const int nt = K / BK;           // 1, or even
  stageA(0, 0); loadB(B0, 0);
  if (nt == 1) {
    vm_wait<0>(); bar(); compute(B0);
  } else {
    for (int t = 1; t + 1 < nt; t += 2) {
      stageA(1, t);     loadB(B1, t);
      vm_wait<LPW>(); bar(); compute(B0); bar();
      stageA(0, t + 1); loadB(B0, t + 1);
      vm_wait<LPW>(); bar(); compute(B1); bar();
    }
    stageA(1, nt - 1); loadB(B1, nt - 1);
    vm_wait<LPW>(); bar(); compute(B0); bar();
    vm_wait<0>(); bar(); compute(B1);
  }

  #pragma unroll
  for (int i = 0; i < AM; ++i) {
    #pragma unroll
    for (int j = 0; j < AN; ++j) {
      const int n = n0 + wc * WTN + j * 16 + lm;
      const float bj = BIAS ? bias[n] : 0.f;
      #pragma unroll
      for (int rr = 0; rr < 4; ++rr) {
        const int m = m0 + wr * WTM + i * 16 + quad * 4 + rr;
        float v = acc[i][j][rr] * scale + bj;
        if (RELU) v = fmaxf(v, 0.f);
        const long long co = cOff + (long long)m * ldc + n;
        if (OUTF32) ((float*)C)[co] = v;
        else        ((bf16*)C)[co] = f2b(v);
      }
    }
  }
}

// ---------------------------------------------------------------------------
// Fused flash attention (dense MHA): per (q-tile of 128, b, h) block.
// Swapped QK^T -> S^T frags (q = lane&15); online softmax via 2 shfl_xor;
// P^T bf16 B-frags built in-register via shfl. K/V^T staged via
// global_load_lds + XOR slot swizzle; counted-vmcnt 2-barrier pipeline.
// grid (NS/128, NB*NH), 256 threads.
// ---------------------------------------------------------------------------
__global__ __launch_bounds__(256) void attn_kernel(
    const bf16* __restrict__ qkv,   // [B][S][3*ND]
    const bf16* __restrict__ Vt,    // [B*H][NDH][NS]
    bf16* __restrict__ ctx)         // [B][S][ND]
{
  __shared__ short smem[2][2][64 * 64];   // [buf][K|V][4096] = 32 KB
  const int tid = threadIdx.x, lane = tid & 63, w = tid >> 6;
  const int lm = lane & 15, quad = lane >> 4;
  const int z = blockIdx.y, b = z >> 4, h = z & 15;
  const int q0 = blockIdx.x * 128;
  const bf16* Qb = qkv + (long long)b * NS * 3072 + h * 64;
  const bf16* Kb = Qb + ND;
  const bf16* Vb = Vt + (long long)z * (NDH * NS);

  // Q B-frags [j][kk]: col q = q0 + w*32 + j*16 + lm, k(d) = kk*32 + quad*8 + e
  short8 qf[2][2];
  #pragma unroll
  for (int j = 0; j < 2; ++j)
    #pragma unroll
    for (int kk = 0; kk < 2; ++kk)
      qf[j][kk] = *(const short8*)(Qb + (long long)(q0 + w * 32 + j * 16 + lm) * 3072
                                      + kk * 32 + quad * 8);

  // staging map (8 slots of 16B per 64-elem row; 8 rows per issue per wave)
  const int slot = lane & 7, sr = lane >> 3;
  const int scol = (slot ^ sr) << 3;      // shorts; involution with read side

  auto stage = [&](int buf, int t) {
    #pragma unroll
    for (int u = 0; u < 2; ++u) {
      const int row = w * 16 + u * 8;     // kv row within tile
      gload_lds16(Kb + (long long)(t * 64 + row + sr) * 3072 + scol,
                  &smem[buf][0][row * 64]);
    }
    #pragma unroll
    for (int u = 0; u < 2; ++u) {
      const int row = w * 16 + u * 8;     // d row
      gload_lds16(Vb + (long long)(row + sr) * NS + t * 64 + scol,
                  &smem[buf][1][row * 64]);
    }
  };

  f32x4 o[4][2];                          // O^T: d-tile i, q-tile j
  #pragma unroll
  for (int i = 0; i < 4; ++i)
    #pragma unroll
    for (int j = 0; j < 2; ++j) o[i][j] = (f32x4){0.f, 0.f, 0.f, 0.f};
  float m[2] = {-1e30f, -1e30f}, l[2] = {0.f, 0.f};

  stage(0, 0);
  for (int t = 0; t < 16; ++t) {
    const int buf = t & 1;
    if (t < 15) { stage(buf ^ 1, t + 1); vm_wait<4>(); }
    else        { vm_wait<0>(); }
    bar();                                // tile t's loads visible to all

    // --- S^T = (K @ Q^T)/8 : st[i][j], i = kv-tile, j = q-tile
    f32x4 st[4][2];
    #pragma unroll
    for (int i = 0; i < 4; ++i)
      #pragma unroll
      for (int j = 0; j < 2; ++j) st[i][j] = (f32x4){0.f, 0.f, 0.f, 0.f};
    #pragma unroll
    for (int kk = 0; kk < 2; ++kk) {
      const int cb = ((kk * 4 + quad) ^ (lm & 7)) << 3;
      short8 ka[4];
      #pragma unroll
      for (int i = 0; i < 4; ++i)
        ka[i] = *(const short8*)&smem[buf][0][(i * 16 + lm) * 64 + cb];
      #pragma unroll
      for (int i = 0; i < 4; ++i)
        #pragma unroll
        for (int j = 0; j < 2; ++j)
          st[i][j] = __builtin_amdgcn_mfma_f32_16x16x32_bf16(ka[i], qf[j][kk], st[i][j], 0, 0, 0);
    }

    // --- online softmax per q-col (j); kv spread over 16 regs x 4 quads
    #pragma unroll
    for (int j = 0; j < 2; ++j) {
      float pm = -1e30f;
      #pragma unroll
      for (int i = 0; i < 4; ++i)
        #pragma unroll
        for (int r = 0; r < 4; ++r) {
          st[i][j][r] *= 0.125f;
          pm = fmaxf(pm, st[i][j][r]);
        }
      pm = fmaxf(pm, __shfl_xor(pm, 16, 64));
      pm = fmaxf(pm, __shfl_xor(pm, 32, 64));
      const float mn = fmaxf(m[j], pm);
      const float sc = __expf(m[j] - mn);
      float ps = 0.f;
      #pragma unroll
      for (int i = 0; i < 4; ++i)
        #pragma unroll
        for (int r = 0; r < 4; ++r) {
          const float e = __expf(st[i][j][r] - mn);
          st[i][j][r] = e;                 // st now holds P^T
          ps += e;
        }
      ps += __shfl_xor(ps, 16, 64);
      ps += __shfl_xor(ps, 32, 64);
      l[j] = l[j] * sc + ps;
      m[j] = mn;
      #pragma unroll
      for (int i = 0; i < 4; ++i)
        #pragma unroll
        for (int r = 0; r < 4; ++r) o[i][j][r] *= sc;
    }

    // --- pack P^T to bf16 pairs: u0 = (r0,r1), u1 = (r2,r3)
    unsigned u0[4][2], u1[4][2];
    #pragma unroll
    for (int i = 0; i < 4; ++i)
      #pragma unroll
      for (int j = 0; j < 2; ++j) {
        u0[i][j] = (unsigned)bfbits(st[i][j][0]) | ((unsigned)bfbits(st[i][j][1]) << 16);
        u1[i][j] = (unsigned)bfbits(st[i][j][2]) | ((unsigned)bfbits(st[i][j][3]) << 16);
      }
    // target frag (kk,j) elem e: kv = kk*32+quad*8+e comes from
    //   i_src = kk*2 + (quad>>1), src lane = ((quad&1)*2 + (e>>2))*16 + lm, r = e&3
    const int s0l = ((quad & 1) * 2) * 16 + lm;
    const int s1l = s0l + 16;
    const bool hi = (quad >> 1) != 0;

    // --- O^T += V^T @ P^T
    #pragma unroll
    for (int kk = 0; kk < 2; ++kk) {
      short8 pf[2];
      #pragma unroll
      for (int j = 0; j < 2; ++j) {
        const unsigned a0 = __shfl(u0[kk * 2][j],     s0l, 64);
        const unsigned a1 = __shfl(u1[kk * 2][j],     s0l, 64);
        const unsigned b0 = __shfl(u0[kk * 2 + 1][j], s0l, 64);
        const unsigned b1 = __shfl(u1[kk * 2 + 1][j], s0l, 64);
        const unsigned c0 = __shfl(u0[kk * 2][j],     s1l, 64);
        const unsigned c1 = __shfl(u1[kk * 2][j],     s1l, 64);
        const unsigned d0 = __shfl(u0[kk * 2 + 1][j], s1l, 64);
        const unsigned d1 = __shfl(u1[kk * 2 + 1][j], s1l, 64);
        union { uint4 u; short8 s; } cv;
        cv.u.x = hi ? b0 : a0; cv.u.y = hi ? b1 : a1;
        cv.u.z = hi ? d0 : c0; cv.u.w = hi ? d1 : c1;
        pf[j] = cv.s;
      }
      const int cb = ((kk * 4 + quad) ^ (lm & 7)) << 3;
      short8 va[4];
      #pragma unroll
      for (int i = 0; i < 4; ++i)
        va[i] = *(const short8*)&smem[buf][1][(i * 16 + lm) * 64 + cb];
      #pragma unroll
      for (int i = 0; i < 4; ++i)
        #pragma unroll
        for (int j = 0; j < 2; ++j)
          o[i][j] = __builtin_amdgcn_mfma_f32_16x16x32_bf16(va[i], pf[j], o[i][j], 0, 0, 0);
    }
    bar();   // all waves done reading buf before next overwrite / epilogue
  }

  // --- epilogue: normalize, transpose O^T -> O through LDS, coalesced store
  short (*OL)[72] = (short(*)[72])&smem[0][0][0];   // 128 x 72 = 18.4 KB
  #pragma unroll
  for (int j = 0; j < 2; ++j) {
    const float inv = 1.f / l[j];
    #pragma unroll
    for (int i = 0; i < 4; ++i) {
      uint2 u;
      u.x = (unsigned)bfbits(o[i][j][0] * inv) | ((unsigned)bfbits(o[i][j][1] * inv) << 16);
      u.y = (unsigned)bfbits(o[i][j][2] * inv) | ((unsigned)bfbits(o[i][j][3] * inv) << 16);
      *(uint2*)&OL[w * 32 + j * 16 + lm][i * 16 + quad * 4] = u;
    }
  }
  __syncthreads();
  {
    const int q = tid >> 1, c = (tid & 1) * 32;
    const uint4 r0 = *(const uint4*)&OL[q][c];
    const uint4 r1 = *(const uint4*)&OL[q][c + 8];
    const uint4 r2 = *(const uint4*)&OL[q][c + 16];
    const uint4 r3 = *(const uint4*)&OL[q][c + 24];
    bf16* dst = ctx + ((long long)(b * NS + q0 + q)) * 1024 + h * 64 + c;
    ((uint4*)dst)[0] = r0; ((uint4*)dst)[1] = r1;
    ((uint4*)dst)[2] = r2; ((uint4*)dst)[3] = r3;
  }
}

// ---------------------------------------------------------------------------
// All-batch: Vt[b*16+h][d][s] = qkv[b][s][2048 + h*64 + d]  (64x64 transpose)
// ---------------------------------------------------------------------------
__global__ __launch_bounds__(256) void transpose_v_kernel(
    const bf16* __restrict__ qkv, bf16* __restrict__ Vt) {
  __shared__ short T[64][72];
  const int tid = threadIdx.x;
  const int h = blockIdx.y;
  const int b = blockIdx.z;
  const int s0 = blockIdx.x * 64;
  const bf16* src = qkv + ((long long)b * NS + s0) * 3072 + 2 * ND + h * 64;
  {
    const int s = tid >> 2, c = (tid & 3) * 16;
    const uint4 a0 = *(const uint4*)(src + (long long)s * 3072 + c);
    const uint4 a1 = *(const uint4*)(src + (long long)s * 3072 + c + 8);
    *(uint4*)&T[s][c] = a0; *(uint4*)&T[s][c + 8] = a1;
  }
  __syncthreads();
  {
    const int d = tid >> 2, c = (tid & 3) * 16;
    unsigned wds[8];
    #pragma unroll
    for (int u = 0; u < 8; ++u) {
      const unsigned lo = (unsigned short)T[c + 2 * u][d];
      const unsigned hi = (unsigned short)T[c + 2 * u + 1][d];
      wds[u] = lo | (hi << 16);
    }
    bf16* dst = Vt + (long long)(b * NH + h) * (NDH * NS) + (long long)d * NS + s0 + c;
    uint4 o0, o1;
    o0.x = wds[0]; o0.y = wds[1]; o0.z = wds[2]; o0.w = wds[3];
    o1.x = wds[4]; o1.y = wds[5]; o1.z = wds[6]; o1.w = wds[7];
    ((uint4*)dst)[0] = o0; ((uint4*)dst)[1] = o1;
  }
}

// ---------------------------------------------------------------------------
// Batched 1024x1024 bf16 transpose: dst[b][d][s] = src[b][s][d]
// ---------------------------------------------------------------------------
__global__ __launch_bounds__(256) void transpose_sq_kernel(
    const bf16* __restrict__ src, bf16* __restrict__ dst) {
  __shared__ short T[64][72];
  const int tid = threadIdx.x;
  const int b = blockIdx.z;
  const int s0 = blockIdx.x * 64, d0 = blockIdx.y * 64;
  const bf16* sp = src + ((long long)b * NS + s0) * ND + d0;
  {
    const int s = tid >> 2, c = (tid & 3) * 16;
    const uint4 a0 = *(const uint4*)(sp + (long long)s * ND + c);
    const uint4 a1 = *(const uint4*)(sp + (long long)s * ND + c + 8);
    *(uint4*)&T[s][c] = a0; *(uint4*)&T[s][c + 8] = a1;
  }
  __syncthreads();
  {
    const int d = tid >> 2, c = (tid & 3) * 16;
    unsigned wds[8];
    #pragma unroll
    for (int u = 0; u < 8; ++u) {
      const unsigned lo = (unsigned short)T[c + 2 * u][d];
      const unsigned hi = (unsigned short)T[c + 2 * u + 1][d];
      wds[u] = lo | (hi << 16);
    }
    bf16* dp = dst + ((long long)b * ND + d0 + d) * NS + s0 + c;
    uint4 o0, o1;
    o0.x = wds[0]; o0.y = wds[1]; o0.z = wds[2]; o0.w = wds[3];
    o1.x = wds[4]; o1.y = wds[5]; o1.z = wds[6]; o1.w = wds[7];
    ((uint4*)dp)[0] = o0; ((uint4*)dp)[1] = o1;
  }
}

// ---------------------------------------------------------------------------
// Sparse top-k selection from precomputed fp32 scores S[row][1024].
// One WAVE per row (4 rows/block); wave-local radix select.
// ---------------------------------------------------------------------------
__global__ __launch_bounds__(256) void sparse_select_kernel(
    const float* __restrict__ S, bf16* __restrict__ aw)
{
  __shared__ unsigned hist[4][256];
  const int tid = threadIdx.x;
  const int lane = tid & 63;
  const int wv = tid >> 6;
  const long long row = (long long)blockIdx.x * 4 + wv;

  float sv[16];
  const float* sp = S + row * 1024 + lane * 16;
  #pragma unroll
  for (int c = 0; c < 4; ++c) {
    const float4 v = ((const float4*)sp)[c];
    sv[4*c] = v.x; sv[4*c+1] = v.y; sv[4*c+2] = v.z; sv[4*c+3] = v.w;
  }
  unsigned key[16];
  #pragma unroll
  for (int j = 0; j < 16; ++j) {
    const unsigned u = __float_as_uint(sv[j]);
    key[j] = (u & 0x80000000u) ? ~u : (u | 0x80000000u);  // order-preserving
  }

  unsigned pref = 0u;
  int need = NTOPK;
  #pragma unroll
  for (int p = 3; p >= 0; --p) {
    *(uint4*)&hist[wv][lane * 4] = (uint4){0u, 0u, 0u, 0u};
    __syncthreads();
    const int sh = (p + 1) * 8;
    #pragma unroll
    for (int j = 0; j < 16; ++j) {
      const bool part = (p == 3) || ((key[j] >> sh) == pref);
      if (part) atomicAdd(&hist[wv][(key[j] >> (p * 8)) & 255u], 1u);
    }
    __syncthreads();
    const unsigned h0 = hist[wv][4*lane],     h1 = hist[wv][4*lane + 1];
    const unsigned h2 = hist[wv][4*lane + 2], h3 = hist[wv][4*lane + 3];
    const unsigned s3 = h3, s2 = h2 + s3, s1 = h1 + s2, s0 = h0 + s1;
    unsigned sum = s0;                      // suffix sum over lanes >= lane
    #pragma unroll
    for (int d2 = 1; d2 < 64; d2 <<= 1) {
      const unsigned t = __shfl_down(sum, d2, 64);
      if (lane < 64 - d2) sum += t;
    }
    const unsigned above = sum - s0;
    const unsigned cum[4]  = {above + s0, above + s1, above + s2, above + s3};
    const unsigned next[4] = {above + s1, above + s2, above + s3, above};
    unsigned candPref = 0u; int candNeed = 0; bool has = false;
    #pragma unroll
    for (int i = 0; i < 4; ++i) {
      if ((int)cum[i] >= need && (int)next[i] < need) {
        has = true;
        candPref = (pref << 8) | (unsigned)(4 * lane + i);
        candNeed = need - (int)next[i];
      }
    }
    const unsigned long long m = __ballot(has);
    const int srcLane = (int)(__ffsll((long long)m) - 1);
    pref = (unsigned)__shfl((int)candPref, srcLane, 64);
    need = __shfl(candNeed, srcLane, 64);
  }

  const unsigned T = pref;                  // 204th-largest key
  const unsigned tb = (T & 0x80000000u) ? (T ^ 0x80000000u) : ~T;
  const float thr = __uint_as_float(tb);

  float wvv[16];
  float psTop = 0.f, psAll = 0.f;
  #pragma unroll
  for (int j = 0; j < 16; ++j) {
    const float e = __expf(sv[j] - thr);
    psAll += e;
    const float wt = (key[j] >= T) ? e : 0.f;
    psTop += wt;
    wvv[j] = wt;
  }
  #pragma unroll
  for (int s = 1; s < 64; s <<= 1) {
    psTop += __shfl_xor(psTop, s, 64);
    psAll += __shfl_xor(psAll, s, 64);
  }
  const float inv = 1.f / (psTop + 1e-9f * psAll);

  uint4 o0, o1;
  o0.x = (unsigned)bfbits(wvv[0]*inv)  | ((unsigned)bfbits(wvv[1]*inv)  << 16);
  o0.y = (unsigned)bfbits(wvv[2]*inv)  | ((unsigned)bfbits(wvv[3]*inv)  << 16);
  o0.z = (unsigned)bfbits(wvv[4]*inv)  | ((unsigned)bfbits(wvv[5]*inv)  << 16);
  o0.w = (unsigned)bfbits(wvv[6]*inv)  | ((unsigned)bfbits(wvv[7]*inv)  << 16);
  o1.x = (unsigned)bfbits(wvv[8]*inv)  | ((unsigned)bfbits(wvv[9]*inv)  << 16);
  o1.y = (unsigned)bfbits(wvv[10]*inv) | ((unsigned)bfbits(wvv[11]*inv) << 16);
  o1.z = (unsigned)bfbits(wvv[12]*inv) | ((unsigned)bfbits(wvv[13]*inv) << 16);
  o1.w = (unsigned)bfbits(wvv[14]*inv) | ((unsigned)bfbits(wvv[15]*inv) << 16);
  bf16* op = aw + row * 1024 + lane * 16;
  ((uint4*)op)[0] = o0; ((uint4*)op)[1] = o1;
}

// ---------------------------------------------------------------------------
// fused = sig*dense + (1-sig)*sparse ; x1 = LN1(src + fused)  (bf16 out)
// ---------------------------------------------------------------------------
__global__ __launch_bounds__(256) void fuse_ln1_kernel(
    const float* __restrict__ src, const bf16* __restrict__ dense,
    const bf16* __restrict__ sparse, const float* __restrict__ lam,
    const float* __restrict__ g, const float* __restrict__ beta,
    bf16* __restrict__ x1)
{
  __shared__ float y[ND];
  __shared__ float rbuf[256];
  const int tid = threadIdx.x;
  const size_t base = (size_t)blockIdx.x * ND;
  const float sig = 1.f / (1.f + __expf(-lam[0]));
  const float c1 = 1.f - sig;
  float s1 = 0.f, s2 = 0.f;
  #pragma unroll
  for (int j = 0; j < 4; ++j) {
    const int i = tid + (j << 8);
    const float v = src[base + i] + sig * b2f(dense[base + i]) + c1 * b2f(sparse[base + i]);
    y[i] = v; s1 += v; s2 += v * v;
  }
  const float sum1 = block_sum_256(s1, rbuf, tid);
  const float sum2 = block_sum_256(s2, rbuf, tid);
  const float mean = sum1 * (1.f / ND);
  const float var  = sum2 * (1.f / ND) - mean * mean;
  const float rstd = rsqrtf(var + 1e-5f);
  #pragma unroll
  for (int j = 0; j < 4; ++j) {
    const int i = tid + (j << 8);
    x1[base + i] = f2b((y[i] - mean) * rstd * g[i] + beta[i]);
  }
}

// out = LN2(x1 + ff)  (fp32 out; ff is bf16)
__global__ __launch_bounds__(256) void ln2_kernel(
    const bf16* __restrict__ x1, const bf16* __restrict__ ff,
    const float* __restrict__ g, const float* __restrict__ beta,
    float* __restrict__ outp)
{
  __shared__ float y[ND];
  __shared__ float rbuf[256];
  const int tid = threadIdx.x;
  const size_t base = (size_t)blockIdx.x * ND;
  float s1 = 0.f, s2 = 0.f;
  #pragma unroll
  for (int j = 0; j < 4; ++j) {
    const int i = tid + (j << 8);
    const float v = b2f(x1[base + i]) + b2f(ff[base + i]);
    y[i] = v; s1 += v; s2 += v * v;
  }
  const float sum1 = block_sum_256(s1, rbuf, tid);
  const float sum2 = block_sum_256(s2, rbuf, tid);
  const float mean = sum1 * (1.f / ND);
  const float var  = sum2 * (1.f / ND) - mean * mean;
  const float rstd = rsqrtf(var + 1e-5f);
  #pragma unroll
  for (int j = 0; j < 4; ++j) {
    const int i = tid + (j << 8);
    outp[base + i] = (y[i] - mean) * rstd * g[i] + beta[i];
  }
}

// ---------------------------------------------------------------------------
extern "C" void kernel_launch(void* const* d_in, const int* in_sizes, int n_in,
                              void* d_out, int out_size, void* d_ws, size_t ws_size,
                              hipStream_t stream)
{
  const float* src        = (const float*)d_in[0];
  const float* in_proj_w  = (const float*)d_in[1];
  const float* in_proj_b  = (const float*)d_in[2];
  const float* out_proj_w = (const float*)d_in[3];
  const float* out_proj_b = (const float*)d_in[4];
  const float* Qp_w  = (const float*)d_in[5];
  const float* Qp_b  = (const float*)d_in[6];
  const float* Kp_w  = (const float*)d_in[7];
  const float* Kp_b  = (const float*)d_in[8];
  const float* Vp_w  = (const float*)d_in[9];
  const float* Vp_b  = (const float*)d_in[10];
  const float* lam   = (const float*)d_in[11];
  const float* ff1_w = (const float*)d_in[12];
  const float* ff1_b = (const float*)d_in[13];
  const float* ff2_w = (const float*)d_in[14];
  const float* ff2_b = (const float*)d_in[15];
  const float* ln1_g = (const float*)d_in[16];
  const float* ln1_b = (const float*)d_in[17];
  const float* ln2_g = (const float*)d_in[18];
  const float* ln2_b = (const float*)d_in[19];
  (void)in_sizes; (void)n_in; (void)out_size; (void)ws_size;

  // --------- workspace layout (offsets IDENTICAL to the proven layout;
  // Vt_all reuses the old S_b slot)
  char* ws = (char*)d_ws;
  size_t off = 0;
  auto take = [&](size_t bytes) -> void* {
    void* p = ws + off; off += (bytes + 255) & ~(size_t)255; return p;
  };
  bf16*  src_bf  = (bf16*) take((size_t)NM * ND * 2);          //  8.4 MB
  bf16*  w_qkv   = (bf16*) take((size_t)3 * ND * ND * 2);      //  6.3 MB
  bf16*  w_out   = (bf16*) take((size_t)ND * ND * 2);          //  2.1 MB
  bf16*  w_vp    = (bf16*) take((size_t)ND * ND * 2);          //  2.1 MB
  bf16*  w_ff1   = (bf16*) take((size_t)NDFF * ND * 2);        //  8.4 MB
  bf16*  w_ff2   = (bf16*) take((size_t)ND * NDFF * 2);        //  8.4 MB
  bf16*  w_qk    = (bf16*) take((size_t)128 * ND * 2);         //  0.26 MB
  float* bias_qk = (float*)take(128 * 4);
  const size_t mark = off;                                     // reuse point
  bf16*  qkv     = (bf16*) take((size_t)NM * 3 * ND * 2);      // 25.2 MB [dead after attn]
  bf16*  Vt_all  = (bf16*) take((size_t)NH * NS * NS * 2);     // slot 33.5 MB (uses 8.4) [dead after attn]
  bf16*  Vt_old  = (bf16*) take((size_t)NH * NDH * NS * 2);    //  2.1 MB [unused slot, keeps offsets]
  bf16*  ctx     = (bf16*) take((size_t)NM * ND * 2);          //  8.4 MB [dead after step 3]
  bf16*  dense   = (bf16*) take((size_t)NM * ND * 2);          //  8.4 MB
  bf16*  QKs_bf  = (bf16*) take((size_t)NM * 128 * 2);         //  1.05 MB
  bf16*  Vsp     = (bf16*) take((size_t)NM * ND * 2);          //  8.4 MB
  bf16*  sparse  = (bf16*) take((size_t)NM * ND * 2);          //  8.4 MB
  (void)Vt_old;
  // aliases into dead regions (qkv+Vt_all dead after the attention):
  bf16*  x1    = (bf16*)(ws + mark);                                       // [0, 8.4M)
  bf16*  h1    = (bf16*)(ws + mark + (size_t)NM * ND * 2);                 // [8.4, 42.0M)
  bf16*  ffout = (bf16*)(ws + mark + (size_t)NM * ND * 2 + (size_t)NM * NDFF * 2); // [42.0, 50.4M)
  bf16*  aw    = (bf16*)(ws + mark + 2 * (size_t)NM * ND * 2 + (size_t)NM * NDFF * 2); // [50.4, 58.8M)
  float* S_sp  = (float*)(ws + mark + (size_t)NM * ND * 2);    // [8.4, 25.2M): written 4b,
                                                               // read 6a, dead before h1
  bf16*  Vsp_t = (bf16*)ctx;  // ctx dead after step 3

  const dim3 blk(256);
  // 0. fp32 -> bf16 conversions, one fused launch (6 regions, 17408 blocks)
  {
    CastArgs a;
    a.in[0] = src;        a.out[0] = src_bf;  // 4096 blocks
    a.in[1] = in_proj_w;  a.out[1] = w_qkv;   // 3072
    a.in[2] = out_proj_w; a.out[2] = w_out;   // 1024
    a.in[3] = Vp_w;       a.out[3] = w_vp;    // 1024
    a.in[4] = ff1_w;      a.out[4] = w_ff1;   // 4096
    a.in[5] = ff2_w;      a.out[5] = w_ff2;   // 4096
    a.end[0] = 4096; a.end[1] = 7168; a.end[2] = 8192;
    a.end[3] = 9216; a.end[4] = 13312; a.end[5] = 17408;
    cast6_kernel<<<dim3(17408), blk, 0, stream>>>(a);
  }
  pack_qk_kernel<<<dim3(128), blk, 0, stream>>>(Qp_w, Kp_w, Qp_b, Kp_b, w_qk, bias_qk);

  // 1. qkv = src @ in_proj^T + b   [4096,3072] bf16  (768 blocks)
  mfma_gemm<128,128,32,1,0,0><<<dim3(3*ND/128, NM/128, 1), blk, 0, stream>>>(
      src_bf, w_qkv, in_proj_b, qkv, ND, ND, ND, 3*ND, 0,0, 0,0, 0,0, 1.f);

  // 2. dense MHA: V transpose (all batches) + fused flash attention
  transpose_v_kernel<<<dim3(NS/64, NH, NB), blk, 0, stream>>>(qkv, Vt_all);
  attn_kernel<<<dim3(NS/128, NB*NH), blk, 0, stream>>>(qkv, Vt_all, ctx);

  // 3. dense_output = ctx @ out_proj^T + b  (bf16; 128x64xBK64 -> 512 blocks)
  mfma_gemm<128,64,64,1,0,0><<<dim3(ND/64, NM/128, 1), blk, 0, stream>>>(
      ctx, w_out, out_proj_b, dense, ND, ND, ND, ND, 0,0, 0,0, 0,0, 1.f);
  // 4. QKs_bf = src @ [Qp;Kp]^T + b  (bf16 [4096][128]; 64 blocks)
  mfma_gemm<128,64,64,1,0,0><<<dim3(2, NM/128, 1), blk, 0, stream>>>(
      src_bf, w_qk, bias_qk, QKs_bf, ND, ND, ND, 128, 0,0, 0,0, 0,0, 1.f);
  // 4b. S_sp[b] = (Qs Ks^T)/8  fp32, batched over b (single K-tile at BK=64)
  mfma_gemm<128,64,64,0,0,1><<<dim3(NS/64, NS/128, NB), blk, 0, stream>>>(
      QKs_bf, QKs_bf + 64, nullptr, S_sp, 64, 128, 128, NS,
      0, (long long)NS*128, 0, (long long)NS*128, 0, (long long)NS*NS, 0.125f);
  // 5. Vsp = src @ Vp^T + b  (bf16; 512 blocks)
  mfma_gemm<128,64,64,1,0,0><<<dim3(ND/64, NM/128, 1), blk, 0, stream>>>(
      src_bf, w_vp, Vp_b, Vsp, ND, ND, ND, ND, 0,0, 0,0, 0,0, 1.f);
  // 5b. Vsp_t[b][d][s] = Vsp[b][s][d]   (ctx slot reused)
  transpose_sq_kernel<<<dim3(NS/64, ND/64, NB), blk, 0, stream>>>(Vsp, Vsp_t);
  // 6a. top-k select + normalized weights -> aw (bf16), one wave per row
  sparse_select_kernel<<<dim3(NM/4), blk, 0, stream>>>(S_sp, aw);
  // 6b. sparse = aw @ Vsp^T  (batched per b; 512 blocks)
  mfma_gemm<128,64,64,0,0,0><<<dim3(ND/64, NS/128, NB), blk, 0, stream>>>(
      aw, Vsp_t, nullptr, sparse, NS, NS, NS, ND,
      0, (long long)NS*ND, 0, (long long)ND*NS, 0, (long long)NS*ND, 1.f);
  // 7. fuse + residual + LN1 -> x1 (bf16)  [qkv/Vt_all dead; x1 aliases them]
  fuse_ln1_kernel<<<dim3(NM), blk, 0, stream>>>(src, dense, sparse, lam, ln1_g, ln1_b, x1);
  // 8. h1 = relu(x1 @ ff1^T + b)  (bf16; 1024 blocks)
  mfma_gemm<128,128,32,1,1,0><<<dim3(NDFF/128, NM/128, 1), blk, 0, stream>>>(
      x1, w_ff1, ff1_b, h1, ND, ND, ND, NDFF, 0,0, 0,0, 0,0, 1.f);
  // 9. ff = h1 @ ff2^T + b  (bf16; 128x64xBK64 -> 512 blocks)
  mfma_gemm<128,64,64,1,0,0><<<dim3(ND/64, NM/128, 1), blk, 0, stream>>>(
      h1, w_ff2, ff2_b, ffout, NDFF, NDFF, NDFF, ND, 0,0, 0,0, 0,0, 1.f);
  // 10. out = LN2(x1 + ff)  (fp32)
  ln2_kernel<<<dim3(NM), blk, 0, stream>>>(x1, ffout, ln2_g, ln2_b, (float*)d_out);
}

// Round 5
// 436.624 us; speedup vs baseline: 1.2468x; 1.2468x over previous
//
#include <hip/hip_runtime.h>
#include <hip/hip_bf16.h>
#include <math.h>

typedef __hip_bfloat16 bf16;
typedef __attribute__((ext_vector_type(8))) short short8;
typedef __attribute__((ext_vector_type(4))) float f32x4;

// Problem constants
#define NB 4
#define NS 1024
#define ND 1024
#define NH 16
#define NDH 64
#define NR 64
#define NDFF 4096
#define NM (NB*NS)     // 4096 rows
#define NTOPK 204      // int(1024*0.2)

static __device__ __forceinline__ float b2f(bf16 x) { return __bfloat162float(x); }
static __device__ __forceinline__ bf16  f2b(float x) { return __float2bfloat16(x); }
static __device__ __forceinline__ unsigned short bfbits(float x) {
  bf16 h = __float2bfloat16(x);
  return *reinterpret_cast<unsigned short*>(&h);
}

// async global->LDS, 16B per lane; LDS dest = wave-uniform base + lane*16
static __device__ __forceinline__ void gload_lds16(const void* g, void* l) {
  __builtin_amdgcn_global_load_lds(
      (const __attribute__((address_space(1))) void*)g,
      (__attribute__((address_space(3))) void*)l, 16, 0, 0);
}

// counted vmcnt wait (T4): wait own outstanding VMEM ops <= N, leaving the
// newest N (the in-flight prefetch) pending across the following barrier.
template<int N> static __device__ __forceinline__ void vm_wait() {
  if constexpr (N == 0)       asm volatile("s_waitcnt vmcnt(0)" ::: "memory");
  else if constexpr (N == 4)  asm volatile("s_waitcnt vmcnt(4)" ::: "memory");
  else if constexpr (N == 6)  asm volatile("s_waitcnt vmcnt(6)" ::: "memory");
  else if constexpr (N == 8)  asm volatile("s_waitcnt vmcnt(8)" ::: "memory");
  else static_assert(N == 0, "unsupported vmcnt");
}
// raw barrier (no implicit vmcnt drain); memory clobber = compiler fence so
// LDS accesses cannot be moved across it.
static __device__ __forceinline__ void bar() {
  asm volatile("s_barrier" ::: "memory");
}

// 8 consecutive bf16 -> fp32 (one 16B load)
static __device__ __forceinline__ void ld8(const bf16* p, float* d) {
  const uint4 u = *(const uint4*)p;
  d[0] = __uint_as_float((u.x & 0xffffu) << 16);
  d[1] = __uint_as_float(u.x & 0xffff0000u);
  d[2] = __uint_as_float((u.y & 0xffffu) << 16);
  d[3] = __uint_as_float(u.y & 0xffff0000u);
  d[4] = __uint_as_float((u.z & 0xffffu) << 16);
  d[5] = __uint_as_float(u.z & 0xffff0000u);
  d[6] = __uint_as_float((u.w & 0xffffu) << 16);
  d[7] = __uint_as_float(u.w & 0xffff0000u);
}

static __device__ __forceinline__ float block_sum_256(float v, float* rbuf, int tid) {
  rbuf[tid] = v;
  __syncthreads();
  #pragma unroll
  for (int st = 128; st > 0; st >>= 1) {
    if (tid < st) rbuf[tid] += rbuf[tid + st];
    __syncthreads();
  }
  const float r = rbuf[0];
  __syncthreads();
  return r;
}

// ---------------------------------------------------------------------------
// Fused fp32 -> bf16 cast over 6 regions (each a multiple of 1024 elems).
// ---------------------------------------------------------------------------
struct CastArgs {
  const float* in[6];
  bf16* out[6];
  unsigned end[6];   // cumulative block counts
};
__global__ __launch_bounds__(256) void cast6_kernel(CastArgs a) {
  const unsigned b = blockIdx.x;
  int r = 0; unsigned base = 0;
  #pragma unroll
  for (int k = 0; k < 5; ++k)
    if (b >= a.end[k]) { r = k + 1; base = a.end[k]; }
  const float* in = a.in[r];
  bf16* out = a.out[r];
  const unsigned i = ((b - base) * 256 + threadIdx.x) * 4;
  const float4 v = *(const float4*)(in + i);
  uint2 o;
  o.x = (unsigned)bfbits(v.x) | ((unsigned)bfbits(v.y) << 16);
  o.y = (unsigned)bfbits(v.z) | ((unsigned)bfbits(v.w) << 16);
  *(uint2*)(out + i) = o;
}

// Concat Qp_w/Kp_w -> bf16 [128][1024], Qp_b/Kp_b -> fp32 [128]
__global__ __launch_bounds__(256) void pack_qk_kernel(
    const float* __restrict__ Qw, const float* __restrict__ Kw,
    const float* __restrict__ Qb, const float* __restrict__ Kb,
    bf16* __restrict__ w, float* __restrict__ bias) {
  const int r = blockIdx.x;  // 0..127
  const float* srcw = (r < 64) ? (Qw + (size_t)r * ND) : (Kw + (size_t)(r - 64) * ND);
  for (int i = threadIdx.x; i < ND; i += 256) w[(size_t)r * ND + i] = f2b(srcw[i]);
  if (r == 0)
    for (int i = threadIdx.x; i < 128; i += 256)
      bias[i] = (i < 64) ? Qb[i] : Kb[i - 64];
}

// ---------------------------------------------------------------------------
// Generic batched MFMA GEMM: C = scale*(A @ W^T) (+bias), bf16 in.
// R3-proven core: A and B staged via global_load_lds (XOR-slot swizzle on the
// GLOBAL source column, undone at ds_read), double-buffered, counted-vmcnt
// 2-barrier pipeline (never vmcnt(0) in the main loop).
// Epilogue variants (this round):
//   VT=1  : blocks with n0 >= 2*ND write their tile TRANSPOSED into C2 as
//           Vt[b*16+h][d][s] (h=(n-2048)/64, d=(n-2048)%64, s=m%1024) and
//           skip the normal C write — eliminates the transpose_v kernel.
//           4 consecutive-m acc values = 4 consecutive s -> one 8B store.
//   OUTT=1: ALL tiles stored transposed as C[b][n][s] (b=m/1024, s=m%1024),
//           batch stride ND*NS — eliminates the transpose_sq kernel.
// 256 threads = 4 waves in a 2x2 grid; wave tile = (BM/2)x(BN/2).
// Batch z: off = (z>>4)*Hi + (z&15)*Lo.  K multiple of BK.
// XCD-compact swizzle when gridDim.x%8==0 (perf heuristic only).
// ---------------------------------------------------------------------------
template<int BM, int BN, int BK, int BIAS, int RELU, int OUTF32, int OUTT, int VT>
__global__ __launch_bounds__(256) void mfma_gemm(
    const bf16* __restrict__ A, const bf16* __restrict__ W,
    const float* __restrict__ bias, void* __restrict__ C,
    int K, int lda, int ldb, int ldc,
    long long aHi, long long aLo, long long bHi, long long bLo,
    long long cHi, long long cLo, float scale, bf16* __restrict__ C2)
{
  constexpr int WTM = BM / 2;
  constexpr int WTN = BN / 2;
  constexpr int AM = WTM / 16;
  constexpr int AN = WTN / 16;
  constexpr int KK = BK / 32;        // MFMA sub-steps per K-tile
  constexpr int SLOTS = BK / 8;      // 16B slots per LDS row
  constexpr int RPC = 512 / BK;      // rows per wave per gload_lds16 call
  constexpr int LPW = (BM * BK) / 2048 + (BN * BK) / 2048;  // loads/wave/stage
  __shared__ short As[2][BM * BK];
  __shared__ short Bs[2][BN * BK];
  const int tid  = threadIdx.x;
  const int lane = tid & 63;
  const int w    = tid >> 6;
  const int z    = blockIdx.z;
  const long long aOff = (long long)(z >> 4) * aHi + (long long)(z & 15) * aLo;
  const long long bOff = (long long)(z >> 4) * bHi + (long long)(z & 15) * bLo;
  const long long cOff = (long long)(z >> 4) * cHi + (long long)(z & 15) * cLo;

  int bx = blockIdx.x, by = blockIdx.y;
  if ((gridDim.x & 7) == 0) {
    const unsigned lin = blockIdx.y * gridDim.x + blockIdx.x;
    const unsigned Wd = gridDim.x >> 3;
    const unsigned xcd = lin & 7, i = lin >> 3;
    bx = (int)(xcd * Wd + (i % Wd));
    by = (int)(i / Wd);
  }
  const int m0 = by * BM;
  const int n0 = bx * BN;
  const int wr = w >> 1, wc = w & 1;
  const int lm = lane & 15, quad = lane >> 4;

  f32x4 acc[AM][AN];
  #pragma unroll
  for (int i = 0; i < AM; ++i)
    #pragma unroll
    for (int j = 0; j < AN; ++j) acc[i][j] = (f32x4){0.f, 0.f, 0.f, 0.f};

  // staging lane map + slot swizzle (write side, applied to GLOBAL source col)
  const int slot = lane & (SLOTS - 1);
  const int sr   = lane / SLOTS;     // row within this wave's RPC-row chunk
  const int swz  = (BK == 32) ? ((sr >> 1) & 3) : (sr & 7);
  const int scol = (slot ^ swz) << 3;  // shorts
  // read-side swizzle (row == lm mod 16; chunk bases are slot-period aligned)
  const int xv   = (BK == 32) ? ((lm >> 1) & 3) : (lm & 7);
  const bf16* Ab = A + aOff;
  const bf16* Bb = W + bOff;

  auto stage = [&](int buf, int k0) {
    #pragma unroll
    for (int t = 0; t < (BM * BK) / 2048; ++t) {
      const int row = w * (BM / 4) + t * RPC;
      gload_lds16(Ab + (long long)(m0 + row + sr) * lda + k0 + scol, &As[buf][row * BK]);
    }
    #pragma unroll
    for (int t = 0; t < (BN * BK) / 2048; ++t) {
      const int row = w * (BN / 4) + t * RPC;
      gload_lds16(Bb + (long long)(n0 + row + sr) * ldb + k0 + scol, &Bs[buf][row * BK]);
    }
  };
  auto compute = [&](int buf) {
    #pragma unroll
    for (int kk = 0; kk < KK; ++kk) {
      const int cb = ((kk * 4 + quad) ^ xv) << 3;   // swizzled 16B slot, shorts
      short8 af[AM], bfr[AN];
      #pragma unroll
      for (int i = 0; i < AM; ++i)
        af[i] = *(const short8*)&As[buf][(wr * WTM + i * 16 + lm) * BK + cb];
      #pragma unroll
      for (int j = 0; j < AN; ++j)
        bfr[j] = *(const short8*)&Bs[buf][(wc * WTN + j * 16 + lm) * BK + cb];
      #pragma unroll
      for (int i = 0; i < AM; ++i)
        #pragma unroll
        for (int j = 0; j < AN; ++j)
          acc[i][j] = __builtin_amdgcn_mfma_f32_16x16x32_bf16(af[i], bfr[j], acc[i][j], 0, 0, 0);
    }
  };

  stage(0, 0);
  int cur = 0;
  for (int k0 = BK; k0 < K; k0 += BK) {
    stage(cur ^ 1, k0);          // prefetch into idle buffer (stays in flight)
    vm_wait<LPW>();              // only the PREVIOUS stage's loads must land
    bar();                       // publish them to all waves
    compute(cur);
    bar();                       // all waves done reading cur before overwrite
    cur ^= 1;
  }
  vm_wait<0>();                  // last tile's loads
  bar();
  compute(cur);

  #pragma unroll
  for (int i = 0; i < AM; ++i) {
    #pragma unroll
    for (int j = 0; j < AN; ++j) {
      const int n = n0 + wc * WTN + j * 16 + lm;
      const float bj = BIAS ? bias[n] : 0.f;
      float v0 = acc[i][j][0] * scale + bj;
      float v1 = acc[i][j][1] * scale + bj;
      float v2 = acc[i][j][2] * scale + bj;
      float v3 = acc[i][j][3] * scale + bj;
      if (RELU) {
        v0 = fmaxf(v0, 0.f); v1 = fmaxf(v1, 0.f);
        v2 = fmaxf(v2, 0.f); v3 = fmaxf(v3, 0.f);
      }
      const int mm = m0 + wr * WTM + i * 16 + quad * 4;
      if (VT && n0 >= 2 * ND) {
        // transposed V store: Vt[(b*16+h)][d][s], 4 consecutive s -> 8B
        const int h = (n - 2 * ND) >> 6, d = (n - 2 * ND) & 63;
        uint2 u;
        u.x = (unsigned)bfbits(v0) | ((unsigned)bfbits(v1) << 16);
        u.y = (unsigned)bfbits(v2) | ((unsigned)bfbits(v3) << 16);
        bf16* dst = C2 + (long long)((mm >> 10) * NH + h) * (NDH * NS)
                       + (long long)d * NS + (mm & 1023);
        *(uint2*)dst = u;
      } else if (OUTT) {
        // transposed store: C[b][n][s], batch stride ND*NS
        uint2 u;
        u.x = (unsigned)bfbits(v0) | ((unsigned)bfbits(v1) << 16);
        u.y = (unsigned)bfbits(v2) | ((unsigned)bfbits(v3) << 16);
        bf16* dst = (bf16*)C + cOff + (long long)(mm >> 10) * ((long long)ND * NS)
                       + (long long)n * NS + (mm & 1023);
        *(uint2*)dst = u;
      } else {
        const float vv[4] = {v0, v1, v2, v3};
        #pragma unroll
        for (int rr = 0; rr < 4; ++rr) {
          const long long co = cOff + (long long)(mm + rr) * ldc + n;
          if (OUTF32) ((float*)C)[co] = vv[rr];
          else        ((bf16*)C)[co] = f2b(vv[rr]);
        }
      }
    }
  }
}

// ---------------------------------------------------------------------------
// Fused flash attention (dense MHA): per (q-tile of 128, b, h) block.
// Swapped QK^T -> S^T frags (q = lane&15); online softmax via 2 shfl_xor;
// P^T bf16 B-frags built in-register via shfl. K/V^T staged via
// global_load_lds + XOR slot swizzle; counted-vmcnt 2-barrier pipeline.
// grid (NS/128, NB*NH), 256 threads.
// ---------------------------------------------------------------------------
__global__ __launch_bounds__(256) void attn_kernel(
    const bf16* __restrict__ qkv,   // [B][S][3*ND]
    const bf16* __restrict__ Vt,    // [B*H][NDH][NS]
    bf16* __restrict__ ctx)         // [B][S][ND]
{
  __shared__ short smem[2][2][64 * 64];   // [buf][K|V][4096] = 32 KB
  const int tid = threadIdx.x, lane = tid & 63, w = tid >> 6;
  const int lm = lane & 15, quad = lane >> 4;
  const int z = blockIdx.y, b = z >> 4, h = z & 15;
  const int q0 = blockIdx.x * 128;
  const bf16* Qb = qkv + (long long)b * NS * 3072 + h * 64;
  const bf16* Kb = Qb + ND;
  const bf16* Vb = Vt + (long long)z * (NDH * NS);

  // Q B-frags [j][kk]: col q = q0 + w*32 + j*16 + lm, k(d) = kk*32 + quad*8 + e
  short8 qf[2][2];
  #pragma unroll
  for (int j = 0; j < 2; ++j)
    #pragma unroll
    for (int kk = 0; kk < 2; ++kk)
      qf[j][kk] = *(const short8*)(Qb + (long long)(q0 + w * 32 + j * 16 + lm) * 3072
                                      + kk * 32 + quad * 8);

  // staging map (8 slots of 16B per 64-elem row; 8 rows per issue per wave)
  const int slot = lane & 7, sr = lane >> 3;
  const int scol = (slot ^ sr) << 3;      // shorts; involution with read side

  auto stage = [&](int buf, int t) {
    #pragma unroll
    for (int u = 0; u < 2; ++u) {
      const int row = w * 16 + u * 8;     // kv row within tile
      gload_lds16(Kb + (long long)(t * 64 + row + sr) * 3072 + scol,
                  &smem[buf][0][row * 64]);
    }
    #pragma unroll
    for (int u = 0; u < 2; ++u) {
      const int row = w * 16 + u * 8;     // d row
      gload_lds16(Vb + (long long)(row + sr) * NS + t * 64 + scol,
                  &smem[buf][1][row * 64]);
    }
  };

  f32x4 o[4][2];                          // O^T: d-tile i, q-tile j
  #pragma unroll
  for (int i = 0; i < 4; ++i)
    #pragma unroll
    for (int j = 0; j < 2; ++j) o[i][j] = (f32x4){0.f, 0.f, 0.f, 0.f};
  float m[2] = {-1e30f, -1e30f}, l[2] = {0.f, 0.f};

  stage(0, 0);
  for (int t = 0; t < 16; ++t) {
    const int buf = t & 1;
    if (t < 15) { stage(buf ^ 1, t + 1); vm_wait<4>(); }
    else        { vm_wait<0>(); }
    bar();                                // tile t's loads visible to all

    // --- S^T = (K @ Q^T)/8 : st[i][j], i = kv-tile, j = q-tile
    f32x4 st[4][2];
    #pragma unroll
    for (int i = 0; i < 4; ++i)
      #pragma unroll
      for (int j = 0; j < 2; ++j) st[i][j] = (f32x4){0.f, 0.f, 0.f, 0.f};
    #pragma unroll
    for (int kk = 0; kk < 2; ++kk) {
      const int cb = ((kk * 4 + quad) ^ (lm & 7)) << 3;
      short8 ka[4];
      #pragma unroll
      for (int i = 0; i < 4; ++i)
        ka[i] = *(const short8*)&smem[buf][0][(i * 16 + lm) * 64 + cb];
      #pragma unroll
      for (int i = 0; i < 4; ++i)
        #pragma unroll
        for (int j = 0; j < 2; ++j)
          st[i][j] = __builtin_amdgcn_mfma_f32_16x16x32_bf16(ka[i], qf[j][kk], st[i][j], 0, 0, 0);
    }

    // --- online softmax per q-col (j); kv spread over 16 regs x 4 quads
    #pragma unroll
    for (int j = 0; j < 2; ++j) {
      float pm = -1e30f;
      #pragma unroll
      for (int i = 0; i < 4; ++i)
        #pragma unroll
        for (int r = 0; r < 4; ++r) {
          st[i][j][r] *= 0.125f;
          pm = fmaxf(pm, st[i][j][r]);
        }
      pm = fmaxf(pm, __shfl_xor(pm, 16, 64));
      pm = fmaxf(pm, __shfl_xor(pm, 32, 64));
      const float mn = fmaxf(m[j], pm);
      const float sc = __expf(m[j] - mn);
      float ps = 0.f;
      #pragma unroll
      for (int i = 0; i < 4; ++i)
        #pragma unroll
        for (int r = 0; r < 4; ++r) {
          const float e = __expf(st[i][j][r] - mn);
          st[i][j][r] = e;                 // st now holds P^T
          ps += e;
        }
      ps += __shfl_xor(ps, 16, 64);
      ps += __shfl_xor(ps, 32, 64);
      l[j] = l[j] * sc + ps;
      m[j] = mn;
      #pragma unroll
      for (int i = 0; i < 4; ++i)
        #pragma unroll
        for (int r = 0; r < 4; ++r) o[i][j][r] *= sc;
    }

    // --- pack P^T to bf16 pairs: u0 = (r0,r1), u1 = (r2,r3)
    unsigned u0[4][2], u1[4][2];
    #pragma unroll
    for (int i = 0; i < 4; ++i)
      #pragma unroll
      for (int j = 0; j < 2; ++j) {
        u0[i][j] = (unsigned)bfbits(st[i][j][0]) | ((unsigned)bfbits(st[i][j][1]) << 16);
        u1[i][j] = (unsigned)bfbits(st[i][j][2]) | ((unsigned)bfbits(st[i][j][3]) << 16);
      }
    // target frag (kk,j) elem e: kv = kk*32+quad*8+e comes from
    //   i_src = kk*2 + (quad>>1), src lane = ((quad&1)*2 + (e>>2))*16 + lm, r = e&3
    const int s0l = ((quad & 1) * 2) * 16 + lm;
    const int s1l = s0l + 16;
    const bool hi = (quad >> 1) != 0;

    // --- O^T += V^T @ P^T
    #pragma unroll
    for (int kk = 0; kk < 2; ++kk) {
      short8 pf[2];
      #pragma unroll
      for (int j = 0; j < 2; ++j) {
        const unsigned a0 = __shfl(u0[kk * 2][j],     s0l, 64);
        const unsigned a1 = __shfl(u1[kk * 2][j],     s0l, 64);
        const unsigned b0 = __shfl(u0[kk * 2 + 1][j], s0l, 64);
        const unsigned b1 = __shfl(u1[kk * 2 + 1][j], s0l, 64);
        const unsigned c0 = __shfl(u0[kk * 2][j],     s1l, 64);
        const unsigned c1 = __shfl(u1[kk * 2][j],     s1l, 64);
        const unsigned d0 = __shfl(u0[kk * 2 + 1][j], s1l, 64);
        const unsigned d1 = __shfl(u1[kk * 2 + 1][j], s1l, 64);
        union { uint4 u; short8 s; } cv;
        cv.u.x = hi ? b0 : a0; cv.u.y = hi ? b1 : a1;
        cv.u.z = hi ? d0 : c0; cv.u.w = hi ? d1 : c1;
        pf[j] = cv.s;
      }
      const int cb = ((kk * 4 + quad) ^ (lm & 7)) << 3;
      short8 va[4];
      #pragma unroll
      for (int i = 0; i < 4; ++i)
        va[i] = *(const short8*)&smem[buf][1][(i * 16 + lm) * 64 + cb];
      #pragma unroll
      for (int i = 0; i < 4; ++i)
        #pragma unroll
        for (int j = 0; j < 2; ++j)
          o[i][j] = __builtin_amdgcn_mfma_f32_16x16x32_bf16(va[i], pf[j], o[i][j], 0, 0, 0);
    }
    bar();   // all waves done reading buf before next overwrite / epilogue
  }

  // --- epilogue: normalize, transpose O^T -> O through LDS, coalesced store
  short (*OL)[72] = (short(*)[72])&smem[0][0][0];   // 128 x 72 = 18.4 KB
  #pragma unroll
  for (int j = 0; j < 2; ++j) {
    const float inv = 1.f / l[j];
    #pragma unroll
    for (int i = 0; i < 4; ++i) {
      uint2 u;
      u.x = (unsigned)bfbits(o[i][j][0] * inv) | ((unsigned)bfbits(o[i][j][1] * inv) << 16);
      u.y = (unsigned)bfbits(o[i][j][2] * inv) | ((unsigned)bfbits(o[i][j][3] * inv) << 16);
      *(uint2*)&OL[w * 32 + j * 16 + lm][i * 16 + quad * 4] = u;
    }
  }
  __syncthreads();
  {
    const int q = tid >> 1, c = (tid & 1) * 32;
    const uint4 r0 = *(const uint4*)&OL[q][c];
    const uint4 r1 = *(const uint4*)&OL[q][c + 8];
    const uint4 r2 = *(const uint4*)&OL[q][c + 16];
    const uint4 r3 = *(const uint4*)&OL[q][c + 24];
    bf16* dst = ctx + ((long long)(b * NS + q0 + q)) * 1024 + h * 64 + c;
    ((uint4*)dst)[0] = r0; ((uint4*)dst)[1] = r1;
    ((uint4*)dst)[2] = r2; ((uint4*)dst)[3] = r3;
  }
}

// ---------------------------------------------------------------------------
// Sparse top-k selection from precomputed fp32 scores S[row][1024].
// One WAVE per row (4 rows/block); wave-local radix select.
// ---------------------------------------------------------------------------
__global__ __launch_bounds__(256) void sparse_select_kernel(
    const float* __restrict__ S, bf16* __restrict__ aw)
{
  __shared__ unsigned hist[4][256];
  const int tid = threadIdx.x;
  const int lane = tid & 63;
  const int wv = tid >> 6;
  const long long row = (long long)blockIdx.x * 4 + wv;

  float sv[16];
  const float* sp = S + row * 1024 + lane * 16;
  #pragma unroll
  for (int c = 0; c < 4; ++c) {
    const float4 v = ((const float4*)sp)[c];
    sv[4*c] = v.x; sv[4*c+1] = v.y; sv[4*c+2] = v.z; sv[4*c+3] = v.w;
  }
  unsigned key[16];
  #pragma unroll
  for (int j = 0; j < 16; ++j) {
    const unsigned u = __float_as_uint(sv[j]);
    key[j] = (u & 0x80000000u) ? ~u : (u | 0x80000000u);  // order-preserving
  }

  unsigned pref = 0u;
  int need = NTOPK;
  #pragma unroll
  for (int p = 3; p >= 0; --p) {
    *(uint4*)&hist[wv][lane * 4] = (uint4){0u, 0u, 0u, 0u};
    __syncthreads();
    const int sh = (p + 1) * 8;
    #pragma unroll
    for (int j = 0; j < 16; ++j) {
      const bool part = (p == 3) || ((key[j] >> sh) == pref);
      if (part) atomicAdd(&hist[wv][(key[j] >> (p * 8)) & 255u], 1u);
    }
    __syncthreads();
    const unsigned h0 = hist[wv][4*lane],     h1 = hist[wv][4*lane + 1];
    const unsigned h2 = hist[wv][4*lane + 2], h3 = hist[wv][4*lane + 3];
    const unsigned s3 = h3, s2 = h2 + s3, s1 = h1 + s2, s0 = h0 + s1;
    unsigned sum = s0;                      // suffix sum over lanes >= lane
    #pragma unroll
    for (int d2 = 1; d2 < 64; d2 <<= 1) {
      const unsigned t = __shfl_down(sum, d2, 64);
      if (lane < 64 - d2) sum += t;
    }
    const unsigned above = sum - s0;
    const unsigned cum[4]  = {above + s0, above + s1, above + s2, above + s3};
    const unsigned next[4] = {above + s1, above + s2, above + s3, above};
    unsigned candPref = 0u; int candNeed = 0; bool has = false;
    #pragma unroll
    for (int i = 0; i < 4; ++i) {
      if ((int)cum[i] >= need && (int)next[i] < need) {
        has = true;
        candPref = (pref << 8) | (unsigned)(4 * lane + i);
        candNeed = need - (int)next[i];
      }
    }
    const unsigned long long m = __ballot(has);
    const int srcLane = (int)(__ffsll((long long)m) - 1);
    pref = (unsigned)__shfl((int)candPref, srcLane, 64);
    need = __shfl(candNeed, srcLane, 64);
  }

  const unsigned T = pref;                  // 204th-largest key
  const unsigned tb = (T & 0x80000000u) ? (T ^ 0x80000000u) : ~T;
  const float thr = __uint_as_float(tb);

  float wvv[16];
  float psTop = 0.f, psAll = 0.f;
  #pragma unroll
  for (int j = 0; j < 16; ++j) {
    const float e = __expf(sv[j] - thr);
    psAll += e;
    const float wt = (key[j] >= T) ? e : 0.f;
    psTop += wt;
    wvv[j] = wt;
  }
  #pragma unroll
  for (int s = 1; s < 64; s <<= 1) {
    psTop += __shfl_xor(psTop, s, 64);
    psAll += __shfl_xor(psAll, s, 64);
  }
  const float inv = 1.f / (psTop + 1e-9f * psAll);

  uint4 o0, o1;
  o0.x = (unsigned)bfbits(wvv[0]*inv)  | ((unsigned)bfbits(wvv[1]*inv)  << 16);
  o0.y = (unsigned)bfbits(wvv[2]*inv)  | ((unsigned)bfbits(wvv[3]*inv)  << 16);
  o0.z = (unsigned)bfbits(wvv[4]*inv)  | ((unsigned)bfbits(wvv[5]*inv)  << 16);
  o0.w = (unsigned)bfbits(wvv[6]*inv)  | ((unsigned)bfbits(wvv[7]*inv)  << 16);
  o1.x = (unsigned)bfbits(wvv[8]*inv)  | ((unsigned)bfbits(wvv[9]*inv)  << 16);
  o1.y = (unsigned)bfbits(wvv[10]*inv) | ((unsigned)bfbits(wvv[11]*inv) << 16);
  o1.z = (unsigned)bfbits(wvv[12]*inv) | ((unsigned)bfbits(wvv[13]*inv) << 16);
  o1.w = (unsigned)bfbits(wvv[14]*inv) | ((unsigned)bfbits(wvv[15]*inv) << 16);
  bf16* op = aw + row * 1024 + lane * 16;
  ((uint4*)op)[0] = o0; ((uint4*)op)[1] = o1;
}

// ---------------------------------------------------------------------------
// fused = sig*dense + (1-sig)*sparse ; x1 = LN1(src + fused)  (bf16 out)
// ---------------------------------------------------------------------------
__global__ __launch_bounds__(256) void fuse_ln1_kernel(
    const float* __restrict__ src, const bf16* __restrict__ dense,
    const bf16* __restrict__ sparse, const float* __restrict__ lam,
    const float* __restrict__ g, const float* __restrict__ beta,
    bf16* __restrict__ x1)
{
  __shared__ float y[ND];
  __shared__ float rbuf[256];
  const int tid = threadIdx.x;
  const size_t base = (size_t)blockIdx.x * ND;
  const float sig = 1.f / (1.f + __expf(-lam[0]));
  const float c1 = 1.f - sig;
  float s1 = 0.f, s2 = 0.f;
  #pragma unroll
  for (int j = 0; j < 4; ++j) {
    const int i = tid + (j << 8);
    const float v = src[base + i] + sig * b2f(dense[base + i]) + c1 * b2f(sparse[base + i]);
    y[i] = v; s1 += v; s2 += v * v;
  }
  const float sum1 = block_sum_256(s1, rbuf, tid);
  const float sum2 = block_sum_256(s2, rbuf, tid);
  const float mean = sum1 * (1.f / ND);
  const float var  = sum2 * (1.f / ND) - mean * mean;
  const float rstd = rsqrtf(var + 1e-5f);
  #pragma unroll
  for (int j = 0; j < 4; ++j) {
    const int i = tid + (j << 8);
    x1[base + i] = f2b((y[i] - mean) * rstd * g[i] + beta[i]);
  }
}

// out = LN2(x1 + ff)  (fp32 out; ff is bf16)
__global__ __launch_bounds__(256) void ln2_kernel(
    const bf16* __restrict__ x1, const bf16* __restrict__ ff,
    const float* __restrict__ g, const float* __restrict__ beta,
    float* __restrict__ outp)
{
  __shared__ float y[ND];
  __shared__ float rbuf[256];
  const int tid = threadIdx.x;
  const size_t base = (size_t)blockIdx.x * ND;
  float s1 = 0.f, s2 = 0.f;
  #pragma unroll
  for (int j = 0; j < 4; ++j) {
    const int i = tid + (j << 8);
    const float v = b2f(x1[base + i]) + b2f(ff[base + i]);
    y[i] = v; s1 += v; s2 += v * v;
  }
  const float sum1 = block_sum_256(s1, rbuf, tid);
  const float sum2 = block_sum_256(s2, rbuf, tid);
  const float mean = sum1 * (1.f / ND);
  const float var  = sum2 * (1.f / ND) - mean * mean;
  const float rstd = rsqrtf(var + 1e-5f);
  #pragma unroll
  for (int j = 0; j < 4; ++j) {
    const int i = tid + (j << 8);
    outp[base + i] = (y[i] - mean) * rstd * g[i] + beta[i];
  }
}

// ---------------------------------------------------------------------------
extern "C" void kernel_launch(void* const* d_in, const int* in_sizes, int n_in,
                              void* d_out, int out_size, void* d_ws, size_t ws_size,
                              hipStream_t stream)
{
  const float* src        = (const float*)d_in[0];
  const float* in_proj_w  = (const float*)d_in[1];
  const float* in_proj_b  = (const float*)d_in[2];
  const float* out_proj_w = (const float*)d_in[3];
  const float* out_proj_b = (const float*)d_in[4];
  const float* Qp_w  = (const float*)d_in[5];
  const float* Qp_b  = (const float*)d_in[6];
  const float* Kp_w  = (const float*)d_in[7];
  const float* Kp_b  = (const float*)d_in[8];
  const float* Vp_w  = (const float*)d_in[9];
  const float* Vp_b  = (const float*)d_in[10];
  const float* lam   = (const float*)d_in[11];
  const float* ff1_w = (const float*)d_in[12];
  const float* ff1_b = (const float*)d_in[13];
  const float* ff2_w = (const float*)d_in[14];
  const float* ff2_b = (const float*)d_in[15];
  const float* ln1_g = (const float*)d_in[16];
  const float* ln1_b = (const float*)d_in[17];
  const float* ln2_g = (const float*)d_in[18];
  const float* ln2_b = (const float*)d_in[19];
  (void)in_sizes; (void)n_in; (void)out_size; (void)ws_size;

  // --------- workspace layout (offsets IDENTICAL to the proven layout;
  // Vt_all reuses the old S_b slot)
  char* ws = (char*)d_ws;
  size_t off = 0;
  auto take = [&](size_t bytes) -> void* {
    void* p = ws + off; off += (bytes + 255) & ~(size_t)255; return p;
  };
  bf16*  src_bf  = (bf16*) take((size_t)NM * ND * 2);          //  8.4 MB
  bf16*  w_qkv   = (bf16*) take((size_t)3 * ND * ND * 2);      //  6.3 MB
  bf16*  w_out   = (bf16*) take((size_t)ND * ND * 2);          //  2.1 MB
  bf16*  w_vp    = (bf16*) take((size_t)ND * ND * 2);          //  2.1 MB
  bf16*  w_ff1   = (bf16*) take((size_t)NDFF * ND * 2);        //  8.4 MB
  bf16*  w_ff2   = (bf16*) take((size_t)ND * NDFF * 2);        //  8.4 MB
  bf16*  w_qk    = (bf16*) take((size_t)128 * ND * 2);         //  0.26 MB
  float* bias_qk = (float*)take(128 * 4);
  const size_t mark = off;                                     // reuse point
  bf16*  qkv     = (bf16*) take((size_t)NM * 3 * ND * 2);      // 25.2 MB [dead after attn]
  bf16*  Vt_all  = (bf16*) take((size_t)NH * NS * NS * 2);     // slot 33.5 MB (uses 8.4) [dead after attn]
  bf16*  Vt_old  = (bf16*) take((size_t)NH * NDH * NS * 2);    //  2.1 MB [unused slot, keeps offsets]
  bf16*  ctx     = (bf16*) take((size_t)NM * ND * 2);          //  8.4 MB [dead after step 3]
  bf16*  dense   = (bf16*) take((size_t)NM * ND * 2);          //  8.4 MB
  bf16*  QKs_bf  = (bf16*) take((size_t)NM * 128 * 2);         //  1.05 MB
  bf16*  Vsp     = (bf16*) take((size_t)NM * ND * 2);          //  8.4 MB [unused slot now]
  bf16*  sparse  = (bf16*) take((size_t)NM * ND * 2);          //  8.4 MB
  (void)Vt_old; (void)Vsp;
  // aliases into dead regions (qkv+Vt_all dead after the attention):
  bf16*  x1    = (bf16*)(ws + mark);                                       // [0, 8.4M)
  bf16*  h1    = (bf16*)(ws + mark + (size_t)NM * ND * 2);                 // [8.4, 42.0M)
  bf16*  ffout = (bf16*)(ws + mark + (size_t)NM * ND * 2 + (size_t)NM * NDFF * 2); // [42.0, 50.4M)
  bf16*  aw    = (bf16*)(ws + mark + 2 * (size_t)NM * ND * 2 + (size_t)NM * NDFF * 2); // [50.4, 58.8M)
  float* S_sp  = (float*)(ws + mark + (size_t)NM * ND * 2);    // [8.4, 25.2M): written 4b,
                                                               // read 6a, dead before h1
  bf16*  Vsp_t = (bf16*)ctx;  // ctx dead after step 3; written directly by step 5 (OUTT)

  const dim3 blk(256);
  bf16* const NOC2 = nullptr;
  // 0. fp32 -> bf16 conversions, one fused launch (6 regions, 17408 blocks)
  {
    CastArgs a;
    a.in[0] = src;        a.out[0] = src_bf;  // 4096 blocks
    a.in[1] = in_proj_w;  a.out[1] = w_qkv;   // 3072
    a.in[2] = out_proj_w; a.out[2] = w_out;   // 1024
    a.in[3] = Vp_w;       a.out[3] = w_vp;    // 1024
    a.in[4] = ff1_w;      a.out[4] = w_ff1;   // 4096
    a.in[5] = ff2_w;      a.out[5] = w_ff2;   // 4096
    a.end[0] = 4096; a.end[1] = 7168; a.end[2] = 8192;
    a.end[3] = 9216; a.end[4] = 13312; a.end[5] = 17408;
    cast6_kernel<<<dim3(17408), blk, 0, stream>>>(a);
  }
  pack_qk_kernel<<<dim3(128), blk, 0, stream>>>(Qp_w, Kp_w, Qp_b, Kp_b, w_qk, bias_qk);

  // 1. qkv = src @ in_proj^T + b  [4096,3072] bf16; V third written DIRECTLY
  //    TRANSPOSED into Vt_all (VT=1) — replaces the transpose_v kernel.
  mfma_gemm<128,128,32,1,0,0,0,1><<<dim3(3*ND/128, NM/128, 1), blk, 0, stream>>>(
      src_bf, w_qkv, in_proj_b, qkv, ND, ND, ND, 3*ND, 0,0, 0,0, 0,0, 1.f, Vt_all);

  // 2. dense MHA: fused flash attention (Vt_all already populated by step 1)
  attn_kernel<<<dim3(NS/128, NB*NH), blk, 0, stream>>>(qkv, Vt_all, ctx);

  // 3. dense_output = ctx @ out_proj^T + b  (bf16; 128x64xBK64 -> 512 blocks)
  mfma_gemm<128,64,64,1,0,0,0,0><<<dim3(ND/64, NM/128, 1), blk, 0, stream>>>(
      ctx, w_out, out_proj_b, dense, ND, ND, ND, ND, 0,0, 0,0, 0,0, 1.f, NOC2);
  // 4. QKs_bf = src @ [Qp;Kp]^T + b  (bf16 [4096][128]; 64 blocks)
  mfma_gemm<128,64,64,1,0,0,0,0><<<dim3(2, NM/128, 1), blk, 0, stream>>>(
      src_bf, w_qk, bias_qk, QKs_bf, ND, ND, ND, 128, 0,0, 0,0, 0,0, 1.f, NOC2);
  // 4b. S_sp[b] = (Qs Ks^T)/8  fp32, batched over b (single K-tile at BK=64)
  mfma_gemm<128,64,64,0,0,1,0,0><<<dim3(NS/64, NS/128, NB), blk, 0, stream>>>(
      QKs_bf, QKs_bf + 64, nullptr, S_sp, 64, 128, 128, NS,
      0, (long long)NS*128, 0, (long long)NS*128, 0, (long long)NS*NS, 0.125f, NOC2);
  // 5. Vsp_t[b][d][s] = (src @ Vp^T + b)^T — stored DIRECTLY TRANSPOSED
  //    (OUTT=1) into the ctx slot — replaces Vsp + the transpose_sq kernel.
  mfma_gemm<128,64,64,1,0,0,1,0><<<dim3(ND/64, NM/128, 1), blk, 0, stream>>>(
      src_bf, w_vp, Vp_b, Vsp_t, ND, ND, ND, NS, 0,0, 0,0, 0,0, 1.f, NOC2);
  // 6a. top-k select + normalized weights -> aw (bf16), one wave per row
  sparse_select_kernel<<<dim3(NM/4), blk, 0, stream>>>(S_sp, aw);
  // 6b. sparse = aw @ Vsp^T  (batched per b; 512 blocks)
  mfma_gemm<128,64,64,0,0,0,0,0><<<dim3(ND/64, NS/128, NB), blk, 0, stream>>>(
      aw, Vsp_t, nullptr, sparse, NS, NS, NS, ND,
      0, (long long)NS*ND, 0, (long long)ND*NS, 0, (long long)NS*ND, 1.f, NOC2);
  // 7. fuse + residual + LN1 -> x1 (bf16)  [qkv/Vt_all dead; x1 aliases them]
  fuse_ln1_kernel<<<dim3(NM), blk, 0, stream>>>(src, dense, sparse, lam, ln1_g, ln1_b, x1);
  // 8. h1 = relu(x1 @ ff1^T + b)  (bf16; 1024 blocks)
  mfma_gemm<128,128,32,1,1,0,0,0><<<dim3(NDFF/128, NM/128, 1), blk, 0, stream>>>(
      x1, w_ff1, ff1_b, h1, ND, ND, ND, NDFF, 0,0, 0,0, 0,0, 1.f, NOC2);
  // 9. ff = h1 @ ff2^T + b  (bf16; 128x64xBK64 -> 512 blocks)
  mfma_gemm<128,64,64,1,0,0,0,0><<<dim3(ND/64, NM/128, 1), blk, 0, stream>>>(
      h1, w_ff2, ff2_b, ffout, NDFF, NDFF, NDFF, ND, 0,0, 0,0, 0,0, 1.f, NOC2);
  // 10. out = LN2(x1 + ff)  (fp32)
  ln2_kernel<<<dim3(NM), blk, 0, stream>>>(x1, ffout, ln2_g, ln2_b, (float*)d_out);
}

// Round 6
// 424.302 us; speedup vs baseline: 1.2830x; 1.0290x over previous
//
#include <hip/hip_runtime.h>
#include <hip/hip_bf16.h>
#include <math.h>
#include <type_traits>

typedef __hip_bfloat16 bf16;
typedef __attribute__((ext_vector_type(8))) short short8;
typedef __attribute__((ext_vector_type(4))) float f32x4;

// Problem constants
#define NB 4
#define NS 1024
#define ND 1024
#define NH 16
#define NDH 64
#define NR 64
#define NDFF 4096
#define NM (NB*NS)     // 4096 rows
#define NTOPK 204      // int(1024*0.2)

static __device__ __forceinline__ float b2f(bf16 x) { return __bfloat162float(x); }
static __device__ __forceinline__ bf16  f2b(float x) { return __float2bfloat16(x); }
static __device__ __forceinline__ unsigned short bfbits(float x) {
  bf16 h = __float2bfloat16(x);
  return *reinterpret_cast<unsigned short*>(&h);
}

// async global->LDS, 16B per lane; LDS dest = wave-uniform base + lane*16
static __device__ __forceinline__ void gload_lds16(const void* g, void* l) {
  __builtin_amdgcn_global_load_lds(
      (const __attribute__((address_space(1))) void*)g,
      (__attribute__((address_space(3))) void*)l, 16, 0, 0);
}

// counted vmcnt wait (T4): wait own outstanding VMEM ops <= N, leaving the
// newest N (the in-flight prefetch) pending across the following barrier.
template<int N> static __device__ __forceinline__ void vm_wait() {
  if constexpr (N == 0)       asm volatile("s_waitcnt vmcnt(0)" ::: "memory");
  else if constexpr (N == 2)  asm volatile("s_waitcnt vmcnt(2)" ::: "memory");
  else if constexpr (N == 4)  asm volatile("s_waitcnt vmcnt(4)" ::: "memory");
  else if constexpr (N == 6)  asm volatile("s_waitcnt vmcnt(6)" ::: "memory");
  else if constexpr (N == 8)  asm volatile("s_waitcnt vmcnt(8)" ::: "memory");
  else static_assert(N == 0, "unsupported vmcnt");
}
// raw barrier (no implicit vmcnt drain); memory clobber = compiler fence so
// LDS accesses cannot be moved across it.
static __device__ __forceinline__ void bar() {
  asm volatile("s_barrier" ::: "memory");
}

// 8 consecutive bf16 -> fp32 (one 16B load)
static __device__ __forceinline__ void ld8(const bf16* p, float* d) {
  const uint4 u = *(const uint4*)p;
  d[0] = __uint_as_float((u.x & 0xffffu) << 16);
  d[1] = __uint_as_float(u.x & 0xffff0000u);
  d[2] = __uint_as_float((u.y & 0xffffu) << 16);
  d[3] = __uint_as_float(u.y & 0xffff0000u);
  d[4] = __uint_as_float((u.z & 0xffffu) << 16);
  d[5] = __uint_as_float(u.z & 0xffff0000u);
  d[6] = __uint_as_float((u.w & 0xffffu) << 16);
  d[7] = __uint_as_float(u.w & 0xffff0000u);
}

static __device__ __forceinline__ float block_sum_256(float v, float* rbuf, int tid) {
  rbuf[tid] = v;
  __syncthreads();
  #pragma unroll
  for (int st = 128; st > 0; st >>= 1) {
    if (tid < st) rbuf[tid] += rbuf[tid + st];
    __syncthreads();
  }
  const float r = rbuf[0];
  __syncthreads();
  return r;
}

// ---------------------------------------------------------------------------
// Fused fp32 -> bf16 cast over 6 regions (each a multiple of 1024 elems).
// ---------------------------------------------------------------------------
struct CastArgs {
  const float* in[6];
  bf16* out[6];
  unsigned end[6];   // cumulative block counts
};
__global__ __launch_bounds__(256) void cast6_kernel(CastArgs a) {
  const unsigned b = blockIdx.x;
  int r = 0; unsigned base = 0;
  #pragma unroll
  for (int k = 0; k < 5; ++k)
    if (b >= a.end[k]) { r = k + 1; base = a.end[k]; }
  const float* in = a.in[r];
  bf16* out = a.out[r];
  const unsigned i = ((b - base) * 256 + threadIdx.x) * 4;
  const float4 v = *(const float4*)(in + i);
  uint2 o;
  o.x = (unsigned)bfbits(v.x) | ((unsigned)bfbits(v.y) << 16);
  o.y = (unsigned)bfbits(v.z) | ((unsigned)bfbits(v.w) << 16);
  *(uint2*)(out + i) = o;
}

// Concat Qp_w/Kp_w -> bf16 [128][1024], Qp_b/Kp_b -> fp32 [128]
__global__ __launch_bounds__(256) void pack_qk_kernel(
    const float* __restrict__ Qw, const float* __restrict__ Kw,
    const float* __restrict__ Qb, const float* __restrict__ Kb,
    bf16* __restrict__ w, float* __restrict__ bias) {
  const int r = blockIdx.x;  // 0..127
  const float* srcw = (r < 64) ? (Qw + (size_t)r * ND) : (Kw + (size_t)(r - 64) * ND);
  for (int i = threadIdx.x; i < ND; i += 256) w[(size_t)r * ND + i] = f2b(srcw[i]);
  if (r == 0)
    for (int i = threadIdx.x; i < 128; i += 256)
      bias[i] = (i < 64) ? Qb[i] : Kb[i - 64];
}

// ---------------------------------------------------------------------------
// Generic batched MFMA GEMM (2-phase 128-tile template): C = scale*(A@W^T)
// (+bias), bf16 in. A/B staged via global_load_lds (XOR-slot swizzle on the
// GLOBAL source column, undone at ds_read), double-buffered, counted-vmcnt
// 2-barrier pipeline. Epilogue variants: VT (transposed V store), OUTT
// (transposed C store). Used for the N=1024-class GEMMs (grids too small for
// the 256-tile 8-phase kernel below).
// ---------------------------------------------------------------------------
template<int BM, int BN, int BK, int BIAS, int RELU, int OUTF32, int OUTT, int VT>
__global__ __launch_bounds__(256) void mfma_gemm(
    const bf16* __restrict__ A, const bf16* __restrict__ W,
    const float* __restrict__ bias, void* __restrict__ C,
    int K, int lda, int ldb, int ldc,
    long long aHi, long long aLo, long long bHi, long long bLo,
    long long cHi, long long cLo, float scale, bf16* __restrict__ C2)
{
  constexpr int WTM = BM / 2;
  constexpr int WTN = BN / 2;
  constexpr int AM = WTM / 16;
  constexpr int AN = WTN / 16;
  constexpr int KK = BK / 32;        // MFMA sub-steps per K-tile
  constexpr int SLOTS = BK / 8;      // 16B slots per LDS row
  constexpr int RPC = 512 / BK;      // rows per wave per gload_lds16 call
  constexpr int LPW = (BM * BK) / 2048 + (BN * BK) / 2048;  // loads/wave/stage
  __shared__ short As[2][BM * BK];
  __shared__ short Bs[2][BN * BK];
  const int tid  = threadIdx.x;
  const int lane = tid & 63;
  const int w    = tid >> 6;
  const int z    = blockIdx.z;
  const long long aOff = (long long)(z >> 4) * aHi + (long long)(z & 15) * aLo;
  const long long bOff = (long long)(z >> 4) * bHi + (long long)(z & 15) * bLo;
  const long long cOff = (long long)(z >> 4) * cHi + (long long)(z & 15) * cLo;

  int bx = blockIdx.x, by = blockIdx.y;
  if ((gridDim.x & 7) == 0) {
    const unsigned lin = blockIdx.y * gridDim.x + blockIdx.x;
    const unsigned Wd = gridDim.x >> 3;
    const unsigned xcd = lin & 7, i = lin >> 3;
    bx = (int)(xcd * Wd + (i % Wd));
    by = (int)(i / Wd);
  }
  const int m0 = by * BM;
  const int n0 = bx * BN;
  const int wr = w >> 1, wc = w & 1;
  const int lm = lane & 15, quad = lane >> 4;

  f32x4 acc[AM][AN];
  #pragma unroll
  for (int i = 0; i < AM; ++i)
    #pragma unroll
    for (int j = 0; j < AN; ++j) acc[i][j] = (f32x4){0.f, 0.f, 0.f, 0.f};

  // staging lane map + slot swizzle (write side, applied to GLOBAL source col)
  const int slot = lane & (SLOTS - 1);
  const int sr   = lane / SLOTS;     // row within this wave's RPC-row chunk
  const int swz  = (BK == 32) ? ((sr >> 1) & 3) : (sr & 7);
  const int scol = (slot ^ swz) << 3;  // shorts
  // read-side swizzle (row == lm mod 16; chunk bases are slot-period aligned)
  const int xv   = (BK == 32) ? ((lm >> 1) & 3) : (lm & 7);
  const bf16* Ab = A + aOff;
  const bf16* Bb = W + bOff;

  auto stage = [&](int buf, int k0) {
    #pragma unroll
    for (int t = 0; t < (BM * BK) / 2048; ++t) {
      const int row = w * (BM / 4) + t * RPC;
      gload_lds16(Ab + (long long)(m0 + row + sr) * lda + k0 + scol, &As[buf][row * BK]);
    }
    #pragma unroll
    for (int t = 0; t < (BN * BK) / 2048; ++t) {
      const int row = w * (BN / 4) + t * RPC;
      gload_lds16(Bb + (long long)(n0 + row + sr) * ldb + k0 + scol, &Bs[buf][row * BK]);
    }
  };
  auto compute = [&](int buf) {
    #pragma unroll
    for (int kk = 0; kk < KK; ++kk) {
      const int cb = ((kk * 4 + quad) ^ xv) << 3;   // swizzled 16B slot, shorts
      short8 af[AM], bfr[AN];
      #pragma unroll
      for (int i = 0; i < AM; ++i)
        af[i] = *(const short8*)&As[buf][(wr * WTM + i * 16 + lm) * BK + cb];
      #pragma unroll
      for (int j = 0; j < AN; ++j)
        bfr[j] = *(const short8*)&Bs[buf][(wc * WTN + j * 16 + lm) * BK + cb];
      #pragma unroll
      for (int i = 0; i < AM; ++i)
        #pragma unroll
        for (int j = 0; j < AN; ++j)
          acc[i][j] = __builtin_amdgcn_mfma_f32_16x16x32_bf16(af[i], bfr[j], acc[i][j], 0, 0, 0);
    }
  };

  stage(0, 0);
  int cur = 0;
  for (int k0 = BK; k0 < K; k0 += BK) {
    stage(cur ^ 1, k0);          // prefetch into idle buffer (stays in flight)
    vm_wait<LPW>();              // only the PREVIOUS stage's loads must land
    bar();                       // publish them to all waves
    compute(cur);
    bar();                       // all waves done reading cur before overwrite
    cur ^= 1;
  }
  vm_wait<0>();                  // last tile's loads
  bar();
  compute(cur);

  #pragma unroll
  for (int i = 0; i < AM; ++i) {
    #pragma unroll
    for (int j = 0; j < AN; ++j) {
      const int n = n0 + wc * WTN + j * 16 + lm;
      const float bj = BIAS ? bias[n] : 0.f;
      float v0 = acc[i][j][0] * scale + bj;
      float v1 = acc[i][j][1] * scale + bj;
      float v2 = acc[i][j][2] * scale + bj;
      float v3 = acc[i][j][3] * scale + bj;
      if (RELU) {
        v0 = fmaxf(v0, 0.f); v1 = fmaxf(v1, 0.f);
        v2 = fmaxf(v2, 0.f); v3 = fmaxf(v3, 0.f);
      }
      const int mm = m0 + wr * WTM + i * 16 + quad * 4;
      if (VT && n0 >= 2 * ND) {
        // transposed V store: Vt[(b*16+h)][d][s], 4 consecutive s -> 8B
        const int h = (n - 2 * ND) >> 6, d = (n - 2 * ND) & 63;
        uint2 u;
        u.x = (unsigned)bfbits(v0) | ((unsigned)bfbits(v1) << 16);
        u.y = (unsigned)bfbits(v2) | ((unsigned)bfbits(v3) << 16);
        bf16* dst = C2 + (long long)((mm >> 10) * NH + h) * (NDH * NS)
                       + (long long)d * NS + (mm & 1023);
        *(uint2*)dst = u;
      } else if (OUTT) {
        // transposed store: C[b][n][s], batch stride ND*NS
        uint2 u;
        u.x = (unsigned)bfbits(v0) | ((unsigned)bfbits(v1) << 16);
        u.y = (unsigned)bfbits(v2) | ((unsigned)bfbits(v3) << 16);
        bf16* dst = (bf16*)C + cOff + (long long)(mm >> 10) * ((long long)ND * NS)
                       + (long long)n * NS + (mm & 1023);
        *(uint2*)dst = u;
      } else {
        const float vv[4] = {v0, v1, v2, v3};
        #pragma unroll
        for (int rr = 0; rr < 4; ++rr) {
          const long long co = cOff + (long long)(mm + rr) * ldc + n;
          if (OUTF32) ((float*)C)[co] = vv[rr];
          else        ((bf16*)C)[co] = f2b(vv[rr]);
        }
      }
    }
  }
}

// ---------------------------------------------------------------------------
// 256x256 8-phase GEMM (T3+T4+T5 port): C = A@W^T (+bias), bf16.
// 512 threads = 8 waves (2M x 4N); wave tile 128x64 (acc 8x4); BK=64;
// LDS = 2 x (A 32KB + B 32KB) = 128 KB -> 1 block/CU. Grid (N/256, M/256).
// Per K-tile: 4 phases, each {ds_read subtile -> 2 prefetch gload_lds ->
// s_barrier -> setprio(1) 16 MFMA setprio(0) -> s_barrier}. Register reuse:
// A-half (8 frags) spans 2 phases; B-halves (4 frags each) span the tile.
// Counted vmcnt, never 0 in main loop: vmcnt(4) at phase2 (drains this
// tile's A-c1/c3, issued 2 phases ago), vmcnt(2) at phase4 (drains next
// tile's B0-3+A0/A2, leaves newest A1/A3 in flight). Deadline check: every
// staged call is vm-waited by its issuing wave before a barrier preceding
// its cross-wave ds_read. Same XOR-slot swizzle as mfma_gemm (BK=64 form).
// VT=1: blocks with n0 >= 2*ND write transposed V into C2 (step 1).
// ---------------------------------------------------------------------------
template<int BIAS, int RELU, int VT>
__global__ __launch_bounds__(512) void mfma_gemm256(
    const bf16* __restrict__ A, const bf16* __restrict__ W,
    const float* __restrict__ bias, bf16* __restrict__ C,
    int K, int lda, int ldb, int ldc, bf16* __restrict__ C2)
{
  __shared__ short As[2][256 * 64];   // 64 KB
  __shared__ short Bs[2][256 * 64];   // 64 KB
  const int tid  = threadIdx.x;
  const int lane = tid & 63;
  const int w    = tid >> 6;          // 0..7
  int bx = blockIdx.x, by = blockIdx.y;
  if ((gridDim.x & 7) == 0) {
    const unsigned lin = blockIdx.y * gridDim.x + blockIdx.x;
    const unsigned Wd = gridDim.x >> 3;
    const unsigned xcd = lin & 7, i = lin >> 3;
    bx = (int)(xcd * Wd + (i % Wd));
    by = (int)(i / Wd);
  }
  const int m0 = by * 256;
  const int n0 = bx * 256;
  const int wr = w >> 2, wc = w & 3;  // wave grid 2(M) x 4(N)
  const int lm = lane & 15, quad = lane >> 4;

  f32x4 acc[8][4];
  #pragma unroll
  for (int i = 0; i < 8; ++i)
    #pragma unroll
    for (int j = 0; j < 4; ++j) acc[i][j] = (f32x4){0.f, 0.f, 0.f, 0.f};

  // staging: 8 slots of 16B per 64-elem row; 8 rows per wave per call;
  // call c covers rows c*64 .. c*64+63 (8 waves x 8 rows).
  const int slot = lane & 7, sr = lane >> 3;
  const int scol = (slot ^ sr) << 3;   // swizzled global col (shorts)
  const int xv   = lm & 7;             // read-side swizzle

  auto stgA = [&](int buf, int c, int k0) {
    gload_lds16(A + (long long)(m0 + c * 64 + w * 8 + sr) * lda + k0 + scol,
                &As[buf][(c * 64 + w * 8) * 64]);
  };
  auto stgB = [&](int buf, int c, int k0) {
    gload_lds16(W + (long long)(n0 + c * 64 + w * 8 + sr) * ldb + k0 + scol,
                &Bs[buf][(c * 64 + w * 8) * 64]);
  };
  auto dsA = [&](short8* afr, int h, int buf) {      // 8 reads: A-half h
    #pragma unroll
    for (int i = 0; i < 4; ++i)
      #pragma unroll
      for (int kk = 0; kk < 2; ++kk)
        afr[i * 2 + kk] = *(const short8*)
            &As[buf][(wr * 128 + h * 64 + i * 16 + lm) * 64 + (((kk * 4 + quad) ^ xv) << 3)];
  };
  auto dsB = [&](short8* bfr, int jh, int buf) {     // 4 reads: B-half jh
    #pragma unroll
    for (int j = 0; j < 2; ++j)
      #pragma unroll
      for (int kk = 0; kk < 2; ++kk)
        bfr[j * 2 + kk] = *(const short8*)
            &Bs[buf][(wc * 64 + jh * 32 + j * 16 + lm) * 64 + (((kk * 4 + quad) ^ xv) << 3)];
  };
  auto mmaq = [&](auto H, auto JH, const short8* afr, const short8* bfr) {
    constexpr int h = decltype(H)::value, jh = decltype(JH)::value;
    __builtin_amdgcn_s_setprio(1);
    #pragma unroll
    for (int i = 0; i < 4; ++i)
      #pragma unroll
      for (int j = 0; j < 2; ++j)
        #pragma unroll
        for (int kk = 0; kk < 2; ++kk)
          acc[h * 4 + i][jh * 2 + j] = __builtin_amdgcn_mfma_f32_16x16x32_bf16(
              afr[i * 2 + kk], bfr[j * 2 + kk], acc[h * 4 + i][jh * 2 + j], 0, 0, 0);
    __builtin_amdgcn_s_setprio(0);
  };
  const std::integral_constant<int, 0> C0{};
  const std::integral_constant<int, 1> C1{};

  // prologue: stage tile 0 into buf 0 (age order matches steady state)
  stgB(0, 0, 0); stgB(0, 1, 0); stgB(0, 2, 0); stgB(0, 3, 0);
  stgA(0, 0, 0); stgA(0, 2, 0); stgA(0, 1, 0); stgA(0, 3, 0);
  vm_wait<0>();
  bar();

  const int NT = K / 64;
  int p = 0;
  for (int kt = 0; kt < NT; ++kt, p ^= 1) {
    const int k1 = (kt + 1) * 64;
    const bool pre = (kt + 1 < NT);
    short8 afr[8], bfrA[4], bfrB[4];
    // phase 1: quadrant (h0, j01)
    dsA(afr, 0, p); dsB(bfrA, 0, p);
    if (pre) { stgB(p ^ 1, 0, k1); stgB(p ^ 1, 1, k1); }
    bar();
    mmaq(C0, C0, afr, bfrA);
    bar();
    // phase 2: quadrant (h0, j23)
    dsB(bfrB, 1, p);
    if (pre) { stgB(p ^ 1, 2, k1); stgB(p ^ 1, 3, k1); vm_wait<4>(); }
    else vm_wait<0>();
    bar();
    mmaq(C0, C1, afr, bfrB);
    bar();
    // phase 3: quadrant (h1, j01)
    dsA(afr, 1, p);
    if (pre) { stgA(p ^ 1, 0, k1); stgA(p ^ 1, 2, k1); }
    bar();
    mmaq(C1, C0, afr, bfrA);
    bar();
    // phase 4: quadrant (h1, j23)
    if (pre) { stgA(p ^ 1, 1, k1); stgA(p ^ 1, 3, k1); vm_wait<2>(); }
    else vm_wait<0>();
    bar();
    mmaq(C1, C1, afr, bfrB);
    bar();
  }

  // epilogue
  #pragma unroll
  for (int i = 0; i < 8; ++i) {
    #pragma unroll
    for (int j = 0; j < 4; ++j) {
      const int n = n0 + wc * 64 + j * 16 + lm;
      const float bj = BIAS ? bias[n] : 0.f;
      float v0 = acc[i][j][0] + bj;
      float v1 = acc[i][j][1] + bj;
      float v2 = acc[i][j][2] + bj;
      float v3 = acc[i][j][3] + bj;
      if (RELU) {
        v0 = fmaxf(v0, 0.f); v1 = fmaxf(v1, 0.f);
        v2 = fmaxf(v2, 0.f); v3 = fmaxf(v3, 0.f);
      }
      const int mm = m0 + wr * 128 + i * 16 + quad * 4;
      if (VT && n0 >= 2 * ND) {
        const int h = (n - 2 * ND) >> 6, d = (n - 2 * ND) & 63;
        uint2 u;
        u.x = (unsigned)bfbits(v0) | ((unsigned)bfbits(v1) << 16);
        u.y = (unsigned)bfbits(v2) | ((unsigned)bfbits(v3) << 16);
        bf16* dst = C2 + (long long)((mm >> 10) * NH + h) * (NDH * NS)
                       + (long long)d * NS + (mm & 1023);
        *(uint2*)dst = u;
      } else {
        C[(long long)(mm + 0) * ldc + n] = f2b(v0);
        C[(long long)(mm + 1) * ldc + n] = f2b(v1);
        C[(long long)(mm + 2) * ldc + n] = f2b(v2);
        C[(long long)(mm + 3) * ldc + n] = f2b(v3);
      }
    }
  }
}

// ---------------------------------------------------------------------------
// Fused flash attention (dense MHA): per (q-tile of 128, b, h) block.
// Swapped QK^T -> S^T frags (q = lane&15); online softmax via 2 shfl_xor;
// P^T bf16 B-frags built in-register via shfl. K/V^T staged via
// global_load_lds + XOR slot swizzle; counted-vmcnt 2-barrier pipeline.
// grid (NS/128, NB*NH), 256 threads.
// ---------------------------------------------------------------------------
__global__ __launch_bounds__(256) void attn_kernel(
    const bf16* __restrict__ qkv,   // [B][S][3*ND]
    const bf16* __restrict__ Vt,    // [B*H][NDH][NS]
    bf16* __restrict__ ctx)         // [B][S][ND]
{
  __shared__ short smem[2][2][64 * 64];   // [buf][K|V][4096] = 32 KB
  const int tid = threadIdx.x, lane = tid & 63, w = tid >> 6;
  const int lm = lane & 15, quad = lane >> 4;
  const int z = blockIdx.y, b = z >> 4, h = z & 15;
  const int q0 = blockIdx.x * 128;
  const bf16* Qb = qkv + (long long)b * NS * 3072 + h * 64;
  const bf16* Kb = Qb + ND;
  const bf16* Vb = Vt + (long long)z * (NDH * NS);

  // Q B-frags [j][kk]: col q = q0 + w*32 + j*16 + lm, k(d) = kk*32 + quad*8 + e
  short8 qf[2][2];
  #pragma unroll
  for (int j = 0; j < 2; ++j)
    #pragma unroll
    for (int kk = 0; kk < 2; ++kk)
      qf[j][kk] = *(const short8*)(Qb + (long long)(q0 + w * 32 + j * 16 + lm) * 3072
                                      + kk * 32 + quad * 8);

  // staging map (8 slots of 16B per 64-elem row; 8 rows per issue per wave)
  const int slot = lane & 7, sr = lane >> 3;
  const int scol = (slot ^ sr) << 3;      // shorts; involution with read side

  auto stage = [&](int buf, int t) {
    #pragma unroll
    for (int u = 0; u < 2; ++u) {
      const int row = w * 16 + u * 8;     // kv row within tile
      gload_lds16(Kb + (long long)(t * 64 + row + sr) * 3072 + scol,
                  &smem[buf][0][row * 64]);
    }
    #pragma unroll
    for (int u = 0; u < 2; ++u) {
      const int row = w * 16 + u * 8;     // d row
      gload_lds16(Vb + (long long)(row + sr) * NS + t * 64 + scol,
                  &smem[buf][1][row * 64]);
    }
  };

  f32x4 o[4][2];                          // O^T: d-tile i, q-tile j
  #pragma unroll
  for (int i = 0; i < 4; ++i)
    #pragma unroll
    for (int j = 0; j < 2; ++j) o[i][j] = (f32x4){0.f, 0.f, 0.f, 0.f};
  float m[2] = {-1e30f, -1e30f}, l[2] = {0.f, 0.f};

  stage(0, 0);
  for (int t = 0; t < 16; ++t) {
    const int buf = t & 1;
    if (t < 15) { stage(buf ^ 1, t + 1); vm_wait<4>(); }
    else        { vm_wait<0>(); }
    bar();                                // tile t's loads visible to all

    // --- S^T = (K @ Q^T)/8 : st[i][j], i = kv-tile, j = q-tile
    f32x4 st[4][2];
    #pragma unroll
    for (int i = 0; i < 4; ++i)
      #pragma unroll
      for (int j = 0; j < 2; ++j) st[i][j] = (f32x4){0.f, 0.f, 0.f, 0.f};
    #pragma unroll
    for (int kk = 0; kk < 2; ++kk) {
      const int cb = ((kk * 4 + quad) ^ (lm & 7)) << 3;
      short8 ka[4];
      #pragma unroll
      for (int i = 0; i < 4; ++i)
        ka[i] = *(const short8*)&smem[buf][0][(i * 16 + lm) * 64 + cb];
      #pragma unroll
      for (int i = 0; i < 4; ++i)
        #pragma unroll
        for (int j = 0; j < 2; ++j)
          st[i][j] = __builtin_amdgcn_mfma_f32_16x16x32_bf16(ka[i], qf[j][kk], st[i][j], 0, 0, 0);
    }

    // --- online softmax per q-col (j); kv spread over 16 regs x 4 quads
    #pragma unroll
    for (int j = 0; j < 2; ++j) {
      float pm = -1e30f;
      #pragma unroll
      for (int i = 0; i < 4; ++i)
        #pragma unroll
        for (int r = 0; r < 4; ++r) {
          st[i][j][r] *= 0.125f;
          pm = fmaxf(pm, st[i][j][r]);
        }
      pm = fmaxf(pm, __shfl_xor(pm, 16, 64));
      pm = fmaxf(pm, __shfl_xor(pm, 32, 64));
      const float mn = fmaxf(m[j], pm);
      const float sc = __expf(m[j] - mn);
      float ps = 0.f;
      #pragma unroll
      for (int i = 0; i < 4; ++i)
        #pragma unroll
        for (int r = 0; r < 4; ++r) {
          const float e = __expf(st[i][j][r] - mn);
          st[i][j][r] = e;                 // st now holds P^T
          ps += e;
        }
      ps += __shfl_xor(ps, 16, 64);
      ps += __shfl_xor(ps, 32, 64);
      l[j] = l[j] * sc + ps;
      m[j] = mn;
      #pragma unroll
      for (int i = 0; i < 4; ++i)
        #pragma unroll
        for (int r = 0; r < 4; ++r) o[i][j][r] *= sc;
    }

    // --- pack P^T to bf16 pairs: u0 = (r0,r1), u1 = (r2,r3)
    unsigned u0[4][2], u1[4][2];
    #pragma unroll
    for (int i = 0; i < 4; ++i)
      #pragma unroll
      for (int j = 0; j < 2; ++j) {
        u0[i][j] = (unsigned)bfbits(st[i][j][0]) | ((unsigned)bfbits(st[i][j][1]) << 16);
        u1[i][j] = (unsigned)bfbits(st[i][j][2]) | ((unsigned)bfbits(st[i][j][3]) << 16);
      }
    // target frag (kk,j) elem e: kv = kk*32+quad*8+e comes from
    //   i_src = kk*2 + (quad>>1), src lane = ((quad&1)*2 + (e>>2))*16 + lm, r = e&3
    const int s0l = ((quad & 1) * 2) * 16 + lm;
    const int s1l = s0l + 16;
    const bool hi = (quad >> 1) != 0;

    // --- O^T += V^T @ P^T
    #pragma unroll
    for (int kk = 0; kk < 2; ++kk) {
      short8 pf[2];
      #pragma unroll
      for (int j = 0; j < 2; ++j) {
        const unsigned a0 = __shfl(u0[kk * 2][j],     s0l, 64);
        const unsigned a1 = __shfl(u1[kk * 2][j],     s0l, 64);
        const unsigned b0 = __shfl(u0[kk * 2 + 1][j], s0l, 64);
        const unsigned b1 = __shfl(u1[kk * 2 + 1][j], s0l, 64);
        const unsigned c0 = __shfl(u0[kk * 2][j],     s1l, 64);
        const unsigned c1 = __shfl(u1[kk * 2][j],     s1l, 64);
        const unsigned d0 = __shfl(u0[kk * 2 + 1][j], s1l, 64);
        const unsigned d1 = __shfl(u1[kk * 2 + 1][j], s1l, 64);
        union { uint4 u; short8 s; } cv;
        cv.u.x = hi ? b0 : a0; cv.u.y = hi ? b1 : a1;
        cv.u.z = hi ? d0 : c0; cv.u.w = hi ? d1 : c1;
        pf[j] = cv.s;
      }
      const int cb = ((kk * 4 + quad) ^ (lm & 7)) << 3;
      short8 va[4];
      #pragma unroll
      for (int i = 0; i < 4; ++i)
        va[i] = *(const short8*)&smem[buf][1][(i * 16 + lm) * 64 + cb];
      #pragma unroll
      for (int i = 0; i < 4; ++i)
        #pragma unroll
        for (int j = 0; j < 2; ++j)
          o[i][j] = __builtin_amdgcn_mfma_f32_16x16x32_bf16(va[i], pf[j], o[i][j], 0, 0, 0);
    }
    bar();   // all waves done reading buf before next overwrite / epilogue
  }

  // --- epilogue: normalize, transpose O^T -> O through LDS, coalesced store
  short (*OL)[72] = (short(*)[72])&smem[0][0][0];   // 128 x 72 = 18.4 KB
  #pragma unroll
  for (int j = 0; j < 2; ++j) {
    const float inv = 1.f / l[j];
    #pragma unroll
    for (int i = 0; i < 4; ++i) {
      uint2 u;
      u.x = (unsigned)bfbits(o[i][j][0] * inv) | ((unsigned)bfbits(o[i][j][1] * inv) << 16);
      u.y = (unsigned)bfbits(o[i][j][2] * inv) | ((unsigned)bfbits(o[i][j][3] * inv) << 16);
      *(uint2*)&OL[w * 32 + j * 16 + lm][i * 16 + quad * 4] = u;
    }
  }
  __syncthreads();
  {
    const int q = tid >> 1, c = (tid & 1) * 32;
    const uint4 r0 = *(const uint4*)&OL[q][c];
    const uint4 r1 = *(const uint4*)&OL[q][c + 8];
    const uint4 r2 = *(const uint4*)&OL[q][c + 16];
    const uint4 r3 = *(const uint4*)&OL[q][c + 24];
    bf16* dst = ctx + ((long long)(b * NS + q0 + q)) * 1024 + h * 64 + c;
    ((uint4*)dst)[0] = r0; ((uint4*)dst)[1] = r1;
    ((uint4*)dst)[2] = r2; ((uint4*)dst)[3] = r3;
  }
}

// ---------------------------------------------------------------------------
// Sparse top-k selection from precomputed fp32 scores S[row][1024].
// One WAVE per row (4 rows/block); wave-local radix select.
// ---------------------------------------------------------------------------
__global__ __launch_bounds__(256) void sparse_select_kernel(
    const float* __restrict__ S, bf16* __restrict__ aw)
{
  __shared__ unsigned hist[4][256];
  const int tid = threadIdx.x;
  const int lane = tid & 63;
  const int wv = tid >> 6;
  const long long row = (long long)blockIdx.x * 4 + wv;

  float sv[16];
  const float* sp = S + row * 1024 + lane * 16;
  #pragma unroll
  for (int c = 0; c < 4; ++c) {
    const float4 v = ((const float4*)sp)[c];
    sv[4*c] = v.x; sv[4*c+1] = v.y; sv[4*c+2] = v.z; sv[4*c+3] = v.w;
  }
  unsigned key[16];
  #pragma unroll
  for (int j = 0; j < 16; ++j) {
    const unsigned u = __float_as_uint(sv[j]);
    key[j] = (u & 0x80000000u) ? ~u : (u | 0x80000000u);  // order-preserving
  }

  unsigned pref = 0u;
  int need = NTOPK;
  #pragma unroll
  for (int p = 3; p >= 0; --p) {
    *(uint4*)&hist[wv][lane * 4] = (uint4){0u, 0u, 0u, 0u};
    __syncthreads();
    const int sh = (p + 1) * 8;
    #pragma unroll
    for (int j = 0; j < 16; ++j) {
      const bool part = (p == 3) || ((key[j] >> sh) == pref);
      if (part) atomicAdd(&hist[wv][(key[j] >> (p * 8)) & 255u], 1u);
    }
    __syncthreads();
    const unsigned h0 = hist[wv][4*lane],     h1 = hist[wv][4*lane + 1];
    const unsigned h2 = hist[wv][4*lane + 2], h3 = hist[wv][4*lane + 3];
    const unsigned s3 = h3, s2 = h2 + s3, s1 = h1 + s2, s0 = h0 + s1;
    unsigned sum = s0;                      // suffix sum over lanes >= lane
    #pragma unroll
    for (int d2 = 1; d2 < 64; d2 <<= 1) {
      const unsigned t = __shfl_down(sum, d2, 64);
      if (lane < 64 - d2) sum += t;
    }
    const unsigned above = sum - s0;
    const unsigned cum[4]  = {above + s0, above + s1, above + s2, above + s3};
    const unsigned next[4] = {above + s1, above + s2, above + s3, above};
    unsigned candPref = 0u; int candNeed = 0; bool has = false;
    #pragma unroll
    for (int i = 0; i < 4; ++i) {
      if ((int)cum[i] >= need && (int)next[i] < need) {
        has = true;
        candPref = (pref << 8) | (unsigned)(4 * lane + i);
        candNeed = need - (int)next[i];
      }
    }
    const unsigned long long m = __ballot(has);
    const int srcLane = (int)(__ffsll((long long)m) - 1);
    pref = (unsigned)__shfl((int)candPref, srcLane, 64);
    need = __shfl(candNeed, srcLane, 64);
  }

  const unsigned T = pref;                  // 204th-largest key
  const unsigned tb = (T & 0x80000000u) ? (T ^ 0x80000000u) : ~T;
  const float thr = __uint_as_float(tb);

  float wvv[16];
  float psTop = 0.f, psAll = 0.f;
  #pragma unroll
  for (int j = 0; j < 16; ++j) {
    const float e = __expf(sv[j] - thr);
    psAll += e;
    const float wt = (key[j] >= T) ? e : 0.f;
    psTop += wt;
    wvv[j] = wt;
  }
  #pragma unroll
  for (int s = 1; s < 64; s <<= 1) {
    psTop += __shfl_xor(psTop, s, 64);
    psAll += __shfl_xor(psAll, s, 64);
  }
  const float inv = 1.f / (psTop + 1e-9f * psAll);

  uint4 o0, o1;
  o0.x = (unsigned)bfbits(wvv[0]*inv)  | ((unsigned)bfbits(wvv[1]*inv)  << 16);
  o0.y = (unsigned)bfbits(wvv[2]*inv)  | ((unsigned)bfbits(wvv[3]*inv)  << 16);
  o0.z = (unsigned)bfbits(wvv[4]*inv)  | ((unsigned)bfbits(wvv[5]*inv)  << 16);
  o0.w = (unsigned)bfbits(wvv[6]*inv)  | ((unsigned)bfbits(wvv[7]*inv)  << 16);
  o1.x = (unsigned)bfbits(wvv[8]*inv)  | ((unsigned)bfbits(wvv[9]*inv)  << 16);
  o1.y = (unsigned)bfbits(wvv[10]*inv) | ((unsigned)bfbits(wvv[11]*inv) << 16);
  o1.z = (unsigned)bfbits(wvv[12]*inv) | ((unsigned)bfbits(wvv[13]*inv) << 16);
  o1.w = (unsigned)bfbits(wvv[14]*inv) | ((unsigned)bfbits(wvv[15]*inv) << 16);
  bf16* op = aw + row * 1024 + lane * 16;
  ((uint4*)op)[0] = o0; ((uint4*)op)[1] = o1;
}

// ---------------------------------------------------------------------------
// fused = sig*dense + (1-sig)*sparse ; x1 = LN1(src + fused)  (bf16 out)
// ---------------------------------------------------------------------------
__global__ __launch_bounds__(256) void fuse_ln1_kernel(
    const float* __restrict__ src, const bf16* __restrict__ dense,
    const bf16* __restrict__ sparse, const float* __restrict__ lam,
    const float* __restrict__ g, const float* __restrict__ beta,
    bf16* __restrict__ x1)
{
  __shared__ float y[ND];
  __shared__ float rbuf[256];
  const int tid = threadIdx.x;
  const size_t base = (size_t)blockIdx.x * ND;
  const float sig = 1.f / (1.f + __expf(-lam[0]));
  const float c1 = 1.f - sig;
  float s1 = 0.f, s2 = 0.f;
  #pragma unroll
  for (int j = 0; j < 4; ++j) {
    const int i = tid + (j << 8);
    const float v = src[base + i] + sig * b2f(dense[base + i]) + c1 * b2f(sparse[base + i]);
    y[i] = v; s1 += v; s2 += v * v;
  }
  const float sum1 = block_sum_256(s1, rbuf, tid);
  const float sum2 = block_sum_256(s2, rbuf, tid);
  const float mean = sum1 * (1.f / ND);
  const float var  = sum2 * (1.f / ND) - mean * mean;
  const float rstd = rsqrtf(var + 1e-5f);
  #pragma unroll
  for (int j = 0; j < 4; ++j) {
    const int i = tid + (j << 8);
    x1[base + i] = f2b((y[i] - mean) * rstd * g[i] + beta[i]);
  }
}

// out = LN2(x1 + ff)  (fp32 out; ff is bf16)
__global__ __launch_bounds__(256) void ln2_kernel(
    const bf16* __restrict__ x1, const bf16* __restrict__ ff,
    const float* __restrict__ g, const float* __restrict__ beta,
    float* __restrict__ outp)
{
  __shared__ float y[ND];
  __shared__ float rbuf[256];
  const int tid = threadIdx.x;
  const size_t base = (size_t)blockIdx.x * ND;
  float s1 = 0.f, s2 = 0.f;
  #pragma unroll
  for (int j = 0; j < 4; ++j) {
    const int i = tid + (j << 8);
    const float v = b2f(x1[base + i]) + b2f(ff[base + i]);
    y[i] = v; s1 += v; s2 += v * v;
  }
  const float sum1 = block_sum_256(s1, rbuf, tid);
  const float sum2 = block_sum_256(s2, rbuf, tid);
  const float mean = sum1 * (1.f / ND);
  const float var  = sum2 * (1.f / ND) - mean * mean;
  const float rstd = rsqrtf(var + 1e-5f);
  #pragma unroll
  for (int j = 0; j < 4; ++j) {
    const int i = tid + (j << 8);
    outp[base + i] = (y[i] - mean) * rstd * g[i] + beta[i];
  }
}

// ---------------------------------------------------------------------------
extern "C" void kernel_launch(void* const* d_in, const int* in_sizes, int n_in,
                              void* d_out, int out_size, void* d_ws, size_t ws_size,
                              hipStream_t stream)
{
  const float* src        = (const float*)d_in[0];
  const float* in_proj_w  = (const float*)d_in[1];
  const float* in_proj_b  = (const float*)d_in[2];
  const float* out_proj_w = (const float*)d_in[3];
  const float* out_proj_b = (const float*)d_in[4];
  const float* Qp_w  = (const float*)d_in[5];
  const float* Qp_b  = (const float*)d_in[6];
  const float* Kp_w  = (const float*)d_in[7];
  const float* Kp_b  = (const float*)d_in[8];
  const float* Vp_w  = (const float*)d_in[9];
  const float* Vp_b  = (const float*)d_in[10];
  const float* lam   = (const float*)d_in[11];
  const float* ff1_w = (const float*)d_in[12];
  const float* ff1_b = (const float*)d_in[13];
  const float* ff2_w = (const float*)d_in[14];
  const float* ff2_b = (const float*)d_in[15];
  const float* ln1_g = (const float*)d_in[16];
  const float* ln1_b = (const float*)d_in[17];
  const float* ln2_g = (const float*)d_in[18];
  const float* ln2_b = (const float*)d_in[19];
  (void)in_sizes; (void)n_in; (void)out_size; (void)ws_size;

  // --------- workspace layout (offsets IDENTICAL to the proven layout;
  // Vt_all reuses the old S_b slot)
  char* ws = (char*)d_ws;
  size_t off = 0;
  auto take = [&](size_t bytes) -> void* {
    void* p = ws + off; off += (bytes + 255) & ~(size_t)255; return p;
  };
  bf16*  src_bf  = (bf16*) take((size_t)NM * ND * 2);          //  8.4 MB
  bf16*  w_qkv   = (bf16*) take((size_t)3 * ND * ND * 2);      //  6.3 MB
  bf16*  w_out   = (bf16*) take((size_t)ND * ND * 2);          //  2.1 MB
  bf16*  w_vp    = (bf16*) take((size_t)ND * ND * 2);          //  2.1 MB
  bf16*  w_ff1   = (bf16*) take((size_t)NDFF * ND * 2);        //  8.4 MB
  bf16*  w_ff2   = (bf16*) take((size_t)ND * NDFF * 2);        //  8.4 MB
  bf16*  w_qk    = (bf16*) take((size_t)128 * ND * 2);         //  0.26 MB
  float* bias_qk = (float*)take(128 * 4);
  const size_t mark = off;                                     // reuse point
  bf16*  qkv     = (bf16*) take((size_t)NM * 3 * ND * 2);      // 25.2 MB [dead after attn]
  bf16*  Vt_all  = (bf16*) take((size_t)NH * NS * NS * 2);     // slot 33.5 MB (uses 8.4) [dead after attn]
  bf16*  Vt_old  = (bf16*) take((size_t)NH * NDH * NS * 2);    //  2.1 MB [unused slot, keeps offsets]
  bf16*  ctx     = (bf16*) take((size_t)NM * ND * 2);          //  8.4 MB [dead after step 3]
  bf16*  dense   = (bf16*) take((size_t)NM * ND * 2);          //  8.4 MB
  bf16*  QKs_bf  = (bf16*) take((size_t)NM * 128 * 2);         //  1.05 MB
  bf16*  Vsp     = (bf16*) take((size_t)NM * ND * 2);          //  8.4 MB [unused slot now]
  bf16*  sparse  = (bf16*) take((size_t)NM * ND * 2);          //  8.4 MB
  (void)Vt_old; (void)Vsp;
  // aliases into dead regions (qkv+Vt_all dead after the attention):
  bf16*  x1    = (bf16*)(ws + mark);                                       // [0, 8.4M)
  bf16*  h1    = (bf16*)(ws + mark + (size_t)NM * ND * 2);                 // [8.4, 42.0M)
  bf16*  ffout = (bf16*)(ws + mark + (size_t)NM * ND * 2 + (size_t)NM * NDFF * 2); // [42.0, 50.4M)
  bf16*  aw    = (bf16*)(ws + mark + 2 * (size_t)NM * ND * 2 + (size_t)NM * NDFF * 2); // [50.4, 58.8M)
  float* S_sp  = (float*)(ws + mark + (size_t)NM * ND * 2);    // [8.4, 25.2M): written 4b,
                                                               // read 6a, dead before h1
  bf16*  Vsp_t = (bf16*)ctx;  // ctx dead after step 3; written directly by step 5 (OUTT)

  const dim3 blk(256);
  bf16* const NOC2 = nullptr;
  // 0. fp32 -> bf16 conversions, one fused launch (6 regions, 17408 blocks)
  {
    CastArgs a;
    a.in[0] = src;        a.out[0] = src_bf;  // 4096 blocks
    a.in[1] = in_proj_w;  a.out[1] = w_qkv;   // 3072
    a.in[2] = out_proj_w; a.out[2] = w_out;   // 1024
    a.in[3] = Vp_w;       a.out[3] = w_vp;    // 1024
    a.in[4] = ff1_w;      a.out[4] = w_ff1;   // 4096
    a.in[5] = ff2_w;      a.out[5] = w_ff2;   // 4096
    a.end[0] = 4096; a.end[1] = 7168; a.end[2] = 8192;
    a.end[3] = 9216; a.end[4] = 13312; a.end[5] = 17408;
    cast6_kernel<<<dim3(17408), blk, 0, stream>>>(a);
  }
  pack_qk_kernel<<<dim3(128), blk, 0, stream>>>(Qp_w, Kp_w, Qp_b, Kp_b, w_qk, bias_qk);

  // 1. qkv = src @ in_proj^T + b  [4096,3072] bf16, 256-tile 8-phase kernel
  //    (192 blocks, 512 thr); V third written TRANSPOSED into Vt_all (VT=1).
  mfma_gemm256<1,0,1><<<dim3(3*ND/256, NM/256), dim3(512), 0, stream>>>(
      src_bf, w_qkv, in_proj_b, qkv, ND, ND, ND, 3*ND, Vt_all);

  // 2. dense MHA: fused flash attention (Vt_all already populated by step 1)
  attn_kernel<<<dim3(NS/128, NB*NH), blk, 0, stream>>>(qkv, Vt_all, ctx);

  // 3. dense_output = ctx @ out_proj^T + b  (bf16; 128x64xBK64 -> 512 blocks)
  mfma_gemm<128,64,64,1,0,0,0,0><<<dim3(ND/64, NM/128, 1), blk, 0, stream>>>(
      ctx, w_out, out_proj_b, dense, ND, ND, ND, ND, 0,0, 0,0, 0,0, 1.f, NOC2);
  // 4. QKs_bf = src @ [Qp;Kp]^T + b  (bf16 [4096][128]; 64 blocks)
  mfma_gemm<128,64,64,1,0,0,0,0><<<dim3(2, NM/128, 1), blk, 0, stream>>>(
      src_bf, w_qk, bias_qk, QKs_bf, ND, ND, ND, 128, 0,0, 0,0, 0,0, 1.f, NOC2);
  // 4b. S_sp[b] = (Qs Ks^T)/8  fp32, batched over b (single K-tile at BK=64)
  mfma_gemm<128,64,64,0,0,1,0,0><<<dim3(NS/64, NS/128, NB), blk, 0, stream>>>(
      QKs_bf, QKs_bf + 64, nullptr, S_sp, 64, 128, 128, NS,
      0, (long long)NS*128, 0, (long long)NS*128, 0, (long long)NS*NS, 0.125f, NOC2);
  // 5. Vsp_t[b][d][s] = (src @ Vp^T + b)^T — stored DIRECTLY TRANSPOSED
  //    (OUTT=1) into the ctx slot — replaces Vsp + the transpose_sq kernel.
  mfma_gemm<128,64,64,1,0,0,1,0><<<dim3(ND/64, NM/128, 1), blk, 0, stream>>>(
      src_bf, w_vp, Vp_b, Vsp_t, ND, ND, ND, NS, 0,0, 0,0, 0,0, 1.f, NOC2);
  // 6a. top-k select + normalized weights -> aw (bf16), one wave per row
  sparse_select_kernel<<<dim3(NM/4), blk, 0, stream>>>(S_sp, aw);
  // 6b. sparse = aw @ Vsp^T  (batched per b; 512 blocks)
  mfma_gemm<128,64,64,0,0,0,0,0><<<dim3(ND/64, NS/128, NB), blk, 0, stream>>>(
      aw, Vsp_t, nullptr, sparse, NS, NS, NS, ND,
      0, (long long)NS*ND, 0, (long long)ND*NS, 0, (long long)NS*ND, 1.f, NOC2);
  // 7. fuse + residual + LN1 -> x1 (bf16)  [qkv/Vt_all dead; x1 aliases them]
  fuse_ln1_kernel<<<dim3(NM), blk, 0, stream>>>(src, dense, sparse, lam, ln1_g, ln1_b, x1);
  // 8. h1 = relu(x1 @ ff1^T + b)  (bf16; 256-tile 8-phase, 256 blocks = 1/CU)
  mfma_gemm256<1,1,0><<<dim3(NDFF/256, NM/256), dim3(512), 0, stream>>>(
      x1, w_ff1, ff1_b, h1, ND, ND, ND, NDFF, NOC2);
  // 9. ff = h1 @ ff2^T + b  (bf16; 128x64xBK64 -> 512 blocks)
  mfma_gemm<128,64,64,1,0,0,0,0><<<dim3(ND/64, NM/128, 1), blk, 0, stream>>>(
      h1, w_ff2, ff2_b, ffout, NDFF, NDFF, NDFF, ND, 0,0, 0,0, 0,0, 1.f, NOC2);
  // 10. out = LN2(x1 + ff)  (fp32)
  ln2_kernel<<<dim3(NM), blk, 0, stream>>>(x1, ffout, ln2_g, ln2_b, (float*)d_out);
}

// Round 7
// 421.369 us; speedup vs baseline: 1.2919x; 1.0070x over previous
//
#include <hip/hip_runtime.h>
#include <hip/hip_bf16.h>
#include <math.h>
#include <type_traits>

typedef __hip_bfloat16 bf16;
typedef __attribute__((ext_vector_type(8))) short short8;
typedef __attribute__((ext_vector_type(4))) float f32x4;

// Problem constants
#define NB 4
#define NS 1024
#define ND 1024
#define NH 16
#define NDH 64
#define NR 64
#define NDFF 4096
#define NM (NB*NS)     // 4096 rows
#define NTOPK 204      // int(1024*0.2)

static __device__ __forceinline__ float b2f(bf16 x) { return __bfloat162float(x); }
static __device__ __forceinline__ bf16  f2b(float x) { return __float2bfloat16(x); }
static __device__ __forceinline__ unsigned short bfbits(float x) {
  bf16 h = __float2bfloat16(x);
  return *reinterpret_cast<unsigned short*>(&h);
}

// async global->LDS, 16B per lane; LDS dest = wave-uniform base + lane*16
static __device__ __forceinline__ void gload_lds16(const void* g, void* l) {
  __builtin_amdgcn_global_load_lds(
      (const __attribute__((address_space(1))) void*)g,
      (__attribute__((address_space(3))) void*)l, 16, 0, 0);
}

// counted vmcnt wait (T4): wait own outstanding VMEM ops <= N, leaving the
// newest N (the in-flight prefetch) pending across the following barrier.
template<int N> static __device__ __forceinline__ void vm_wait() {
  if constexpr (N == 0)       asm volatile("s_waitcnt vmcnt(0)" ::: "memory");
  else if constexpr (N == 2)  asm volatile("s_waitcnt vmcnt(2)" ::: "memory");
  else if constexpr (N == 4)  asm volatile("s_waitcnt vmcnt(4)" ::: "memory");
  else if constexpr (N == 6)  asm volatile("s_waitcnt vmcnt(6)" ::: "memory");
  else if constexpr (N == 8)  asm volatile("s_waitcnt vmcnt(8)" ::: "memory");
  else static_assert(N == 0, "unsupported vmcnt");
}
// raw barrier (no implicit vmcnt drain); memory clobber = compiler fence so
// LDS accesses cannot be moved across it.
static __device__ __forceinline__ void bar() {
  asm volatile("s_barrier" ::: "memory");
}

// 8 consecutive bf16 -> fp32 (one 16B load)
static __device__ __forceinline__ void ld8(const bf16* p, float* d) {
  const uint4 u = *(const uint4*)p;
  d[0] = __uint_as_float((u.x & 0xffffu) << 16);
  d[1] = __uint_as_float(u.x & 0xffff0000u);
  d[2] = __uint_as_float((u.y & 0xffffu) << 16);
  d[3] = __uint_as_float(u.y & 0xffff0000u);
  d[4] = __uint_as_float((u.z & 0xffffu) << 16);
  d[5] = __uint_as_float(u.z & 0xffff0000u);
  d[6] = __uint_as_float((u.w & 0xffffu) << 16);
  d[7] = __uint_as_float(u.w & 0xffff0000u);
}

static __device__ __forceinline__ float block_sum_256(float v, float* rbuf, int tid) {
  rbuf[tid] = v;
  __syncthreads();
  #pragma unroll
  for (int st = 128; st > 0; st >>= 1) {
    if (tid < st) rbuf[tid] += rbuf[tid + st];
    __syncthreads();
  }
  const float r = rbuf[0];
  __syncthreads();
  return r;
}

// ---------------------------------------------------------------------------
// Fused fp32 -> bf16 cast over up to 6 regions (each a multiple of 1024).
// ---------------------------------------------------------------------------
struct CastArgs {
  const float* in[6];
  bf16* out[6];
  unsigned end[6];   // cumulative block counts
};
__global__ __launch_bounds__(256) void cast6_kernel(CastArgs a) {
  const unsigned b = blockIdx.x;
  int r = 0; unsigned base = 0;
  #pragma unroll
  for (int k = 0; k < 5; ++k)
    if (b >= a.end[k]) { r = k + 1; base = a.end[k]; }
  const float* in = a.in[r];
  bf16* out = a.out[r];
  const unsigned i = ((b - base) * 256 + threadIdx.x) * 4;
  const float4 v = *(const float4*)(in + i);
  uint2 o;
  o.x = (unsigned)bfbits(v.x) | ((unsigned)bfbits(v.y) << 16);
  o.y = (unsigned)bfbits(v.z) | ((unsigned)bfbits(v.w) << 16);
  *(uint2*)(out + i) = o;
}

// ---------------------------------------------------------------------------
// Pack W[N][K] fp32 -> B-fragment-ordered bf16 blocks:
//   out[(nt*(K/32)+kt2)*512 + lane*8 + e] = W[nt*16+(lane&15)][kt2*32+(lane>>4)*8+e]
// so a GEMM wave's B-frag load is ONE contiguous 1KB global read (no LDS, no
// pow-2-stride pathology). grid (K/128, N/16), 256 thr (4 kt2-groups/block).
// ---------------------------------------------------------------------------
__global__ __launch_bounds__(256) void pack_w_kernel(
    const float* __restrict__ W, bf16* __restrict__ out, int K) {
  const int lane = threadIdx.x & 63, sub = threadIdx.x >> 6;
  const int kt2 = blockIdx.x * 4 + sub;
  const int nt  = blockIdx.y;
  const int lm = lane & 15, quad = lane >> 4;
  const float* p = W + (size_t)(nt * 16 + lm) * K + kt2 * 32 + quad * 8;
  const float4 a = *(const float4*)p;
  const float4 b = *(const float4*)(p + 4);
  uint4 o;
  o.x = (unsigned)bfbits(a.x) | ((unsigned)bfbits(a.y) << 16);
  o.y = (unsigned)bfbits(a.z) | ((unsigned)bfbits(a.w) << 16);
  o.z = (unsigned)bfbits(b.x) | ((unsigned)bfbits(b.y) << 16);
  o.w = (unsigned)bfbits(b.z) | ((unsigned)bfbits(b.w) << 16);
  *(uint4*)(out + (((size_t)(nt * (K >> 5) + kt2)) << 9) + lane * 8) = o;
}

// Concat Qp_w/Kp_w -> bf16 [128][1024], Qp_b/Kp_b -> fp32 [128]
__global__ __launch_bounds__(256) void pack_qk_kernel(
    const float* __restrict__ Qw, const float* __restrict__ Kw,
    const float* __restrict__ Qb, const float* __restrict__ Kb,
    bf16* __restrict__ w, float* __restrict__ bias) {
  const int r = blockIdx.x;  // 0..127
  const float* srcw = (r < 64) ? (Qw + (size_t)r * ND) : (Kw + (size_t)(r - 64) * ND);
  for (int i = threadIdx.x; i < ND; i += 256) w[(size_t)r * ND + i] = f2b(srcw[i]);
  if (r == 0)
    for (int i = threadIdx.x; i < 128; i += 256)
      bias[i] = (i < 64) ? Qb[i] : Kb[i - 64];
}

// ---------------------------------------------------------------------------
// Generic batched MFMA GEMM (2-phase 128-tile template): C = scale*(A@W^T)
// (+bias), bf16 in. A/B staged via global_load_lds (XOR-slot swizzle),
// double-buffered, counted-vmcnt 2-barrier pipeline. Used for steps 4/4b.
// ---------------------------------------------------------------------------
template<int BM, int BN, int BK, int BIAS, int RELU, int OUTF32>
__global__ __launch_bounds__(256) void mfma_gemm(
    const bf16* __restrict__ A, const bf16* __restrict__ W,
    const float* __restrict__ bias, void* __restrict__ C,
    int K, int lda, int ldb, int ldc,
    long long aHi, long long aLo, long long bHi, long long bLo,
    long long cHi, long long cLo, float scale)
{
  constexpr int WTM = BM / 2;
  constexpr int WTN = BN / 2;
  constexpr int AM = WTM / 16;
  constexpr int AN = WTN / 16;
  constexpr int KK = BK / 32;
  constexpr int SLOTS = BK / 8;
  constexpr int RPC = 512 / BK;
  constexpr int LPW = (BM * BK) / 2048 + (BN * BK) / 2048;
  __shared__ short As[2][BM * BK];
  __shared__ short Bs[2][BN * BK];
  const int tid  = threadIdx.x;
  const int lane = tid & 63;
  const int w    = tid >> 6;
  const int z    = blockIdx.z;
  const long long aOff = (long long)(z >> 4) * aHi + (long long)(z & 15) * aLo;
  const long long bOff = (long long)(z >> 4) * bHi + (long long)(z & 15) * bLo;
  const long long cOff = (long long)(z >> 4) * cHi + (long long)(z & 15) * cLo;

  int bx = blockIdx.x, by = blockIdx.y;
  if ((gridDim.x & 7) == 0) {
    const unsigned lin = blockIdx.y * gridDim.x + blockIdx.x;
    const unsigned Wd = gridDim.x >> 3;
    const unsigned xcd = lin & 7, i = lin >> 3;
    bx = (int)(xcd * Wd + (i % Wd));
    by = (int)(i / Wd);
  }
  const int m0 = by * BM;
  const int n0 = bx * BN;
  const int wr = w >> 1, wc = w & 1;
  const int lm = lane & 15, quad = lane >> 4;

  f32x4 acc[AM][AN];
  #pragma unroll
  for (int i = 0; i < AM; ++i)
    #pragma unroll
    for (int j = 0; j < AN; ++j) acc[i][j] = (f32x4){0.f, 0.f, 0.f, 0.f};

  const int slot = lane & (SLOTS - 1);
  const int sr   = lane / SLOTS;
  const int swz  = (BK == 32) ? ((sr >> 1) & 3) : (sr & 7);
  const int scol = (slot ^ swz) << 3;
  const int xv   = (BK == 32) ? ((lm >> 1) & 3) : (lm & 7);
  const bf16* Ab = A + aOff;
  const bf16* Bb = W + bOff;

  auto stage = [&](int buf, int k0) {
    #pragma unroll
    for (int t = 0; t < (BM * BK) / 2048; ++t) {
      const int row = w * (BM / 4) + t * RPC;
      gload_lds16(Ab + (long long)(m0 + row + sr) * lda + k0 + scol, &As[buf][row * BK]);
    }
    #pragma unroll
    for (int t = 0; t < (BN * BK) / 2048; ++t) {
      const int row = w * (BN / 4) + t * RPC;
      gload_lds16(Bb + (long long)(n0 + row + sr) * ldb + k0 + scol, &Bs[buf][row * BK]);
    }
  };
  auto compute = [&](int buf) {
    #pragma unroll
    for (int kk = 0; kk < KK; ++kk) {
      const int cb = ((kk * 4 + quad) ^ xv) << 3;
      short8 af[AM], bfr[AN];
      #pragma unroll
      for (int i = 0; i < AM; ++i)
        af[i] = *(const short8*)&As[buf][(wr * WTM + i * 16 + lm) * BK + cb];
      #pragma unroll
      for (int j = 0; j < AN; ++j)
        bfr[j] = *(const short8*)&Bs[buf][(wc * WTN + j * 16 + lm) * BK + cb];
      #pragma unroll
      for (int i = 0; i < AM; ++i)
        #pragma unroll
        for (int j = 0; j < AN; ++j)
          acc[i][j] = __builtin_amdgcn_mfma_f32_16x16x32_bf16(af[i], bfr[j], acc[i][j], 0, 0, 0);
    }
  };

  stage(0, 0);
  int cur = 0;
  for (int k0 = BK; k0 < K; k0 += BK) {
    stage(cur ^ 1, k0);
    vm_wait<LPW>();
    bar();
    compute(cur);
    bar();
    cur ^= 1;
  }
  vm_wait<0>();
  bar();
  compute(cur);

  #pragma unroll
  for (int i = 0; i < AM; ++i) {
    #pragma unroll
    for (int j = 0; j < AN; ++j) {
      const int n = n0 + wc * WTN + j * 16 + lm;
      const float bj = BIAS ? bias[n] : 0.f;
      #pragma unroll
      for (int rr = 0; rr < 4; ++rr) {
        const int m = m0 + wr * WTM + i * 16 + quad * 4 + rr;
        float v = acc[i][j][rr] * scale + bj;
        if (RELU) v = fmaxf(v, 0.f);
        const long long co = cOff + (long long)m * ldc + n;
        if (OUTF32) ((float*)C)[co] = v;
        else        ((bf16*)C)[co] = f2b(v);
      }
    }
  }
}

// ---------------------------------------------------------------------------
// Packed-B MFMA GEMM (steps 3/5/6b/9): C = A@Bp^T (+bias), bf16.
// The narrow-N GEMMs are LDS-BW-bound (R6 PMC arithmetic: 77% LDS-pipe util,
// MfmaUtil 21%). Fix: B comes from the fragment-packed layout (pack_w /
// step-5 PACKOUT) so each wave's B-frag is ONE contiguous 1KB global->VGPR
// load (L2-resident panel, no pow-2-stride TA serialization — the R4
// failure). A stays LDS-staged with the proven swizzle. LDS traffic/K-tile
// drops 73.7->48 KB; LDS 49152->32768 B.
// B regs double-buffered with STATIC indexing (integral_constant, rule #20).
// Pipeline per iter: stageA(nxt)+loadB(nxt); vmcnt(8); bar; compute(cur); bar.
// BM=128, BN=64, BK=64; 256 thr (2x2 waves, wave tile 64x32).
// PACKOUT=1: output stored fragment-packed per batch b=m>>10 (feeds 6b's B).
// ---------------------------------------------------------------------------
template<int BIAS, int RELU, int PACKOUT>
__global__ __launch_bounds__(256) void mfma_gemm_pb(
    const bf16* __restrict__ A, const bf16* __restrict__ Bp,
    const float* __restrict__ bias, bf16* __restrict__ C,
    int K, int lda, int ldc,
    long long aLo, long long bLo, long long cLo)
{
  __shared__ short As[2][128 * 64];   // 32 KB
  const int tid = threadIdx.x, lane = tid & 63, w = tid >> 6;
  const int z = blockIdx.z;
  const long long aOff = (long long)z * aLo;
  const long long cOff = (long long)z * cLo;
  int bx = blockIdx.x, by = blockIdx.y;
  if ((gridDim.x & 7) == 0) {
    const unsigned lin = blockIdx.y * gridDim.x + blockIdx.x;
    const unsigned Wd = gridDim.x >> 3;
    const unsigned xcd = lin & 7, i = lin >> 3;
    bx = (int)(xcd * Wd + (i % Wd));
    by = (int)(i / Wd);
  }
  const int m0 = by * 128, n0 = bx * 64;
  const int wr = w >> 1, wc = w & 1;
  const int lm = lane & 15, quad = lane >> 4;
  const int KT2 = K >> 5;

  f32x4 acc[4][2];
  #pragma unroll
  for (int i = 0; i < 4; ++i)
    #pragma unroll
    for (int j = 0; j < 2; ++j) acc[i][j] = (f32x4){0.f, 0.f, 0.f, 0.f};

  const int slot = lane & 7, sr = lane >> 3;
  const int scol = (slot ^ sr) << 3;   // A write-side swizzle (global col)
  const int xv   = lm & 7;             // A read-side swizzle
  const bf16* Ab = A + aOff;
  // B base: packed block (n/16-group) * KT2, + lane entry
  const bf16* Bb = Bp + (long long)z * bLo
                 + (((long long)(n0 / 16 + wc * 2) * KT2) << 9) + lane * 8;

  auto stageA = [&](int buf, int t) {
    const int k0 = t * 64;
    #pragma unroll
    for (int u = 0; u < 4; ++u) {
      const int row = w * 32 + u * 8;
      gload_lds16(Ab + (long long)(m0 + row + sr) * lda + k0 + scol, &As[buf][row * 64]);
    }
  };
  short8 brg[2][4];
  auto loadB = [&](auto BUF, int t) {
    constexpr int bu = decltype(BUF)::value;
    #pragma unroll
    for (int j = 0; j < 2; ++j)
      #pragma unroll
      for (int kk = 0; kk < 2; ++kk)
        brg[bu][j * 2 + kk] =
            *(const short8*)(Bb + (((long long)j * KT2 + t * 2 + kk) << 9));
  };
  auto compute = [&](auto BUF) {
    constexpr int bu = decltype(BUF)::value;
    #pragma unroll
    for (int kk = 0; kk < 2; ++kk) {
      const int cb = ((kk * 4 + quad) ^ xv) << 3;
      short8 af[4];
      #pragma unroll
      for (int i = 0; i < 4; ++i)
        af[i] = *(const short8*)&As[bu][(wr * 64 + i * 16 + lm) * 64 + cb];
      #pragma unroll
      for (int i = 0; i < 4; ++i)
        #pragma unroll
        for (int j = 0; j < 2; ++j)
          acc[i][j] = __builtin_amdgcn_mfma_f32_16x16x32_bf16(
              af[i], brg[bu][j * 2 + kk], acc[i][j], 0, 0, 0);
    }
  };
  const std::integral_constant<int, 0> B0{};
  const std::integral_constant<int, 1> B1{};

  const int nt = K / 64;               // >= 16, even
  stageA(0, 0); loadB(B0, 0);
  for (int t = 1; t + 1 < nt; t += 2) {
    stageA(1, t);     loadB(B1, t);
    vm_wait<8>(); bar(); compute(B0); bar();
    stageA(0, t + 1); loadB(B0, t + 1);
    vm_wait<8>(); bar(); compute(B1); bar();
  }
  stageA(1, nt - 1); loadB(B1, nt - 1);
  vm_wait<8>(); bar(); compute(B0); bar();
  vm_wait<0>(); bar(); compute(B1);

  #pragma unroll
  for (int i = 0; i < 4; ++i) {
    #pragma unroll
    for (int j = 0; j < 2; ++j) {
      const int n = n0 + wc * 32 + j * 16 + lm;
      const float bj = BIAS ? bias[n] : 0.f;
      float v0 = acc[i][j][0] + bj;
      float v1 = acc[i][j][1] + bj;
      float v2 = acc[i][j][2] + bj;
      float v3 = acc[i][j][3] + bj;
      if (RELU) {
        v0 = fmaxf(v0, 0.f); v1 = fmaxf(v1, 0.f);
        v2 = fmaxf(v2, 0.f); v3 = fmaxf(v3, 0.f);
      }
      const int mm = m0 + wr * 64 + i * 16 + quad * 4;
      if (PACKOUT) {
        // fragment-packed store: value(s=mm..+3, d=n) of W' = C^T per batch.
        // elem = b*NS*ND + ((d>>4)*(NS/32) + (s>>5))*512
        //        + (((s>>3)&3)*16 + (d&15))*8 + (s&7)
        const int b = mm >> 10, s = mm & 1023;
        bf16* dst = C + (long long)b * ((long long)NS * ND)
                  + (((long long)(n >> 4) * (NS >> 5) + (s >> 5)) << 9)
                  + (((s >> 3) & 3) * 16 + (n & 15)) * 8 + (s & 7);
        uint2 u;
        u.x = (unsigned)bfbits(v0) | ((unsigned)bfbits(v1) << 16);
        u.y = (unsigned)bfbits(v2) | ((unsigned)bfbits(v3) << 16);
        *(uint2*)dst = u;
      } else {
        C[cOff + (long long)(mm + 0) * ldc + n] = f2b(v0);
        C[cOff + (long long)(mm + 1) * ldc + n] = f2b(v1);
        C[cOff + (long long)(mm + 2) * ldc + n] = f2b(v2);
        C[cOff + (long long)(mm + 3) * ldc + n] = f2b(v3);
      }
    }
  }
}

// ---------------------------------------------------------------------------
// 256x256 8-phase GEMM (T3+T4+T5 port): C = A@W^T (+bias), bf16.
// 512 threads = 8 waves (2M x 4N); wave tile 128x64 (acc 8x4); BK=64;
// LDS = 128 KB -> 1 block/CU. Counted vmcnt, never 0 in main loop.
// VT=1: blocks with n0 >= 2*ND write transposed V into C2 (step 1).
// ---------------------------------------------------------------------------
template<int BIAS, int RELU, int VT>
__global__ __launch_bounds__(512) void mfma_gemm256(
    const bf16* __restrict__ A, const bf16* __restrict__ W,
    const float* __restrict__ bias, bf16* __restrict__ C,
    int K, int lda, int ldb, int ldc, bf16* __restrict__ C2)
{
  __shared__ short As[2][256 * 64];   // 64 KB
  __shared__ short Bs[2][256 * 64];   // 64 KB
  const int tid  = threadIdx.x;
  const int lane = tid & 63;
  const int w    = tid >> 6;          // 0..7
  int bx = blockIdx.x, by = blockIdx.y;
  if ((gridDim.x & 7) == 0) {
    const unsigned lin = blockIdx.y * gridDim.x + blockIdx.x;
    const unsigned Wd = gridDim.x >> 3;
    const unsigned xcd = lin & 7, i = lin >> 3;
    bx = (int)(xcd * Wd + (i % Wd));
    by = (int)(i / Wd);
  }
  const int m0 = by * 256;
  const int n0 = bx * 256;
  const int wr = w >> 2, wc = w & 3;  // wave grid 2(M) x 4(N)
  const int lm = lane & 15, quad = lane >> 4;

  f32x4 acc[8][4];
  #pragma unroll
  for (int i = 0; i < 8; ++i)
    #pragma unroll
    for (int j = 0; j < 4; ++j) acc[i][j] = (f32x4){0.f, 0.f, 0.f, 0.f};

  const int slot = lane & 7, sr = lane >> 3;
  const int scol = (slot ^ sr) << 3;   // swizzled global col (shorts)
  const int xv   = lm & 7;             // read-side swizzle

  auto stgA = [&](int buf, int c, int k0) {
    gload_lds16(A + (long long)(m0 + c * 64 + w * 8 + sr) * lda + k0 + scol,
                &As[buf][(c * 64 + w * 8) * 64]);
  };
  auto stgB = [&](int buf, int c, int k0) {
    gload_lds16(W + (long long)(n0 + c * 64 + w * 8 + sr) * ldb + k0 + scol,
                &Bs[buf][(c * 64 + w * 8) * 64]);
  };
  auto dsA = [&](short8* afr, int h, int buf) {      // 8 reads: A-half h
    #pragma unroll
    for (int i = 0; i < 4; ++i)
      #pragma unroll
      for (int kk = 0; kk < 2; ++kk)
        afr[i * 2 + kk] = *(const short8*)
            &As[buf][(wr * 128 + h * 64 + i * 16 + lm) * 64 + (((kk * 4 + quad) ^ xv) << 3)];
  };
  auto dsB = [&](short8* bfr, int jh, int buf) {     // 4 reads: B-half jh
    #pragma unroll
    for (int j = 0; j < 2; ++j)
      #pragma unroll
      for (int kk = 0; kk < 2; ++kk)
        bfr[j * 2 + kk] = *(const short8*)
            &Bs[buf][(wc * 64 + jh * 32 + j * 16 + lm) * 64 + (((kk * 4 + quad) ^ xv) << 3)];
  };
  auto mmaq = [&](auto H, auto JH, const short8* afr, const short8* bfr) {
    constexpr int h = decltype(H)::value, jh = decltype(JH)::value;
    __builtin_amdgcn_s_setprio(1);
    #pragma unroll
    for (int i = 0; i < 4; ++i)
      #pragma unroll
      for (int j = 0; j < 2; ++j)
        #pragma unroll
        for (int kk = 0; kk < 2; ++kk)
          acc[h * 4 + i][jh * 2 + j] = __builtin_amdgcn_mfma_f32_16x16x32_bf16(
              afr[i * 2 + kk], bfr[j * 2 + kk], acc[h * 4 + i][jh * 2 + j], 0, 0, 0);
    __builtin_amdgcn_s_setprio(0);
  };
  const std::integral_constant<int, 0> C0{};
  const std::integral_constant<int, 1> C1{};

  // prologue: stage tile 0 into buf 0 (age order matches steady state)
  stgB(0, 0, 0); stgB(0, 1, 0); stgB(0, 2, 0); stgB(0, 3, 0);
  stgA(0, 0, 0); stgA(0, 2, 0); stgA(0, 1, 0); stgA(0, 3, 0);
  vm_wait<0>();
  bar();

  const int NT = K / 64;
  int p = 0;
  for (int kt = 0; kt < NT; ++kt, p ^= 1) {
    const int k1 = (kt + 1) * 64;
    const bool pre = (kt + 1 < NT);
    short8 afr[8], bfrA[4], bfrB[4];
    // phase 1: quadrant (h0, j01)
    dsA(afr, 0, p); dsB(bfrA, 0, p);
    if (pre) { stgB(p ^ 1, 0, k1); stgB(p ^ 1, 1, k1); }
    bar();
    mmaq(C0, C0, afr, bfrA);
    bar();
    // phase 2: quadrant (h0, j23)
    dsB(bfrB, 1, p);
    if (pre) { stgB(p ^ 1, 2, k1); stgB(p ^ 1, 3, k1); vm_wait<4>(); }
    else vm_wait<0>();
    bar();
    mmaq(C0, C1, afr, bfrB);
    bar();
    // phase 3: quadrant (h1, j01)
    dsA(afr, 1, p);
    if (pre) { stgA(p ^ 1, 0, k1); stgA(p ^ 1, 2, k1); }
    bar();
    mmaq(C1, C0, afr, bfrA);
    bar();
    // phase 4: quadrant (h1, j23)
    if (pre) { stgA(p ^ 1, 1, k1); stgA(p ^ 1, 3, k1); vm_wait<2>(); }
    else vm_wait<0>();
    bar();
    mmaq(C1, C1, afr, bfrB);
    bar();
  }

  // epilogue
  #pragma unroll
  for (int i = 0; i < 8; ++i) {
    #pragma unroll
    for (int j = 0; j < 4; ++j) {
      const int n = n0 + wc * 64 + j * 16 + lm;
      const float bj = BIAS ? bias[n] : 0.f;
      float v0 = acc[i][j][0] + bj;
      float v1 = acc[i][j][1] + bj;
      float v2 = acc[i][j][2] + bj;
      float v3 = acc[i][j][3] + bj;
      if (RELU) {
        v0 = fmaxf(v0, 0.f); v1 = fmaxf(v1, 0.f);
        v2 = fmaxf(v2, 0.f); v3 = fmaxf(v3, 0.f);
      }
      const int mm = m0 + wr * 128 + i * 16 + quad * 4;
      if (VT && n0 >= 2 * ND) {
        const int h = (n - 2 * ND) >> 6, d = (n - 2 * ND) & 63;
        uint2 u;
        u.x = (unsigned)bfbits(v0) | ((unsigned)bfbits(v1) << 16);
        u.y = (unsigned)bfbits(v2) | ((unsigned)bfbits(v3) << 16);
        bf16* dst = C2 + (long long)((mm >> 10) * NH + h) * (NDH * NS)
                       + (long long)d * NS + (mm & 1023);
        *(uint2*)dst = u;
      } else {
        C[(long long)(mm + 0) * ldc + n] = f2b(v0);
        C[(long long)(mm + 1) * ldc + n] = f2b(v1);
        C[(long long)(mm + 2) * ldc + n] = f2b(v2);
        C[(long long)(mm + 3) * ldc + n] = f2b(v3);
      }
    }
  }
}

// ---------------------------------------------------------------------------
// Fused flash attention (dense MHA): per (q-tile of 128, b, h) block.
// Swapped QK^T -> S^T frags (q = lane&15); online softmax via 2 shfl_xor;
// P^T bf16 B-frags built in-register via shfl. K/V^T staged via
// global_load_lds + XOR slot swizzle; counted-vmcnt 2-barrier pipeline.
// grid (NS/128, NB*NH), 256 threads.
// ---------------------------------------------------------------------------
__global__ __launch_bounds__(256) void attn_kernel(
    const bf16* __restrict__ qkv,   // [B][S][3*ND]
    const bf16* __restrict__ Vt,    // [B*H][NDH][NS]
    bf16* __restrict__ ctx)         // [B][S][ND]
{
  __shared__ short smem[2][2][64 * 64];   // [buf][K|V][4096] = 32 KB
  const int tid = threadIdx.x, lane = tid & 63, w = tid >> 6;
  const int lm = lane & 15, quad = lane >> 4;
  const int z = blockIdx.y, b = z >> 4, h = z & 15;
  const int q0 = blockIdx.x * 128;
  const bf16* Qb = qkv + (long long)b * NS * 3072 + h * 64;
  const bf16* Kb = Qb + ND;
  const bf16* Vb = Vt + (long long)z * (NDH * NS);

  // Q B-frags [j][kk]: col q = q0 + w*32 + j*16 + lm, k(d) = kk*32 + quad*8 + e
  short8 qf[2][2];
  #pragma unroll
  for (int j = 0; j < 2; ++j)
    #pragma unroll
    for (int kk = 0; kk < 2; ++kk)
      qf[j][kk] = *(const short8*)(Qb + (long long)(q0 + w * 32 + j * 16 + lm) * 3072
                                      + kk * 32 + quad * 8);

  // staging map (8 slots of 16B per 64-elem row; 8 rows per issue per wave)
  const int slot = lane & 7, sr = lane >> 3;
  const int scol = (slot ^ sr) << 3;      // shorts; involution with read side

  auto stage = [&](int buf, int t) {
    #pragma unroll
    for (int u = 0; u < 2; ++u) {
      const int row = w * 16 + u * 8;     // kv row within tile
      gload_lds16(Kb + (long long)(t * 64 + row + sr) * 3072 + scol,
                  &smem[buf][0][row * 64]);
    }
    #pragma unroll
    for (int u = 0; u < 2; ++u) {
      const int row = w * 16 + u * 8;     // d row
      gload_lds16(Vb + (long long)(row + sr) * NS + t * 64 + scol,
                  &smem[buf][1][row * 64]);
    }
  };

  f32x4 o[4][2];                          // O^T: d-tile i, q-tile j
  #pragma unroll
  for (int i = 0; i < 4; ++i)
    #pragma unroll
    for (int j = 0; j < 2; ++j) o[i][j] = (f32x4){0.f, 0.f, 0.f, 0.f};
  float m[2] = {-1e30f, -1e30f}, l[2] = {0.f, 0.f};

  stage(0, 0);
  for (int t = 0; t < 16; ++t) {
    const int buf = t & 1;
    if (t < 15) { stage(buf ^ 1, t + 1); vm_wait<4>(); }
    else        { vm_wait<0>(); }
    bar();                                // tile t's loads visible to all

    // --- S^T = (K @ Q^T)/8 : st[i][j], i = kv-tile, j = q-tile
    f32x4 st[4][2];
    #pragma unroll
    for (int i = 0; i < 4; ++i)
      #pragma unroll
      for (int j = 0; j < 2; ++j) st[i][j] = (f32x4){0.f, 0.f, 0.f, 0.f};
    #pragma unroll
    for (int kk = 0; kk < 2; ++kk) {
      const int cb = ((kk * 4 + quad) ^ (lm & 7)) << 3;
      short8 ka[4];
      #pragma unroll
      for (int i = 0; i < 4; ++i)
        ka[i] = *(const short8*)&smem[buf][0][(i * 16 + lm) * 64 + cb];
      #pragma unroll
      for (int i = 0; i < 4; ++i)
        #pragma unroll
        for (int j = 0; j < 2; ++j)
          st[i][j] = __builtin_amdgcn_mfma_f32_16x16x32_bf16(ka[i], qf[j][kk], st[i][j], 0, 0, 0);
    }

    // --- online softmax per q-col (j); kv spread over 16 regs x 4 quads
    #pragma unroll
    for (int j = 0; j < 2; ++j) {
      float pm = -1e30f;
      #pragma unroll
      for (int i = 0; i < 4; ++i)
        #pragma unroll
        for (int r = 0; r < 4; ++r) {
          st[i][j][r] *= 0.125f;
          pm = fmaxf(pm, st[i][j][r]);
        }
      pm = fmaxf(pm, __shfl_xor(pm, 16, 64));
      pm = fmaxf(pm, __shfl_xor(pm, 32, 64));
      const float mn = fmaxf(m[j], pm);
      const float sc = __expf(m[j] - mn);
      float ps = 0.f;
      #pragma unroll
      for (int i = 0; i < 4; ++i)
        #pragma unroll
        for (int r = 0; r < 4; ++r) {
          const float e = __expf(st[i][j][r] - mn);
          st[i][j][r] = e;                 // st now holds P^T
          ps += e;
        }
      ps += __shfl_xor(ps, 16, 64);
      ps += __shfl_xor(ps, 32, 64);
      l[j] = l[j] * sc + ps;
      m[j] = mn;
      #pragma unroll
      for (int i = 0; i < 4; ++i)
        #pragma unroll
        for (int r = 0; r < 4; ++r) o[i][j][r] *= sc;
    }

    // --- pack P^T to bf16 pairs: u0 = (r0,r1), u1 = (r2,r3)
    unsigned u0[4][2], u1[4][2];
    #pragma unroll
    for (int i = 0; i < 4; ++i)
      #pragma unroll
      for (int j = 0; j < 2; ++j) {
        u0[i][j] = (unsigned)bfbits(st[i][j][0]) | ((unsigned)bfbits(st[i][j][1]) << 16);
        u1[i][j] = (unsigned)bfbits(st[i][j][2]) | ((unsigned)bfbits(st[i][j][3]) << 16);
      }
    // target frag (kk,j) elem e: kv = kk*32+quad*8+e comes from
    //   i_src = kk*2 + (quad>>1), src lane = ((quad&1)*2 + (e>>2))*16 + lm, r = e&3
    const int s0l = ((quad & 1) * 2) * 16 + lm;
    const int s1l = s0l + 16;
    const bool hi = (quad >> 1) != 0;

    // --- O^T += V^T @ P^T
    #pragma unroll
    for (int kk = 0; kk < 2; ++kk) {
      short8 pf[2];
      #pragma unroll
      for (int j = 0; j < 2; ++j) {
        const unsigned a0 = __shfl(u0[kk * 2][j],     s0l, 64);
        const unsigned a1 = __shfl(u1[kk * 2][j],     s0l, 64);
        const unsigned b0 = __shfl(u0[kk * 2 + 1][j], s0l, 64);
        const unsigned b1 = __shfl(u1[kk * 2 + 1][j], s0l, 64);
        const unsigned c0 = __shfl(u0[kk * 2][j],     s1l, 64);
        const unsigned c1 = __shfl(u1[kk * 2][j],     s1l, 64);
        const unsigned d0 = __shfl(u0[kk * 2 + 1][j], s1l, 64);
        const unsigned d1 = __shfl(u1[kk * 2 + 1][j], s1l, 64);
        union { uint4 u; short8 s; } cv;
        cv.u.x = hi ? b0 : a0; cv.u.y = hi ? b1 : a1;
        cv.u.z = hi ? d0 : c0; cv.u.w = hi ? d1 : c1;
        pf[j] = cv.s;
      }
      const int cb = ((kk * 4 + quad) ^ (lm & 7)) << 3;
      short8 va[4];
      #pragma unroll
      for (int i = 0; i < 4; ++i)
        va[i] = *(const short8*)&smem[buf][1][(i * 16 + lm) * 64 + cb];
      #pragma unroll
      for (int i = 0; i < 4; ++i)
        #pragma unroll
        for (int j = 0; j < 2; ++j)
          o[i][j] = __builtin_amdgcn_mfma_f32_16x16x32_bf16(va[i], pf[j], o[i][j], 0, 0, 0);
    }
    bar();   // all waves done reading buf before next overwrite / epilogue
  }

  // --- epilogue: normalize, transpose O^T -> O through LDS, coalesced store
  short (*OL)[72] = (short(*)[72])&smem[0][0][0];   // 128 x 72 = 18.4 KB
  #pragma unroll
  for (int j = 0; j < 2; ++j) {
    const float inv = 1.f / l[j];
    #pragma unroll
    for (int i = 0; i < 4; ++i) {
      uint2 u;
      u.x = (unsigned)bfbits(o[i][j][0] * inv) | ((unsigned)bfbits(o[i][j][1] * inv) << 16);
      u.y = (unsigned)bfbits(o[i][j][2] * inv) | ((unsigned)bfbits(o[i][j][3] * inv) << 16);
      *(uint2*)&OL[w * 32 + j * 16 + lm][i * 16 + quad * 4] = u;
    }
  }
  __syncthreads();
  {
    const int q = tid >> 1, c = (tid & 1) * 32;
    const uint4 r0 = *(const uint4*)&OL[q][c];
    const uint4 r1 = *(const uint4*)&OL[q][c + 8];
    const uint4 r2 = *(const uint4*)&OL[q][c + 16];
    const uint4 r3 = *(const uint4*)&OL[q][c + 24];
    bf16* dst = ctx + ((long long)(b * NS + q0 + q)) * 1024 + h * 64 + c;
    ((uint4*)dst)[0] = r0; ((uint4*)dst)[1] = r1;
    ((uint4*)dst)[2] = r2; ((uint4*)dst)[3] = r3;
  }
}

// ---------------------------------------------------------------------------
// Sparse top-k selection from precomputed fp32 scores S[row][1024].
// One WAVE per row (4 rows/block); wave-local radix select.
// ---------------------------------------------------------------------------
__global__ __launch_bounds__(256) void sparse_select_kernel(
    const float* __restrict__ S, bf16* __restrict__ aw)
{
  __shared__ unsigned hist[4][256];
  const int tid = threadIdx.x;
  const int lane = tid & 63;
  const int wv = tid >> 6;
  const long long row = (long long)blockIdx.x * 4 + wv;

  float sv[16];
  const float* sp = S + row * 1024 + lane * 16;
  #pragma unroll
  for (int c = 0; c < 4; ++c) {
    const float4 v = ((const float4*)sp)[c];
    sv[4*c] = v.x; sv[4*c+1] = v.y; sv[4*c+2] = v.z; sv[4*c+3] = v.w;
  }
  unsigned key[16];
  #pragma unroll
  for (int j = 0; j < 16; ++j) {
    const unsigned u = __float_as_uint(sv[j]);
    key[j] = (u & 0x80000000u) ? ~u : (u | 0x80000000u);  // order-preserving
  }

  unsigned pref = 0u;
  int need = NTOPK;
  #pragma unroll
  for (int p = 3; p >= 0; --p) {
    *(uint4*)&hist[wv][lane * 4] = (uint4){0u, 0u, 0u, 0u};
    __syncthreads();
    const int sh = (p + 1) * 8;
    #pragma unroll
    for (int j = 0; j < 16; ++j) {
      const bool part = (p == 3) || ((key[j] >> sh) == pref);
      if (part) atomicAdd(&hist[wv][(key[j] >> (p * 8)) & 255u], 1u);
    }
    __syncthreads();
    const unsigned h0 = hist[wv][4*lane],     h1 = hist[wv][4*lane + 1];
    const unsigned h2 = hist[wv][4*lane + 2], h3 = hist[wv][4*lane + 3];
    const unsigned s3 = h3, s2 = h2 + s3, s1 = h1 + s2, s0 = h0 + s1;
    unsigned sum = s0;                      // suffix sum over lanes >= lane
    #pragma unroll
    for (int d2 = 1; d2 < 64; d2 <<= 1) {
      const unsigned t = __shfl_down(sum, d2, 64);
      if (lane < 64 - d2) sum += t;
    }
    const unsigned above = sum - s0;
    const unsigned cum[4]  = {above + s0, above + s1, above + s2, above + s3};
    const unsigned next[4] = {above + s1, above + s2, above + s3, above};
    unsigned candPref = 0u; int candNeed = 0; bool has = false;
    #pragma unroll
    for (int i = 0; i < 4; ++i) {
      if ((int)cum[i] >= need && (int)next[i] < need) {
        has = true;
        candPref = (pref << 8) | (unsigned)(4 * lane + i);
        candNeed = need - (int)next[i];
      }
    }
    const unsigned long long m = __ballot(has);
    const int srcLane = (int)(__ffsll((long long)m) - 1);
    pref = (unsigned)__shfl((int)candPref, srcLane, 64);
    need = __shfl(candNeed, srcLane, 64);
  }

  const unsigned T = pref;                  // 204th-largest key
  const unsigned tb = (T & 0x80000000u) ? (T ^ 0x80000000u) : ~T;
  const float thr = __uint_as_float(tb);

  float wvv[16];
  float psTop = 0.f, psAll = 0.f;
  #pragma unroll
  for (int j = 0; j < 16; ++j) {
    const float e = __expf(sv[j] - thr);
    psAll += e;
    const float wt = (key[j] >= T) ? e : 0.f;
    psTop += wt;
    wvv[j] = wt;
  }
  #pragma unroll
  for (int s = 1; s < 64; s <<= 1) {
    psTop += __shfl_xor(psTop, s, 64);
    psAll += __shfl_xor(psAll, s, 64);
  }
  const float inv = 1.f / (psTop + 1e-9f * psAll);

  uint4 o0, o1;
  o0.x = (unsigned)bfbits(wvv[0]*inv)  | ((unsigned)bfbits(wvv[1]*inv)  << 16);
  o0.y = (unsigned)bfbits(wvv[2]*inv)  | ((unsigned)bfbits(wvv[3]*inv)  << 16);
  o0.z = (unsigned)bfbits(wvv[4]*inv)  | ((unsigned)bfbits(wvv[5]*inv)  << 16);
  o0.w = (unsigned)bfbits(wvv[6]*inv)  | ((unsigned)bfbits(wvv[7]*inv)  << 16);
  o1.x = (unsigned)bfbits(wvv[8]*inv)  | ((unsigned)bfbits(wvv[9]*inv)  << 16);
  o1.y = (unsigned)bfbits(wvv[10]*inv) | ((unsigned)bfbits(wvv[11]*inv) << 16);
  o1.z = (unsigned)bfbits(wvv[12]*inv) | ((unsigned)bfbits(wvv[13]*inv) << 16);
  o1.w = (unsigned)bfbits(wvv[14]*inv) | ((unsigned)bfbits(wvv[15]*inv) << 16);
  bf16* op = aw + row * 1024 + lane * 16;
  ((uint4*)op)[0] = o0; ((uint4*)op)[1] = o1;
}

// ---------------------------------------------------------------------------
// fused = sig*dense + (1-sig)*sparse ; x1 = LN1(src + fused)  (bf16 out)
// ---------------------------------------------------------------------------
__global__ __launch_bounds__(256) void fuse_ln1_kernel(
    const float* __restrict__ src, const bf16* __restrict__ dense,
    const bf16* __restrict__ sparse, const float* __restrict__ lam,
    const float* __restrict__ g, const float* __restrict__ beta,
    bf16* __restrict__ x1)
{
  __shared__ float y[ND];
  __shared__ float rbuf[256];
  const int tid = threadIdx.x;
  const size_t base = (size_t)blockIdx.x * ND;
  const float sig = 1.f / (1.f + __expf(-lam[0]));
  const float c1 = 1.f - sig;
  float s1 = 0.f, s2 = 0.f;
  #pragma unroll
  for (int j = 0; j < 4; ++j) {
    const int i = tid + (j << 8);
    const float v = src[base + i] + sig * b2f(dense[base + i]) + c1 * b2f(sparse[base + i]);
    y[i] = v; s1 += v; s2 += v * v;
  }
  const float sum1 = block_sum_256(s1, rbuf, tid);
  const float sum2 = block_sum_256(s2, rbuf, tid);
  const float mean = sum1 * (1.f / ND);
  const float var  = sum2 * (1.f / ND) - mean * mean;
  const float rstd = rsqrtf(var + 1e-5f);
  #pragma unroll
  for (int j = 0; j < 4; ++j) {
    const int i = tid + (j << 8);
    x1[base + i] = f2b((y[i] - mean) * rstd * g[i] + beta[i]);
  }
}

// out = LN2(x1 + ff)  (fp32 out; ff is bf16)
__global__ __launch_bounds__(256) void ln2_kernel(
    const bf16* __restrict__ x1, const bf16* __restrict__ ff,
    const float* __restrict__ g, const float* __restrict__ beta,
    float* __restrict__ outp)
{
  __shared__ float y[ND];
  __shared__ float rbuf[256];
  const int tid = threadIdx.x;
  const size_t base = (size_t)blockIdx.x * ND;
  float s1 = 0.f, s2 = 0.f;
  #pragma unroll
  for (int j = 0; j < 4; ++j) {
    const int i = tid + (j << 8);
    const float v = b2f(x1[base + i]) + b2f(ff[base + i]);
    y[i] = v; s1 += v; s2 += v * v;
  }
  const float sum1 = block_sum_256(s1, rbuf, tid);
  const float sum2 = block_sum_256(s2, rbuf, tid);
  const float mean = sum1 * (1.f / ND);
  const float var  = sum2 * (1.f / ND) - mean * mean;
  const float rstd = rsqrtf(var + 1e-5f);
  #pragma unroll
  for (int j = 0; j < 4; ++j) {
    const int i = tid + (j << 8);
    outp[base + i] = (y[i] - mean) * rstd * g[i] + beta[i];
  }
}

// ---------------------------------------------------------------------------
extern "C" void kernel_launch(void* const* d_in, const int* in_sizes, int n_in,
                              void* d_out, int out_size, void* d_ws, size_t ws_size,
                              hipStream_t stream)
{
  const float* src        = (const float*)d_in[0];
  const float* in_proj_w  = (const float*)d_in[1];
  const float* in_proj_b  = (const float*)d_in[2];
  const float* out_proj_w = (const float*)d_in[3];
  const float* out_proj_b = (const float*)d_in[4];
  const float* Qp_w  = (const float*)d_in[5];
  const float* Qp_b  = (const float*)d_in[6];
  const float* Kp_w  = (const float*)d_in[7];
  const float* Kp_b  = (const float*)d_in[8];
  const float* Vp_w  = (const float*)d_in[9];
  const float* Vp_b  = (const float*)d_in[10];
  const float* lam   = (const float*)d_in[11];
  const float* ff1_w = (const float*)d_in[12];
  const float* ff1_b = (const float*)d_in[13];
  const float* ff2_w = (const float*)d_in[14];
  const float* ff2_b = (const float*)d_in[15];
  const float* ln1_g = (const float*)d_in[16];
  const float* ln1_b = (const float*)d_in[17];
  const float* ln2_g = (const float*)d_in[18];
  const float* ln2_b = (const float*)d_in[19];
  (void)in_sizes; (void)n_in; (void)out_size; (void)ws_size;

  // --------- workspace layout (offsets IDENTICAL to the proven layout;
  // w_out/w_vp/w_ff2 slots now hold the fragment-PACKED weights)
  char* ws = (char*)d_ws;
  size_t off = 0;
  auto take = [&](size_t bytes) -> void* {
    void* p = ws + off; off += (bytes + 255) & ~(size_t)255; return p;
  };
  bf16*  src_bf  = (bf16*) take((size_t)NM * ND * 2);          //  8.4 MB
  bf16*  w_qkv   = (bf16*) take((size_t)3 * ND * ND * 2);      //  6.3 MB
  bf16*  w_out_p = (bf16*) take((size_t)ND * ND * 2);          //  2.1 MB (packed)
  bf16*  w_vp_p  = (bf16*) take((size_t)ND * ND * 2);          //  2.1 MB (packed)
  bf16*  w_ff1   = (bf16*) take((size_t)NDFF * ND * 2);        //  8.4 MB
  bf16*  w_ff2_p = (bf16*) take((size_t)ND * NDFF * 2);        //  8.4 MB (packed)
  bf16*  w_qk    = (bf16*) take((size_t)128 * ND * 2);         //  0.26 MB
  float* bias_qk = (float*)take(128 * 4);
  const size_t mark = off;                                     // reuse point
  bf16*  qkv     = (bf16*) take((size_t)NM * 3 * ND * 2);      // 25.2 MB [dead after attn]
  bf16*  Vt_all  = (bf16*) take((size_t)NH * NS * NS * 2);     // slot 33.5 MB (uses 8.4) [dead after attn]
  bf16*  Vt_old  = (bf16*) take((size_t)NH * NDH * NS * 2);    //  2.1 MB [unused slot, keeps offsets]
  bf16*  ctx     = (bf16*) take((size_t)NM * ND * 2);          //  8.4 MB [dead after step 3]
  bf16*  dense   = (bf16*) take((size_t)NM * ND * 2);          //  8.4 MB
  bf16*  QKs_bf  = (bf16*) take((size_t)NM * 128 * 2);         //  1.05 MB
  bf16*  Vsp     = (bf16*) take((size_t)NM * ND * 2);          //  8.4 MB [unused slot now]
  bf16*  sparse  = (bf16*) take((size_t)NM * ND * 2);          //  8.4 MB
  (void)Vt_old; (void)Vsp;
  // aliases into dead regions (qkv+Vt_all dead after the attention):
  bf16*  x1    = (bf16*)(ws + mark);                                       // [0, 8.4M)
  bf16*  h1    = (bf16*)(ws + mark + (size_t)NM * ND * 2);                 // [8.4, 42.0M)
  bf16*  ffout = (bf16*)(ws + mark + (size_t)NM * ND * 2 + (size_t)NM * NDFF * 2); // [42.0, 50.4M)
  bf16*  aw    = (bf16*)(ws + mark + 2 * (size_t)NM * ND * 2 + (size_t)NM * NDFF * 2); // [50.4, 58.8M)
  float* S_sp  = (float*)(ws + mark + (size_t)NM * ND * 2);    // [8.4, 25.2M): written 4b,
                                                               // read 6a, dead before h1
  bf16*  Vsp_pk = (bf16*)ctx;  // ctx dead after step 3; step 5 writes PACKED here

  const dim3 blk(256);
  bf16* const NOC2 = nullptr;
  // 0a. fp32 -> bf16 casts (3 regions: src, in_proj_w, ff1_w; 11264 blocks)
  {
    CastArgs a;
    a.in[0] = src;        a.out[0] = src_bf;  // 4096 blocks
    a.in[1] = in_proj_w;  a.out[1] = w_qkv;   // 3072
    a.in[2] = ff1_w;      a.out[2] = w_ff1;   // 4096
    a.in[3] = src;        a.out[3] = src_bf;  // unused
    a.in[4] = src;        a.out[4] = src_bf;  // unused
    a.in[5] = src;        a.out[5] = src_bf;  // unused
    a.end[0] = 4096; a.end[1] = 7168; a.end[2] = 11264;
    a.end[3] = 11264; a.end[4] = 11264; a.end[5] = 11264;
    cast6_kernel<<<dim3(11264), blk, 0, stream>>>(a);
  }
  // 0b. fragment-pack the B-side weights (fp32 -> packed bf16)
  pack_w_kernel<<<dim3(ND/128,   ND/16), blk, 0, stream>>>(out_proj_w, w_out_p, ND);
  pack_w_kernel<<<dim3(ND/128,   ND/16), blk, 0, stream>>>(Vp_w,       w_vp_p,  ND);
  pack_w_kernel<<<dim3(NDFF/128, ND/16), blk, 0, stream>>>(ff2_w,      w_ff2_p, NDFF);
  pack_qk_kernel<<<dim3(128), blk, 0, stream>>>(Qp_w, Kp_w, Qp_b, Kp_b, w_qk, bias_qk);

  // 1. qkv = src @ in_proj^T + b  [4096,3072] bf16, 256-tile 8-phase kernel
  //    (192 blocks, 512 thr); V third written TRANSPOSED into Vt_all (VT=1).
  mfma_gemm256<1,0,1><<<dim3(3*ND/256, NM/256), dim3(512), 0, stream>>>(
      src_bf, w_qkv, in_proj_b, qkv, ND, ND, ND, 3*ND, Vt_all);

  // 2. dense MHA: fused flash attention (Vt_all already populated by step 1)
  attn_kernel<<<dim3(NS/128, NB*NH), blk, 0, stream>>>(qkv, Vt_all, ctx);

  // 3. dense_output = ctx @ out_proj^T + b  (packed-B kernel; 512 blocks)
  mfma_gemm_pb<1,0,0><<<dim3(ND/64, NM/128, 1), blk, 0, stream>>>(
      ctx, w_out_p, out_proj_b, dense, ND, ND, ND, 0, 0, 0);
  // 4. QKs_bf = src @ [Qp;Kp]^T + b  (bf16 [4096][128]; 64 blocks, old path)
  mfma_gemm<128,64,64,1,0,0><<<dim3(2, NM/128, 1), blk, 0, stream>>>(
      src_bf, w_qk, bias_qk, QKs_bf, ND, ND, ND, 128, 0,0, 0,0, 0,0, 1.f);
  // 4b. S_sp[b] = (Qs Ks^T)/8  fp32, batched over b (single K-tile at BK=64)
  mfma_gemm<128,64,64,0,0,1><<<dim3(NS/64, NS/128, NB), blk, 0, stream>>>(
      QKs_bf, QKs_bf + 64, nullptr, S_sp, 64, 128, 128, NS,
      0, (long long)NS*128, 0, (long long)NS*128, 0, (long long)NS*NS, 0.125f);
  // 5. Vsp packed: (src @ Vp^T + b) stored in FRAGMENT-PACKED form per batch
  //    (PACKOUT=1) into the ctx slot — feeds step 6b's B directly.
  mfma_gemm_pb<1,0,1><<<dim3(ND/64, NM/128, 1), blk, 0, stream>>>(
      src_bf, w_vp_p, Vp_b, Vsp_pk, ND, ND, 0, 0, 0, 0);
  // 6a. top-k select + normalized weights -> aw (bf16), one wave per row
  sparse_select_kernel<<<dim3(NM/4), blk, 0, stream>>>(S_sp, aw);
  // 6b. sparse = aw @ Vsp^T  (batched per b; packed-B; 512 blocks)
  mfma_gemm_pb<0,0,0><<<dim3(ND/64, NS/128, NB), blk, 0, stream>>>(
      aw, Vsp_pk, nullptr, sparse, NS, NS, ND,
      (long long)NS*ND, (long long)NS*ND, (long long)NS*ND);
  // 7. fuse + residual + LN1 -> x1 (bf16)  [qkv/Vt_all dead; x1 aliases them]
  fuse_ln1_kernel<<<dim3(NM), blk, 0, stream>>>(src, dense, sparse, lam, ln1_g, ln1_b, x1);
  // 8. h1 = relu(x1 @ ff1^T + b)  (bf16; 256-tile 8-phase, 256 blocks = 1/CU)
  mfma_gemm256<1,1,0><<<dim3(NDFF/256, NM/256), dim3(512), 0, stream>>>(
      x1, w_ff1, ff1_b, h1, ND, ND, ND, NDFF, NOC2);
  // 9. ff = h1 @ ff2^T + b  (packed-B kernel; K=4096; 512 blocks)
  mfma_gemm_pb<1,0,0><<<dim3(ND/64, NM/128, 1), blk, 0, stream>>>(
      h1, w_ff2_p, ff2_b, ffout, NDFF, NDFF, ND, 0, 0, 0);
  // 10. out = LN2(x1 + ff)  (fp32)
  ln2_kernel<<<dim3(NM), blk, 0, stream>>>(x1, ffout, ln2_g, ln2_b, (float*)d_out);
}

// Round 8
// 413.756 us; speedup vs baseline: 1.3157x; 1.0184x over previous
//
#include <hip/hip_runtime.h>
#include <hip/hip_bf16.h>
#include <math.h>
#include <type_traits>

typedef __hip_bfloat16 bf16;
typedef __attribute__((ext_vector_type(8))) short short8;
typedef __attribute__((ext_vector_type(4))) float f32x4;

// Problem constants
#define NB 4
#define NS 1024
#define ND 1024
#define NH 16
#define NDH 64
#define NR 64
#define NDFF 4096
#define NM (NB*NS)     // 4096 rows
#define NTOPK 204      // int(1024*0.2)

static __device__ __forceinline__ float b2f(bf16 x) { return __bfloat162float(x); }
static __device__ __forceinline__ bf16  f2b(float x) { return __float2bfloat16(x); }
static __device__ __forceinline__ unsigned short bfbits(float x) {
  bf16 h = __float2bfloat16(x);
  return *reinterpret_cast<unsigned short*>(&h);
}

// async global->LDS, 16B per lane; LDS dest = wave-uniform base + lane*16
static __device__ __forceinline__ void gload_lds16(const void* g, void* l) {
  __builtin_amdgcn_global_load_lds(
      (const __attribute__((address_space(1))) void*)g,
      (__attribute__((address_space(3))) void*)l, 16, 0, 0);
}

// counted vmcnt wait (T4): wait own outstanding VMEM ops <= N, leaving the
// newest N (the in-flight prefetch) pending across the following barrier.
template<int N> static __device__ __forceinline__ void vm_wait() {
  if constexpr (N == 0)       asm volatile("s_waitcnt vmcnt(0)" ::: "memory");
  else if constexpr (N == 2)  asm volatile("s_waitcnt vmcnt(2)" ::: "memory");
  else if constexpr (N == 4)  asm volatile("s_waitcnt vmcnt(4)" ::: "memory");
  else if constexpr (N == 6)  asm volatile("s_waitcnt vmcnt(6)" ::: "memory");
  else if constexpr (N == 8)  asm volatile("s_waitcnt vmcnt(8)" ::: "memory");
  else static_assert(N == 0, "unsupported vmcnt");
}
// raw barrier (no implicit vmcnt drain); memory clobber = compiler fence so
// LDS accesses cannot be moved across it.
static __device__ __forceinline__ void bar() {
  asm volatile("s_barrier" ::: "memory");
}

// 8 consecutive bf16 -> fp32 (one 16B load)
static __device__ __forceinline__ void ld8(const bf16* p, float* d) {
  const uint4 u = *(const uint4*)p;
  d[0] = __uint_as_float((u.x & 0xffffu) << 16);
  d[1] = __uint_as_float(u.x & 0xffff0000u);
  d[2] = __uint_as_float((u.y & 0xffffu) << 16);
  d[3] = __uint_as_float(u.y & 0xffff0000u);
  d[4] = __uint_as_float((u.z & 0xffffu) << 16);
  d[5] = __uint_as_float(u.z & 0xffff0000u);
  d[6] = __uint_as_float((u.w & 0xffffu) << 16);
  d[7] = __uint_as_float(u.w & 0xffff0000u);
}

static __device__ __forceinline__ float block_sum_256(float v, float* rbuf, int tid) {
  rbuf[tid] = v;
  __syncthreads();
  #pragma unroll
  for (int st = 128; st > 0; st >>= 1) {
    if (tid < st) rbuf[tid] += rbuf[tid + st];
    __syncthreads();
  }
  const float r = rbuf[0];
  __syncthreads();
  return r;
}

// ---------------------------------------------------------------------------
// Fused fp32 -> bf16 cast over up to 6 regions (each a multiple of 1024).
// ---------------------------------------------------------------------------
struct CastArgs {
  const float* in[6];
  bf16* out[6];
  unsigned end[6];   // cumulative block counts
};
__global__ __launch_bounds__(256) void cast6_kernel(CastArgs a) {
  const unsigned b = blockIdx.x;
  int r = 0; unsigned base = 0;
  #pragma unroll
  for (int k = 0; k < 5; ++k)
    if (b >= a.end[k]) { r = k + 1; base = a.end[k]; }
  const float* in = a.in[r];
  bf16* out = a.out[r];
  const unsigned i = ((b - base) * 256 + threadIdx.x) * 4;
  const float4 v = *(const float4*)(in + i);
  uint2 o;
  o.x = (unsigned)bfbits(v.x) | ((unsigned)bfbits(v.y) << 16);
  o.y = (unsigned)bfbits(v.z) | ((unsigned)bfbits(v.w) << 16);
  *(uint2*)(out + i) = o;
}

// ---------------------------------------------------------------------------
// Pack W[N][K] fp32 -> B-fragment-ordered bf16 blocks:
//   out[(nt*(K/32)+kt2)*512 + lane*8 + e] = W[nt*16+(lane&15)][kt2*32+(lane>>4)*8+e]
// so a GEMM wave's B-frag load is ONE contiguous 1KB global read (no LDS, no
// pow-2-stride pathology). grid (K/128, N/16), 256 thr (4 kt2-groups/block).
// ---------------------------------------------------------------------------
__global__ __launch_bounds__(256) void pack_w_kernel(
    const float* __restrict__ W, bf16* __restrict__ out, int K) {
  const int lane = threadIdx.x & 63, sub = threadIdx.x >> 6;
  const int kt2 = blockIdx.x * 4 + sub;
  const int nt  = blockIdx.y;
  const int lm = lane & 15, quad = lane >> 4;
  const float* p = W + (size_t)(nt * 16 + lm) * K + kt2 * 32 + quad * 8;
  const float4 a = *(const float4*)p;
  const float4 b = *(const float4*)(p + 4);
  uint4 o;
  o.x = (unsigned)bfbits(a.x) | ((unsigned)bfbits(a.y) << 16);
  o.y = (unsigned)bfbits(a.z) | ((unsigned)bfbits(a.w) << 16);
  o.z = (unsigned)bfbits(b.x) | ((unsigned)bfbits(b.y) << 16);
  o.w = (unsigned)bfbits(b.z) | ((unsigned)bfbits(b.w) << 16);
  *(uint4*)(out + (((size_t)(nt * (K >> 5) + kt2)) << 9) + lane * 8) = o;
}

// Concat Qp_w/Kp_w -> bf16 [128][1024], Qp_b/Kp_b -> fp32 [128]
__global__ __launch_bounds__(256) void pack_qk_kernel(
    const float* __restrict__ Qw, const float* __restrict__ Kw,
    const float* __restrict__ Qb, const float* __restrict__ Kb,
    bf16* __restrict__ w, float* __restrict__ bias) {
  const int r = blockIdx.x;  // 0..127
  const float* srcw = (r < 64) ? (Qw + (size_t)r * ND) : (Kw + (size_t)(r - 64) * ND);
  for (int i = threadIdx.x; i < ND; i += 256) w[(size_t)r * ND + i] = f2b(srcw[i]);
  if (r == 0)
    for (int i = threadIdx.x; i < 128; i += 256)
      bias[i] = (i < 64) ? Qb[i] : Kb[i - 64];
}

// ---------------------------------------------------------------------------
// Generic batched MFMA GEMM (2-phase 128-tile template): C = scale*(A@W^T)
// (+bias), bf16 in. A/B staged via global_load_lds (XOR-slot swizzle),
// double-buffered, counted-vmcnt 2-barrier pipeline. Used for steps 4/4b.
// ---------------------------------------------------------------------------
template<int BM, int BN, int BK, int BIAS, int RELU, int OUTF32>
__global__ __launch_bounds__(256) void mfma_gemm(
    const bf16* __restrict__ A, const bf16* __restrict__ W,
    const float* __restrict__ bias, void* __restrict__ C,
    int K, int lda, int ldb, int ldc,
    long long aHi, long long aLo, long long bHi, long long bLo,
    long long cHi, long long cLo, float scale)
{
  constexpr int WTM = BM / 2;
  constexpr int WTN = BN / 2;
  constexpr int AM = WTM / 16;
  constexpr int AN = WTN / 16;
  constexpr int KK = BK / 32;
  constexpr int SLOTS = BK / 8;
  constexpr int RPC = 512 / BK;
  constexpr int LPW = (BM * BK) / 2048 + (BN * BK) / 2048;
  __shared__ short As[2][BM * BK];
  __shared__ short Bs[2][BN * BK];
  const int tid  = threadIdx.x;
  const int lane = tid & 63;
  const int w    = tid >> 6;
  const int z    = blockIdx.z;
  const long long aOff = (long long)(z >> 4) * aHi + (long long)(z & 15) * aLo;
  const long long bOff = (long long)(z >> 4) * bHi + (long long)(z & 15) * bLo;
  const long long cOff = (long long)(z >> 4) * cHi + (long long)(z & 15) * cLo;

  int bx = blockIdx.x, by = blockIdx.y;
  if ((gridDim.x & 7) == 0) {
    const unsigned lin = blockIdx.y * gridDim.x + blockIdx.x;
    const unsigned Wd = gridDim.x >> 3;
    const unsigned xcd = lin & 7, i = lin >> 3;
    bx = (int)(xcd * Wd + (i % Wd));
    by = (int)(i / Wd);
  }
  const int m0 = by * BM;
  const int n0 = bx * BN;
  const int wr = w >> 1, wc = w & 1;
  const int lm = lane & 15, quad = lane >> 4;

  f32x4 acc[AM][AN];
  #pragma unroll
  for (int i = 0; i < AM; ++i)
    #pragma unroll
    for (int j = 0; j < AN; ++j) acc[i][j] = (f32x4){0.f, 0.f, 0.f, 0.f};

  const int slot = lane & (SLOTS - 1);
  const int sr   = lane / SLOTS;
  const int swz  = (BK == 32) ? ((sr >> 1) & 3) : (sr & 7);
  const int scol = (slot ^ swz) << 3;
  const int xv   = (BK == 32) ? ((lm >> 1) & 3) : (lm & 7);
  const bf16* Ab = A + aOff;
  const bf16* Bb = W + bOff;

  auto stage = [&](int buf, int k0) {
    #pragma unroll
    for (int t = 0; t < (BM * BK) / 2048; ++t) {
      const int row = w * (BM / 4) + t * RPC;
      gload_lds16(Ab + (long long)(m0 + row + sr) * lda + k0 + scol, &As[buf][row * BK]);
    }
    #pragma unroll
    for (int t = 0; t < (BN * BK) / 2048; ++t) {
      const int row = w * (BN / 4) + t * RPC;
      gload_lds16(Bb + (long long)(n0 + row + sr) * ldb + k0 + scol, &Bs[buf][row * BK]);
    }
  };
  auto compute = [&](int buf) {
    #pragma unroll
    for (int kk = 0; kk < KK; ++kk) {
      const int cb = ((kk * 4 + quad) ^ xv) << 3;
      short8 af[AM], bfr[AN];
      #pragma unroll
      for (int i = 0; i < AM; ++i)
        af[i] = *(const short8*)&As[buf][(wr * WTM + i * 16 + lm) * BK + cb];
      #pragma unroll
      for (int j = 0; j < AN; ++j)
        bfr[j] = *(const short8*)&Bs[buf][(wc * WTN + j * 16 + lm) * BK + cb];
      #pragma unroll
      for (int i = 0; i < AM; ++i)
        #pragma unroll
        for (int j = 0; j < AN; ++j)
          acc[i][j] = __builtin_amdgcn_mfma_f32_16x16x32_bf16(af[i], bfr[j], acc[i][j], 0, 0, 0);
    }
  };

  stage(0, 0);
  int cur = 0;
  for (int k0 = BK; k0 < K; k0 += BK) {
    stage(cur ^ 1, k0);
    vm_wait<LPW>();
    bar();
    compute(cur);
    bar();
    cur ^= 1;
  }
  vm_wait<0>();
  bar();
  compute(cur);

  #pragma unroll
  for (int i = 0; i < AM; ++i) {
    #pragma unroll
    for (int j = 0; j < AN; ++j) {
      const int n = n0 + wc * WTN + j * 16 + lm;
      const float bj = BIAS ? bias[n] : 0.f;
      #pragma unroll
      for (int rr = 0; rr < 4; ++rr) {
        const int m = m0 + wr * WTM + i * 16 + quad * 4 + rr;
        float v = acc[i][j][rr] * scale + bj;
        if (RELU) v = fmaxf(v, 0.f);
        const long long co = cOff + (long long)m * ldc + n;
        if (OUTF32) ((float*)C)[co] = v;
        else        ((bf16*)C)[co] = f2b(v);
      }
    }
  }
}

// ---------------------------------------------------------------------------
// Packed-B MFMA GEMM (steps 3/5/6b/9): C = A@Bp^T (+bias), bf16.
// B comes from the fragment-packed layout (pack_w / step-5 PACKOUT) so each
// wave's B-frag is ONE contiguous 1KB global->VGPR load. A stays LDS-staged
// with the proven swizzle. B regs double-buffered with STATIC indexing.
// Pipeline per iter: stageA(nxt)+loadB(nxt); vmcnt(8); bar; compute(cur); bar.
// BM=128, BN=64, BK=64; 256 thr (2x2 waves, wave tile 64x32).
// PACKOUT=1: output stored fragment-packed per batch b=m>>10 (feeds 6b's B).
// ---------------------------------------------------------------------------
template<int BIAS, int RELU, int PACKOUT>
__global__ __launch_bounds__(256) void mfma_gemm_pb(
    const bf16* __restrict__ A, const bf16* __restrict__ Bp,
    const float* __restrict__ bias, bf16* __restrict__ C,
    int K, int lda, int ldc,
    long long aLo, long long bLo, long long cLo)
{
  __shared__ short As[2][128 * 64];   // 32 KB
  const int tid = threadIdx.x, lane = tid & 63, w = tid >> 6;
  const int z = blockIdx.z;
  const long long aOff = (long long)z * aLo;
  const long long cOff = (long long)z * cLo;
  int bx = blockIdx.x, by = blockIdx.y;
  if ((gridDim.x & 7) == 0) {
    const unsigned lin = blockIdx.y * gridDim.x + blockIdx.x;
    const unsigned Wd = gridDim.x >> 3;
    const unsigned xcd = lin & 7, i = lin >> 3;
    bx = (int)(xcd * Wd + (i % Wd));
    by = (int)(i / Wd);
  }
  const int m0 = by * 128, n0 = bx * 64;
  const int wr = w >> 1, wc = w & 1;
  const int lm = lane & 15, quad = lane >> 4;
  const int KT2 = K >> 5;

  f32x4 acc[4][2];
  #pragma unroll
  for (int i = 0; i < 4; ++i)
    #pragma unroll
    for (int j = 0; j < 2; ++j) acc[i][j] = (f32x4){0.f, 0.f, 0.f, 0.f};

  const int slot = lane & 7, sr = lane >> 3;
  const int scol = (slot ^ sr) << 3;   // A write-side swizzle (global col)
  const int xv   = lm & 7;             // A read-side swizzle
  const bf16* Ab = A + aOff;
  // B base: packed block (n/16-group) * KT2, + lane entry
  const bf16* Bb = Bp + (long long)z * bLo
                 + (((long long)(n0 / 16 + wc * 2) * KT2) << 9) + lane * 8;

  auto stageA = [&](int buf, int t) {
    const int k0 = t * 64;
    #pragma unroll
    for (int u = 0; u < 4; ++u) {
      const int row = w * 32 + u * 8;
      gload_lds16(Ab + (long long)(m0 + row + sr) * lda + k0 + scol, &As[buf][row * 64]);
    }
  };
  short8 brg[2][4];
  auto loadB = [&](auto BUF, int t) {
    constexpr int bu = decltype(BUF)::value;
    #pragma unroll
    for (int j = 0; j < 2; ++j)
      #pragma unroll
      for (int kk = 0; kk < 2; ++kk)
        brg[bu][j * 2 + kk] =
            *(const short8*)(Bb + (((long long)j * KT2 + t * 2 + kk) << 9));
  };
  auto compute = [&](auto BUF) {
    constexpr int bu = decltype(BUF)::value;
    #pragma unroll
    for (int kk = 0; kk < 2; ++kk) {
      const int cb = ((kk * 4 + quad) ^ xv) << 3;
      short8 af[4];
      #pragma unroll
      for (int i = 0; i < 4; ++i)
        af[i] = *(const short8*)&As[bu][(wr * 64 + i * 16 + lm) * 64 + cb];
      #pragma unroll
      for (int i = 0; i < 4; ++i)
        #pragma unroll
        for (int j = 0; j < 2; ++j)
          acc[i][j] = __builtin_amdgcn_mfma_f32_16x16x32_bf16(
              af[i], brg[bu][j * 2 + kk], acc[i][j], 0, 0, 0);
    }
  };
  const std::integral_constant<int, 0> B0{};
  const std::integral_constant<int, 1> B1{};

  const int nt = K / 64;               // >= 16, even
  stageA(0, 0); loadB(B0, 0);
  for (int t = 1; t + 1 < nt; t += 2) {
    stageA(1, t);     loadB(B1, t);
    vm_wait<8>(); bar(); compute(B0); bar();
    stageA(0, t + 1); loadB(B0, t + 1);
    vm_wait<8>(); bar(); compute(B1); bar();
  }
  stageA(1, nt - 1); loadB(B1, nt - 1);
  vm_wait<8>(); bar(); compute(B0); bar();
  vm_wait<0>(); bar(); compute(B1);

  #pragma unroll
  for (int i = 0; i < 4; ++i) {
    #pragma unroll
    for (int j = 0; j < 2; ++j) {
      const int n = n0 + wc * 32 + j * 16 + lm;
      const float bj = BIAS ? bias[n] : 0.f;
      float v0 = acc[i][j][0] + bj;
      float v1 = acc[i][j][1] + bj;
      float v2 = acc[i][j][2] + bj;
      float v3 = acc[i][j][3] + bj;
      if (RELU) {
        v0 = fmaxf(v0, 0.f); v1 = fmaxf(v1, 0.f);
        v2 = fmaxf(v2, 0.f); v3 = fmaxf(v3, 0.f);
      }
      const int mm = m0 + wr * 64 + i * 16 + quad * 4;
      if (PACKOUT) {
        // fragment-packed store: value(s=mm..+3, d=n) of W' = C^T per batch.
        const int b = mm >> 10, s = mm & 1023;
        bf16* dst = C + (long long)b * ((long long)NS * ND)
                  + (((long long)(n >> 4) * (NS >> 5) + (s >> 5)) << 9)
                  + (((s >> 3) & 3) * 16 + (n & 15)) * 8 + (s & 7);
        uint2 u;
        u.x = (unsigned)bfbits(v0) | ((unsigned)bfbits(v1) << 16);
        u.y = (unsigned)bfbits(v2) | ((unsigned)bfbits(v3) << 16);
        *(uint2*)dst = u;
      } else {
        C[cOff + (long long)(mm + 0) * ldc + n] = f2b(v0);
        C[cOff + (long long)(mm + 1) * ldc + n] = f2b(v1);
        C[cOff + (long long)(mm + 2) * ldc + n] = f2b(v2);
        C[cOff + (long long)(mm + 3) * ldc + n] = f2b(v3);
      }
    }
  }
}

// ---------------------------------------------------------------------------
// 256x256 8-phase GEMM (T3+T4+T5 port): C = A@W^T (+bias), bf16.
// 512 threads = 8 waves (2M x 4N); wave tile 128x64 (acc 8x4); BK=64;
// LDS = 128 KB -> 1 block/CU. Counted vmcnt, never 0 in main loop.
// VT=1: blocks with n0 >= 2*ND write transposed V into C2 (step 1).
// ---------------------------------------------------------------------------
template<int BIAS, int RELU, int VT>
__global__ __launch_bounds__(512) void mfma_gemm256(
    const bf16* __restrict__ A, const bf16* __restrict__ W,
    const float* __restrict__ bias, bf16* __restrict__ C,
    int K, int lda, int ldb, int ldc, bf16* __restrict__ C2)
{
  __shared__ short As[2][256 * 64];   // 64 KB
  __shared__ short Bs[2][256 * 64];   // 64 KB
  const int tid  = threadIdx.x;
  const int lane = tid & 63;
  const int w    = tid >> 6;          // 0..7
  int bx = blockIdx.x, by = blockIdx.y;
  if ((gridDim.x & 7) == 0) {
    const unsigned lin = blockIdx.y * gridDim.x + blockIdx.x;
    const unsigned Wd = gridDim.x >> 3;
    const unsigned xcd = lin & 7, i = lin >> 3;
    bx = (int)(xcd * Wd + (i % Wd));
    by = (int)(i / Wd);
  }
  const int m0 = by * 256;
  const int n0 = bx * 256;
  const int wr = w >> 2, wc = w & 3;  // wave grid 2(M) x 4(N)
  const int lm = lane & 15, quad = lane >> 4;

  f32x4 acc[8][4];
  #pragma unroll
  for (int i = 0; i < 8; ++i)
    #pragma unroll
    for (int j = 0; j < 4; ++j) acc[i][j] = (f32x4){0.f, 0.f, 0.f, 0.f};

  const int slot = lane & 7, sr = lane >> 3;
  const int scol = (slot ^ sr) << 3;   // swizzled global col (shorts)
  const int xv   = lm & 7;             // read-side swizzle

  auto stgA = [&](int buf, int c, int k0) {
    gload_lds16(A + (long long)(m0 + c * 64 + w * 8 + sr) * lda + k0 + scol,
                &As[buf][(c * 64 + w * 8) * 64]);
  };
  auto stgB = [&](int buf, int c, int k0) {
    gload_lds16(W + (long long)(n0 + c * 64 + w * 8 + sr) * ldb + k0 + scol,
                &Bs[buf][(c * 64 + w * 8) * 64]);
  };
  auto dsA = [&](short8* afr, int h, int buf) {      // 8 reads: A-half h
    #pragma unroll
    for (int i = 0; i < 4; ++i)
      #pragma unroll
      for (int kk = 0; kk < 2; ++kk)
        afr[i * 2 + kk] = *(const short8*)
            &As[buf][(wr * 128 + h * 64 + i * 16 + lm) * 64 + (((kk * 4 + quad) ^ xv) << 3)];
  };
  auto dsB = [&](short8* bfr, int jh, int buf) {     // 4 reads: B-half jh
    #pragma unroll
    for (int j = 0; j < 2; ++j)
      #pragma unroll
      for (int kk = 0; kk < 2; ++kk)
        bfr[j * 2 + kk] = *(const short8*)
            &Bs[buf][(wc * 64 + jh * 32 + j * 16 + lm) * 64 + (((kk * 4 + quad) ^ xv) << 3)];
  };
  auto mmaq = [&](auto H, auto JH, const short8* afr, const short8* bfr) {
    constexpr int h = decltype(H)::value, jh = decltype(JH)::value;
    __builtin_amdgcn_s_setprio(1);
    #pragma unroll
    for (int i = 0; i < 4; ++i)
      #pragma unroll
      for (int j = 0; j < 2; ++j)
        #pragma unroll
        for (int kk = 0; kk < 2; ++kk)
          acc[h * 4 + i][jh * 2 + j] = __builtin_amdgcn_mfma_f32_16x16x32_bf16(
              afr[i * 2 + kk], bfr[j * 2 + kk], acc[h * 4 + i][jh * 2 + j], 0, 0, 0);
    __builtin_amdgcn_s_setprio(0);
  };
  const std::integral_constant<int, 0> C0{};
  const std::integral_constant<int, 1> C1{};

  // prologue: stage tile 0 into buf 0 (age order matches steady state)
  stgB(0, 0, 0); stgB(0, 1, 0); stgB(0, 2, 0); stgB(0, 3, 0);
  stgA(0, 0, 0); stgA(0, 2, 0); stgA(0, 1, 0); stgA(0, 3, 0);
  vm_wait<0>();
  bar();

  const int NT = K / 64;
  int p = 0;
  for (int kt = 0; kt < NT; ++kt, p ^= 1) {
    const int k1 = (kt + 1) * 64;
    const bool pre = (kt + 1 < NT);
    short8 afr[8], bfrA[4], bfrB[4];
    // phase 1: quadrant (h0, j01)
    dsA(afr, 0, p); dsB(bfrA, 0, p);
    if (pre) { stgB(p ^ 1, 0, k1); stgB(p ^ 1, 1, k1); }
    bar();
    mmaq(C0, C0, afr, bfrA);
    bar();
    // phase 2: quadrant (h0, j23)
    dsB(bfrB, 1, p);
    if (pre) { stgB(p ^ 1, 2, k1); stgB(p ^ 1, 3, k1); vm_wait<4>(); }
    else vm_wait<0>();
    bar();
    mmaq(C0, C1, afr, bfrB);
    bar();
    // phase 3: quadrant (h1, j01)
    dsA(afr, 1, p);
    if (pre) { stgA(p ^ 1, 0, k1); stgA(p ^ 1, 2, k1); }
    bar();
    mmaq(C1, C0, afr, bfrA);
    bar();
    // phase 4: quadrant (h1, j23)
    if (pre) { stgA(p ^ 1, 1, k1); stgA(p ^ 1, 3, k1); vm_wait<2>(); }
    else vm_wait<0>();
    bar();
    mmaq(C1, C1, afr, bfrB);
    bar();
  }

  // epilogue
  #pragma unroll
  for (int i = 0; i < 8; ++i) {
    #pragma unroll
    for (int j = 0; j < 4; ++j) {
      const int n = n0 + wc * 64 + j * 16 + lm;
      const float bj = BIAS ? bias[n] : 0.f;
      float v0 = acc[i][j][0] + bj;
      float v1 = acc[i][j][1] + bj;
      float v2 = acc[i][j][2] + bj;
      float v3 = acc[i][j][3] + bj;
      if (RELU) {
        v0 = fmaxf(v0, 0.f); v1 = fmaxf(v1, 0.f);
        v2 = fmaxf(v2, 0.f); v3 = fmaxf(v3, 0.f);
      }
      const int mm = m0 + wr * 128 + i * 16 + quad * 4;
      if (VT && n0 >= 2 * ND) {
        const int h = (n - 2 * ND) >> 6, d = (n - 2 * ND) & 63;
        uint2 u;
        u.x = (unsigned)bfbits(v0) | ((unsigned)bfbits(v1) << 16);
        u.y = (unsigned)bfbits(v2) | ((unsigned)bfbits(v3) << 16);
        bf16* dst = C2 + (long long)((mm >> 10) * NH + h) * (NDH * NS)
                       + (long long)d * NS + (mm & 1023);
        *(uint2*)dst = u;
      } else {
        C[(long long)(mm + 0) * ldc + n] = f2b(v0);
        C[(long long)(mm + 1) * ldc + n] = f2b(v1);
        C[(long long)(mm + 2) * ldc + n] = f2b(v2);
        C[(long long)(mm + 3) * ldc + n] = f2b(v3);
      }
    }
  }
}

// ---------------------------------------------------------------------------
// Fused flash attention (dense MHA): per (q-tile of 128, b, h) block.
// Swapped QK^T -> S^T frags (q = lane&15). R8: NO-MAX softmax — fp32 exp
// cannot overflow at these score magnitudes (overflow needs s>88; scores are
// O(1)), and without max-rescaling the accumulation is exactly LINEAR:
//   O^T += V^T @ exp(S^T/8),  l += rowsum(exp),  normalize once at the end.
// Mathematically identical to reference softmax (max factor cancels), but
// deletes per tile: 64-op max pass, 4 shfl_xor reduces, exp-arg subtract,
// 64-mult O-rescale, per-tile l reduce (l reduced across quads ONCE in the
// epilogue). P^T bf16 B-frags built in-register via shfl. K/V^T staged via
// global_load_lds + XOR slot swizzle; counted-vmcnt 2-barrier pipeline.
// grid (NS/128, NB*NH), 256 threads.
// ---------------------------------------------------------------------------
__global__ __launch_bounds__(256) void attn_kernel(
    const bf16* __restrict__ qkv,   // [B][S][3*ND]
    const bf16* __restrict__ Vt,    // [B*H][NDH][NS]
    bf16* __restrict__ ctx)         // [B][S][ND]
{
  __shared__ short smem[2][2][64 * 64];   // [buf][K|V][4096] = 32 KB
  const int tid = threadIdx.x, lane = tid & 63, w = tid >> 6;
  const int lm = lane & 15, quad = lane >> 4;
  const int z = blockIdx.y, b = z >> 4, h = z & 15;
  const int q0 = blockIdx.x * 128;
  const bf16* Qb = qkv + (long long)b * NS * 3072 + h * 64;
  const bf16* Kb = Qb + ND;
  const bf16* Vb = Vt + (long long)z * (NDH * NS);

  // Q B-frags [j][kk]: col q = q0 + w*32 + j*16 + lm, k(d) = kk*32 + quad*8 + e
  short8 qf[2][2];
  #pragma unroll
  for (int j = 0; j < 2; ++j)
    #pragma unroll
    for (int kk = 0; kk < 2; ++kk)
      qf[j][kk] = *(const short8*)(Qb + (long long)(q0 + w * 32 + j * 16 + lm) * 3072
                                      + kk * 32 + quad * 8);

  // staging map (8 slots of 16B per 64-elem row; 8 rows per issue per wave)
  const int slot = lane & 7, sr = lane >> 3;
  const int scol = (slot ^ sr) << 3;      // shorts; involution with read side

  auto stage = [&](int buf, int t) {
    #pragma unroll
    for (int u = 0; u < 2; ++u) {
      const int row = w * 16 + u * 8;     // kv row within tile
      gload_lds16(Kb + (long long)(t * 64 + row + sr) * 3072 + scol,
                  &smem[buf][0][row * 64]);
    }
    #pragma unroll
    for (int u = 0; u < 2; ++u) {
      const int row = w * 16 + u * 8;     // d row
      gload_lds16(Vb + (long long)(row + sr) * NS + t * 64 + scol,
                  &smem[buf][1][row * 64]);
    }
  };

  f32x4 o[4][2];                          // O^T: d-tile i, q-tile j
  #pragma unroll
  for (int i = 0; i < 4; ++i)
    #pragma unroll
    for (int j = 0; j < 2; ++j) o[i][j] = (f32x4){0.f, 0.f, 0.f, 0.f};
  float l[2] = {0.f, 0.f};                // per-lane partial exp-sums

  stage(0, 0);
  for (int t = 0; t < 16; ++t) {
    const int buf = t & 1;
    if (t < 15) { stage(buf ^ 1, t + 1); vm_wait<4>(); }
    else        { vm_wait<0>(); }
    bar();                                // tile t's loads visible to all

    // --- S^T = (K @ Q^T) : st[i][j], i = kv-tile, j = q-tile
    f32x4 st[4][2];
    #pragma unroll
    for (int i = 0; i < 4; ++i)
      #pragma unroll
      for (int j = 0; j < 2; ++j) st[i][j] = (f32x4){0.f, 0.f, 0.f, 0.f};
    #pragma unroll
    for (int kk = 0; kk < 2; ++kk) {
      const int cb = ((kk * 4 + quad) ^ (lm & 7)) << 3;
      short8 ka[4];
      #pragma unroll
      for (int i = 0; i < 4; ++i)
        ka[i] = *(const short8*)&smem[buf][0][(i * 16 + lm) * 64 + cb];
      #pragma unroll
      for (int i = 0; i < 4; ++i)
        #pragma unroll
        for (int j = 0; j < 2; ++j)
          st[i][j] = __builtin_amdgcn_mfma_f32_16x16x32_bf16(ka[i], qf[j][kk], st[i][j], 0, 0, 0);
    }

    // --- no-max softmax accumulation: P = exp(s/8), l += sum (lane-local)
    #pragma unroll
    for (int j = 0; j < 2; ++j)
      #pragma unroll
      for (int i = 0; i < 4; ++i)
        #pragma unroll
        for (int r = 0; r < 4; ++r) {
          const float e = __expf(st[i][j][r] * 0.125f);
          st[i][j][r] = e;                 // st now holds P^T
          l[j] += e;
        }

    // --- pack P^T to bf16 pairs: u0 = (r0,r1), u1 = (r2,r3)
    unsigned u0[4][2], u1[4][2];
    #pragma unroll
    for (int i = 0; i < 4; ++i)
      #pragma unroll
      for (int j = 0; j < 2; ++j) {
        u0[i][j] = (unsigned)bfbits(st[i][j][0]) | ((unsigned)bfbits(st[i][j][1]) << 16);
        u1[i][j] = (unsigned)bfbits(st[i][j][2]) | ((unsigned)bfbits(st[i][j][3]) << 16);
      }
    // target frag (kk,j) elem e: kv = kk*32+quad*8+e comes from
    //   i_src = kk*2 + (quad>>1), src lane = ((quad&1)*2 + (e>>2))*16 + lm, r = e&3
    const int s0l = ((quad & 1) * 2) * 16 + lm;
    const int s1l = s0l + 16;
    const bool hi = (quad >> 1) != 0;

    // --- O^T += V^T @ P^T
    #pragma unroll
    for (int kk = 0; kk < 2; ++kk) {
      short8 pf[2];
      #pragma unroll
      for (int j = 0; j < 2; ++j) {
        const unsigned a0 = __shfl(u0[kk * 2][j],     s0l, 64);
        const unsigned a1 = __shfl(u1[kk * 2][j],     s0l, 64);
        const unsigned b0 = __shfl(u0[kk * 2 + 1][j], s0l, 64);
        const unsigned b1 = __shfl(u1[kk * 2 + 1][j], s0l, 64);
        const unsigned c0 = __shfl(u0[kk * 2][j],     s1l, 64);
        const unsigned c1 = __shfl(u1[kk * 2][j],     s1l, 64);
        const unsigned d0 = __shfl(u0[kk * 2 + 1][j], s1l, 64);
        const unsigned d1 = __shfl(u1[kk * 2 + 1][j], s1l, 64);
        union { uint4 u; short8 s; } cv;
        cv.u.x = hi ? b0 : a0; cv.u.y = hi ? b1 : a1;
        cv.u.z = hi ? d0 : c0; cv.u.w = hi ? d1 : c1;
        pf[j] = cv.s;
      }
      const int cb = ((kk * 4 + quad) ^ (lm & 7)) << 3;
      short8 va[4];
      #pragma unroll
      for (int i = 0; i < 4; ++i)
        va[i] = *(const short8*)&smem[buf][1][(i * 16 + lm) * 64 + cb];
      #pragma unroll
      for (int i = 0; i < 4; ++i)
        #pragma unroll
        for (int j = 0; j < 2; ++j)
          o[i][j] = __builtin_amdgcn_mfma_f32_16x16x32_bf16(va[i], pf[j], o[i][j], 0, 0, 0);
    }
    bar();   // all waves done reading buf before next overwrite / epilogue
  }

  // --- epilogue: ONE l-reduce across quads, normalize, transpose via LDS
  short (*OL)[72] = (short(*)[72])&smem[0][0][0];   // 128 x 72 = 18.4 KB
  #pragma unroll
  for (int j = 0; j < 2; ++j) {
    float lj = l[j];
    lj += __shfl_xor(lj, 16, 64);
    lj += __shfl_xor(lj, 32, 64);
    const float inv = 1.f / lj;
    #pragma unroll
    for (int i = 0; i < 4; ++i) {
      uint2 u;
      u.x = (unsigned)bfbits(o[i][j][0] * inv) | ((unsigned)bfbits(o[i][j][1] * inv) << 16);
      u.y = (unsigned)bfbits(o[i][j][2] * inv) | ((unsigned)bfbits(o[i][j][3] * inv) << 16);
      *(uint2*)&OL[w * 32 + j * 16 + lm][i * 16 + quad * 4] = u;
    }
  }
  __syncthreads();
  {
    const int q = tid >> 1, c = (tid & 1) * 32;
    const uint4 r0 = *(const uint4*)&OL[q][c];
    const uint4 r1 = *(const uint4*)&OL[q][c + 8];
    const uint4 r2 = *(const uint4*)&OL[q][c + 16];
    const uint4 r3 = *(const uint4*)&OL[q][c + 24];
    bf16* dst = ctx + ((long long)(b * NS + q0 + q)) * 1024 + h * 64 + c;
    ((uint4*)dst)[0] = r0; ((uint4*)dst)[1] = r1;
    ((uint4*)dst)[2] = r2; ((uint4*)dst)[3] = r3;
  }
}

// ---------------------------------------------------------------------------
// Sparse top-k selection from precomputed fp32 scores S[row][1024].
// One WAVE per row (4 rows/block); wave-local radix select.
// ---------------------------------------------------------------------------
__global__ __launch_bounds__(256) void sparse_select_kernel(
    const float* __restrict__ S, bf16* __restrict__ aw)
{
  __shared__ unsigned hist[4][256];
  const int tid = threadIdx.x;
  const int lane = tid & 63;
  const int wv = tid >> 6;
  const long long row = (long long)blockIdx.x * 4 + wv;

  float sv[16];
  const float* sp = S + row * 1024 + lane * 16;
  #pragma unroll
  for (int c = 0; c < 4; ++c) {
    const float4 v = ((const float4*)sp)[c];
    sv[4*c] = v.x; sv[4*c+1] = v.y; sv[4*c+2] = v.z; sv[4*c+3] = v.w;
  }
  unsigned key[16];
  #pragma unroll
  for (int j = 0; j < 16; ++j) {
    const unsigned u = __float_as_uint(sv[j]);
    key[j] = (u & 0x80000000u) ? ~u : (u | 0x80000000u);  // order-preserving
  }

  unsigned pref = 0u;
  int need = NTOPK;
  #pragma unroll
  for (int p = 3; p >= 0; --p) {
    *(uint4*)&hist[wv][lane * 4] = (uint4){0u, 0u, 0u, 0u};
    __syncthreads();
    const int sh = (p + 1) * 8;
    #pragma unroll
    for (int j = 0; j < 16; ++j) {
      const bool part = (p == 3) || ((key[j] >> sh) == pref);
      if (part) atomicAdd(&hist[wv][(key[j] >> (p * 8)) & 255u], 1u);
    }
    __syncthreads();
    const unsigned h0 = hist[wv][4*lane],     h1 = hist[wv][4*lane + 1];
    const unsigned h2 = hist[wv][4*lane + 2], h3 = hist[wv][4*lane + 3];
    const unsigned s3 = h3, s2 = h2 + s3, s1 = h1 + s2, s0 = h0 + s1;
    unsigned sum = s0;                      // suffix sum over lanes >= lane
    #pragma unroll
    for (int d2 = 1; d2 < 64; d2 <<= 1) {
      const unsigned t = __shfl_down(sum, d2, 64);
      if (lane < 64 - d2) sum += t;
    }
    const unsigned above = sum - s0;
    const unsigned cum[4]  = {above + s0, above + s1, above + s2, above + s3};
    const unsigned next[4] = {above + s1, above + s2, above + s3, above};
    unsigned candPref = 0u; int candNeed = 0; bool has = false;
    #pragma unroll
    for (int i = 0; i < 4; ++i) {
      if ((int)cum[i] >= need && (int)next[i] < need) {
        has = true;
        candPref = (pref << 8) | (unsigned)(4 * lane + i);
        candNeed = need - (int)next[i];
      }
    }
    const unsigned long long m = __ballot(has);
    const int srcLane = (int)(__ffsll((long long)m) - 1);
    pref = (unsigned)__shfl((int)candPref, srcLane, 64);
    need = __shfl(candNeed, srcLane, 64);
  }

  const unsigned T = pref;                  // 204th-largest key
  const unsigned tb = (T & 0x80000000u) ? (T ^ 0x80000000u) : ~T;
  const float thr = __uint_as_float(tb);

  float wvv[16];
  float psTop = 0.f, psAll = 0.f;
  #pragma unroll
  for (int j = 0; j < 16; ++j) {
    const float e = __expf(sv[j] - thr);
    psAll += e;
    const float wt = (key[j] >= T) ? e : 0.f;
    psTop += wt;
    wvv[j] = wt;
  }
  #pragma unroll
  for (int s = 1; s < 64; s <<= 1) {
    psTop += __shfl_xor(psTop, s, 64);
    psAll += __shfl_xor(psAll, s, 64);
  }
  const float inv = 1.f / (psTop + 1e-9f * psAll);

  uint4 o0, o1;
  o0.x = (unsigned)bfbits(wvv[0]*inv)  | ((unsigned)bfbits(wvv[1]*inv)  << 16);
  o0.y = (unsigned)bfbits(wvv[2]*inv)  | ((unsigned)bfbits(wvv[3]*inv)  << 16);
  o0.z = (unsigned)bfbits(wvv[4]*inv)  | ((unsigned)bfbits(wvv[5]*inv)  << 16);
  o0.w = (unsigned)bfbits(wvv[6]*inv)  | ((unsigned)bfbits(wvv[7]*inv)  << 16);
  o1.x = (unsigned)bfbits(wvv[8]*inv)  | ((unsigned)bfbits(wvv[9]*inv)  << 16);
  o1.y = (unsigned)bfbits(wvv[10]*inv) | ((unsigned)bfbits(wvv[11]*inv) << 16);
  o1.z = (unsigned)bfbits(wvv[12]*inv) | ((unsigned)bfbits(wvv[13]*inv) << 16);
  o1.w = (unsigned)bfbits(wvv[14]*inv) | ((unsigned)bfbits(wvv[15]*inv) << 16);
  bf16* op = aw + row * 1024 + lane * 16;
  ((uint4*)op)[0] = o0; ((uint4*)op)[1] = o1;
}

// ---------------------------------------------------------------------------
// fused = sig*dense + (1-sig)*sparse ; x1 = LN1(src + fused)  (bf16 out)
// ---------------------------------------------------------------------------
__global__ __launch_bounds__(256) void fuse_ln1_kernel(
    const float* __restrict__ src, const bf16* __restrict__ dense,
    const bf16* __restrict__ sparse, const float* __restrict__ lam,
    const float* __restrict__ g, const float* __restrict__ beta,
    bf16* __restrict__ x1)
{
  __shared__ float y[ND];
  __shared__ float rbuf[256];
  const int tid = threadIdx.x;
  const size_t base = (size_t)blockIdx.x * ND;
  const float sig = 1.f / (1.f + __expf(-lam[0]));
  const float c1 = 1.f - sig;
  float s1 = 0.f, s2 = 0.f;
  #pragma unroll
  for (int j = 0; j < 4; ++j) {
    const int i = tid + (j << 8);
    const float v = src[base + i] + sig * b2f(dense[base + i]) + c1 * b2f(sparse[base + i]);
    y[i] = v; s1 += v; s2 += v * v;
  }
  const float sum1 = block_sum_256(s1, rbuf, tid);
  const float sum2 = block_sum_256(s2, rbuf, tid);
  const float mean = sum1 * (1.f / ND);
  const float var  = sum2 * (1.f / ND) - mean * mean;
  const float rstd = rsqrtf(var + 1e-5f);
  #pragma unroll
  for (int j = 0; j < 4; ++j) {
    const int i = tid + (j << 8);
    x1[base + i] = f2b((y[i] - mean) * rstd * g[i] + beta[i]);
  }
}

// out = LN2(x1 + ff)  (fp32 out; ff is bf16)
__global__ __launch_bounds__(256) void ln2_kernel(
    const bf16* __restrict__ x1, const bf16* __restrict__ ff,
    const float* __restrict__ g, const float* __restrict__ beta,
    float* __restrict__ outp)
{
  __shared__ float y[ND];
  __shared__ float rbuf[256];
  const int tid = threadIdx.x;
  const size_t base = (size_t)blockIdx.x * ND;
  float s1 = 0.f, s2 = 0.f;
  #pragma unroll
  for (int j = 0; j < 4; ++j) {
    const int i = tid + (j << 8);
    const float v = b2f(x1[base + i]) + b2f(ff[base + i]);
    y[i] = v; s1 += v; s2 += v * v;
  }
  const float sum1 = block_sum_256(s1, rbuf, tid);
  const float sum2 = block_sum_256(s2, rbuf, tid);
  const float mean = sum1 * (1.f / ND);
  const float var  = sum2 * (1.f / ND) - mean * mean;
  const float rstd = rsqrtf(var + 1e-5f);
  #pragma unroll
  for (int j = 0; j < 4; ++j) {
    const int i = tid + (j << 8);
    outp[base + i] = (y[i] - mean) * rstd * g[i] + beta[i];
  }
}

// ---------------------------------------------------------------------------
extern "C" void kernel_launch(void* const* d_in, const int* in_sizes, int n_in,
                              void* d_out, int out_size, void* d_ws, size_t ws_size,
                              hipStream_t stream)
{
  const float* src        = (const float*)d_in[0];
  const float* in_proj_w  = (const float*)d_in[1];
  const float* in_proj_b  = (const float*)d_in[2];
  const float* out_proj_w = (const float*)d_in[3];
  const float* out_proj_b = (const float*)d_in[4];
  const float* Qp_w  = (const float*)d_in[5];
  const float* Qp_b  = (const float*)d_in[6];
  const float* Kp_w  = (const float*)d_in[7];
  const float* Kp_b  = (const float*)d_in[8];
  const float* Vp_w  = (const float*)d_in[9];
  const float* Vp_b  = (const float*)d_in[10];
  const float* lam   = (const float*)d_in[11];
  const float* ff1_w = (const float*)d_in[12];
  const float* ff1_b = (const float*)d_in[13];
  const float* ff2_w = (const float*)d_in[14];
  const float* ff2_b = (const float*)d_in[15];
  const float* ln1_g = (const float*)d_in[16];
  const float* ln1_b = (const float*)d_in[17];
  const float* ln2_g = (const float*)d_in[18];
  const float* ln2_b = (const float*)d_in[19];
  (void)in_sizes; (void)n_in; (void)out_size; (void)ws_size;

  // --------- workspace layout (offsets IDENTICAL to the proven layout;
  // w_out/w_vp/w_ff2 slots now hold the fragment-PACKED weights)
  char* ws = (char*)d_ws;
  size_t off = 0;
  auto take = [&](size_t bytes) -> void* {
    void* p = ws + off; off += (bytes + 255) & ~(size_t)255; return p;
  };
  bf16*  src_bf  = (bf16*) take((size_t)NM * ND * 2);          //  8.4 MB
  bf16*  w_qkv   = (bf16*) take((size_t)3 * ND * ND * 2);      //  6.3 MB
  bf16*  w_out_p = (bf16*) take((size_t)ND * ND * 2);          //  2.1 MB (packed)
  bf16*  w_vp_p  = (bf16*) take((size_t)ND * ND * 2);          //  2.1 MB (packed)
  bf16*  w_ff1   = (bf16*) take((size_t)NDFF * ND * 2);        //  8.4 MB
  bf16*  w_ff2_p = (bf16*) take((size_t)ND * NDFF * 2);        //  8.4 MB (packed)
  bf16*  w_qk    = (bf16*) take((size_t)128 * ND * 2);         //  0.26 MB
  float* bias_qk = (float*)take(128 * 4);
  const size_t mark = off;                                     // reuse point
  bf16*  qkv     = (bf16*) take((size_t)NM * 3 * ND * 2);      // 25.2 MB [dead after attn]
  bf16*  Vt_all  = (bf16*) take((size_t)NH * NS * NS * 2);     // slot 33.5 MB (uses 8.4) [dead after attn]
  bf16*  Vt_old  = (bf16*) take((size_t)NH * NDH * NS * 2);    //  2.1 MB [unused slot, keeps offsets]
  bf16*  ctx     = (bf16*) take((size_t)NM * ND * 2);          //  8.4 MB [dead after step 3]
  bf16*  dense   = (bf16*) take((size_t)NM * ND * 2);          //  8.4 MB
  bf16*  QKs_bf  = (bf16*) take((size_t)NM * 128 * 2);         //  1.05 MB
  bf16*  Vsp     = (bf16*) take((size_t)NM * ND * 2);          //  8.4 MB [unused slot now]
  bf16*  sparse  = (bf16*) take((size_t)NM * ND * 2);          //  8.4 MB
  (void)Vt_old; (void)Vsp;
  // aliases into dead regions (qkv+Vt_all dead after the attention):
  bf16*  x1    = (bf16*)(ws + mark);                                       // [0, 8.4M)
  bf16*  h1    = (bf16*)(ws + mark + (size_t)NM * ND * 2);                 // [8.4, 42.0M)
  bf16*  ffout = (bf16*)(ws + mark + (size_t)NM * ND * 2 + (size_t)NM * NDFF * 2); // [42.0, 50.4M)
  bf16*  aw    = (bf16*)(ws + mark + 2 * (size_t)NM * ND * 2 + (size_t)NM * NDFF * 2); // [50.4, 58.8M)
  float* S_sp  = (float*)(ws + mark + (size_t)NM * ND * 2);    // [8.4, 25.2M): written 4b,
                                                               // read 6a, dead before h1
  bf16*  Vsp_pk = (bf16*)ctx;  // ctx dead after step 3; step 5 writes PACKED here

  const dim3 blk(256);
  bf16* const NOC2 = nullptr;
  // 0a. fp32 -> bf16 casts (3 regions: src, in_proj_w, ff1_w; 11264 blocks)
  {
    CastArgs a;
    a.in[0] = src;        a.out[0] = src_bf;  // 4096 blocks
    a.in[1] = in_proj_w;  a.out[1] = w_qkv;   // 3072
    a.in[2] = ff1_w;      a.out[2] = w_ff1;   // 4096
    a.in[3] = src;        a.out[3] = src_bf;  // unused
    a.in[4] = src;        a.out[4] = src_bf;  // unused
    a.in[5] = src;        a.out[5] = src_bf;  // unused
    a.end[0] = 4096; a.end[1] = 7168; a.end[2] = 11264;
    a.end[3] = 11264; a.end[4] = 11264; a.end[5] = 11264;
    cast6_kernel<<<dim3(11264), blk, 0, stream>>>(a);
  }
  // 0b. fragment-pack the B-side weights (fp32 -> packed bf16)
  pack_w_kernel<<<dim3(ND/128,   ND/16), blk, 0, stream>>>(out_proj_w, w_out_p, ND);
  pack_w_kernel<<<dim3(ND/128,   ND/16), blk, 0, stream>>>(Vp_w,       w_vp_p,  ND);
  pack_w_kernel<<<dim3(NDFF/128, ND/16), blk, 0, stream>>>(ff2_w,      w_ff2_p, NDFF);
  pack_qk_kernel<<<dim3(128), blk, 0, stream>>>(Qp_w, Kp_w, Qp_b, Kp_b, w_qk, bias_qk);

  // 1. qkv = src @ in_proj^T + b  [4096,3072] bf16, 256-tile 8-phase kernel
  //    (192 blocks, 512 thr); V third written TRANSPOSED into Vt_all (VT=1).
  mfma_gemm256<1,0,1><<<dim3(3*ND/256, NM/256), dim3(512), 0, stream>>>(
      src_bf, w_qkv, in_proj_b, qkv, ND, ND, ND, 3*ND, Vt_all);

  // 2. dense MHA: fused flash attention (Vt_all already populated by step 1)
  attn_kernel<<<dim3(NS/128, NB*NH), blk, 0, stream>>>(qkv, Vt_all, ctx);

  // 3. dense_output = ctx @ out_proj^T + b  (packed-B kernel; 512 blocks)
  mfma_gemm_pb<1,0,0><<<dim3(ND/64, NM/128, 1), blk, 0, stream>>>(
      ctx, w_out_p, out_proj_b, dense, ND, ND, ND, 0, 0, 0);
  // 4. QKs_bf = src @ [Qp;Kp]^T + b  (bf16 [4096][128]; 64 blocks, old path)
  mfma_gemm<128,64,64,1,0,0><<<dim3(2, NM/128, 1), blk, 0, stream>>>(
      src_bf, w_qk, bias_qk, QKs_bf, ND, ND, ND, 128, 0,0, 0,0, 0,0, 1.f);
  // 4b. S_sp[b] = (Qs Ks^T)/8  fp32, batched over b (single K-tile at BK=64)
  mfma_gemm<128,64,64,0,0,1><<<dim3(NS/64, NS/128, NB), blk, 0, stream>>>(
      QKs_bf, QKs_bf + 64, nullptr, S_sp, 64, 128, 128, NS,
      0, (long long)NS*128, 0, (long long)NS*128, 0, (long long)NS*NS, 0.125f);
  // 5. Vsp packed: (src @ Vp^T + b) stored in FRAGMENT-PACKED form per batch
  //    (PACKOUT=1) into the ctx slot — feeds step 6b's B directly.
  mfma_gemm_pb<1,0,1><<<dim3(ND/64, NM/128, 1), blk, 0, stream>>>(
      src_bf, w_vp_p, Vp_b, Vsp_pk, ND, ND, 0, 0, 0, 0);
  // 6a. top-k select + normalized weights -> aw (bf16), one wave per row
  sparse_select_kernel<<<dim3(NM/4), blk, 0, stream>>>(S_sp, aw);
  // 6b. sparse = aw @ Vsp^T  (batched per b; packed-B; 512 blocks)
  mfma_gemm_pb<0,0,0><<<dim3(ND/64, NS/128, NB), blk, 0, stream>>>(
      aw, Vsp_pk, nullptr, sparse, NS, NS, ND,
      (long long)NS*ND, (long long)NS*ND, (long long)NS*ND);
  // 7. fuse + residual + LN1 -> x1 (bf16)  [qkv/Vt_all dead; x1 aliases them]
  fuse_ln1_kernel<<<dim3(NM), blk, 0, stream>>>(src, dense, sparse, lam, ln1_g, ln1_b, x1);
  // 8. h1 = relu(x1 @ ff1^T + b)  (bf16; 256-tile 8-phase, 256 blocks = 1/CU)
  mfma_gemm256<1,1,0><<<dim3(NDFF/256, NM/256), dim3(512), 0, stream>>>(
      x1, w_ff1, ff1_b, h1, ND, ND, ND, NDFF, NOC2);
  // 9. ff = h1 @ ff2^T + b  (packed-B kernel; K=4096; 512 blocks)
  mfma_gemm_pb<1,0,0><<<dim3(ND/64, NM/128, 1), blk, 0, stream>>>(
      h1, w_ff2_p, ff2_b, ffout, NDFF, NDFF, ND, 0, 0, 0);
  // 10. out = LN2(x1 + ff)  (fp32)
  ln2_kernel<<<dim3(NM), blk, 0, stream>>>(x1, ffout, ln2_g, ln2_b, (float*)d_out);
}